// Round 1
// baseline (1442.786 us; speedup 1.0000x reference)
//
#include <hip/hip_runtime.h>
#include <hip/hip_bf16.h>
#include <math.h>

// Problem constants
#define B 32
#define T 64
#define P 196
#define D 768
#define H 12
#define HD 64
#define F 64

// ---------------- wave helpers (wave64) ----------------
__device__ __forceinline__ float wave_sum(float v) {
#pragma unroll
  for (int o = 32; o > 0; o >>= 1) v += __shfl_xor(v, o);
  return v;
}
__device__ __forceinline__ float wave_max(float v) {
#pragma unroll
  for (int o = 32; o > 0; o >>= 1) v = fmaxf(v, __shfl_xor(v, o));
  return v;
}

// ---------------- generic fp32 GEMM: C[M,N] = A[M,K] @ W[K,N] (+bias) ----------------
// Requires M%64==0, N%64==0, K%16==0. 64x64 tile, 256 threads, 4x4 microtile.
__global__ __launch_bounds__(256) void gemm_bias_kernel(
    const float* __restrict__ A, const float* __restrict__ W,
    const float* __restrict__ bias, float* __restrict__ C,
    int M, int N, int K) {
  __shared__ float As[16][64];   // [k][row]
  __shared__ float Ws[16][64];   // [k][col]
  const int tid = threadIdx.x;
  const int tx = tid & 15;       // col group
  const int ty = tid >> 4;       // row group
  const int row0 = blockIdx.y * 64;
  const int col0 = blockIdx.x * 64;

  // A-load: thread loads float4: row = tid>>2, kofs = (tid&3)*4
  const int ar = tid >> 2;
  const int ak = (tid & 3) << 2;
  // W-load: row k = tid>>4 (0..15), col = (tid&15)*4
  const int kr = tid >> 4;
  const int wc = (tid & 15) << 2;

  const float* Aptr = A + (size_t)(row0 + ar) * K + ak;
  const float* Wptr = W + (size_t)kr * N + col0 + wc;

  float acc[4][4];
#pragma unroll
  for (int i = 0; i < 4; ++i)
#pragma unroll
    for (int j = 0; j < 4; ++j) acc[i][j] = 0.0f;

  for (int k0 = 0; k0 < K; k0 += 16) {
    float4 a4 = *(const float4*)(Aptr + k0);
    float4 w4 = *(const float4*)(Wptr + (size_t)k0 * N);
    As[ak + 0][ar] = a4.x;
    As[ak + 1][ar] = a4.y;
    As[ak + 2][ar] = a4.z;
    As[ak + 3][ar] = a4.w;
    *(float4*)&Ws[kr][wc] = w4;
    __syncthreads();
#pragma unroll
    for (int kk = 0; kk < 16; ++kk) {
      float4 av = *(const float4*)&As[kk][ty * 4];
      float4 wv = *(const float4*)&Ws[kk][tx * 4];
      acc[0][0] += av.x * wv.x; acc[0][1] += av.x * wv.y; acc[0][2] += av.x * wv.z; acc[0][3] += av.x * wv.w;
      acc[1][0] += av.y * wv.x; acc[1][1] += av.y * wv.y; acc[1][2] += av.y * wv.z; acc[1][3] += av.y * wv.w;
      acc[2][0] += av.z * wv.x; acc[2][1] += av.z * wv.y; acc[2][2] += av.z * wv.z; acc[2][3] += av.z * wv.w;
      acc[3][0] += av.w * wv.x; acc[3][1] += av.w * wv.y; acc[3][2] += av.w * wv.z; acc[3][3] += av.w * wv.w;
    }
    __syncthreads();
  }

  float4 bv = make_float4(0.f, 0.f, 0.f, 0.f);
  if (bias) bv = *(const float4*)&bias[col0 + tx * 4];
#pragma unroll
  for (int i = 0; i < 4; ++i) {
    int row = row0 + ty * 4 + i;
    float4 r;
    r.x = acc[i][0] + bv.x;
    r.y = acc[i][1] + bv.y;
    r.z = acc[i][2] + bv.z;
    r.w = acc[i][3] + bv.w;
    *(float4*)&C[(size_t)row * N + col0 + tx * 4] = r;
  }
}

// ---------------- cross attention: one wave per (b,h,t) ----------------
// q:[B,T,D], k,v:[B,P,D] (head h at offset h*64). out:[B,T,D]
__global__ __launch_bounds__(64) void cross_attn_kernel(
    const float* __restrict__ q, const float* __restrict__ k,
    const float* __restrict__ v, float* __restrict__ out) {
  const int t = blockIdx.x, h = blockIdx.y, b = blockIdx.z;
  const int lane = threadIdx.x;
  __shared__ float qs[64];
  __shared__ float kts[64][65];
  __shared__ float sc[196];

  qs[lane] = q[((size_t)(b * T + t)) * D + h * 64 + lane];
  __syncthreads();

  for (int p0 = 0; p0 < P; p0 += 64) {
    int np = min(64, P - p0);
    for (int pp = 0; pp < np; ++pp)
      kts[pp][lane] = k[((size_t)(b * P + p0 + pp)) * D + h * 64 + lane];
    __syncthreads();
    if (lane < np) {
      float s = 0.f;
#pragma unroll 8
      for (int d = 0; d < 64; ++d) s += qs[d] * kts[lane][d];
      sc[p0 + lane] = s * 0.125f;  // 1/sqrt(64)
    }
    __syncthreads();
  }

  // softmax over 196
  float e0 = sc[lane], e1 = sc[lane + 64], e2 = sc[lane + 128];
  float e3 = (lane < 4) ? sc[lane + 192] : -3.4e38f;
  float m = fmaxf(fmaxf(e0, e1), fmaxf(e2, e3));
  m = wave_max(m);
  float p0e = expf(e0 - m), p1e = expf(e1 - m), p2e = expf(e2 - m);
  float p3e = (lane < 4) ? expf(e3 - m) : 0.f;
  float ssum = wave_sum(p0e + p1e + p2e + p3e);
  float inv = 1.0f / ssum;
  sc[lane] = p0e * inv;
  sc[lane + 64] = p1e * inv;
  sc[lane + 128] = p2e * inv;
  if (lane < 4) sc[lane + 192] = p3e * inv;
  __syncthreads();

  float acc = 0.f;
  for (int p = 0; p < P; ++p)
    acc += sc[p] * v[((size_t)(b * P + p)) * D + h * 64 + lane];
  out[((size_t)(b * T + t)) * D + h * 64 + lane] = acc;
}

// ---------------- s_token + f_token ----------------
__global__ __launch_bounds__(256) void token_kernel(
    const float* __restrict__ upd, const float* __restrict__ img,
    float* __restrict__ f_token, float* __restrict__ s_token) {
  const int b = blockIdx.x, tid = threadIdx.x;
  for (int d = tid; d < D; d += 256) {
    float s = 0.f;
    for (int t = 0; t < T; ++t) s += upd[((size_t)(b * T + t)) * D + d];
    f_token[b * D + d] = s * (1.0f / T);
  }
  float part = 0.f;
  for (int idx = tid; idx < T * D; idx += 256) {
    int t = idx / D, d = idx - t * D;
    part += upd[((size_t)(b * T + t)) * D + d] * img[((size_t)(b * P + t)) * D + d];
  }
  part = wave_sum(part);
  __shared__ float red[4];
  if ((tid & 63) == 0) red[tid >> 6] = part;
  __syncthreads();
  if (tid == 0) s_token[b] = (red[0] + red[1] + red[2] + red[3]) * (1.0f / T);
}

// ---------------- text GAT: one wave per (b,h). N=64 nodes ----------------
__global__ __launch_bounds__(64) void text_gat_kernel(
    const float* __restrict__ Wh, const int* __restrict__ adj,
    const float* __restrict__ at, float* __restrict__ tgf) {
  const int h = blockIdx.x, b = blockIdx.y;
  const int lane = threadIdx.x;
  __shared__ float Whs[64][65];
  __shared__ float srcs[64], dsts[64];

  for (int n = 0; n < 64; ++n)
    Whs[n][lane] = Wh[((size_t)(b * T + n)) * D + h * 64 + lane];
  float a_s = at[lane];
  float a_d = at[64 + lane];
  __syncthreads();

  float s = 0.f, dd = 0.f;
#pragma unroll 8
  for (int f = 0; f < 64; ++f) {
    float w = Whs[lane][f];
    s += w * __shfl(a_s, f);
    dd += w * __shfl(a_d, f);
  }
  srcs[lane] = s;
  dsts[lane] = dd;
  __syncthreads();

  const int* adjb = adj + b * T * T;
  float macc = 0.f;
  for (int i = 0; i < 64; ++i) {
    float e = srcs[i] + dsts[lane];
    e = (e >= 0.f) ? e : 0.2f * e;
    if (adjb[i * 64 + lane] == 0) e = -9e15f;
    float m = wave_max(e);
    float pp = expf(e - m);
    float ssum = wave_sum(pp);
    float att = pp / ssum;
    float hp = 0.f;
#pragma unroll 8
    for (int j = 0; j < 64; ++j) hp += __shfl(att, j) * Whs[j][lane];
    macc += (hp > 0.f) ? hp : (expf(hp) - 1.0f);
  }
  tgf[b * D + h * 64 + lane] = macc * (1.0f / T);
}

// ---------------- image GAT: one 256-thread block per (b,h). N=196 ----------------
__global__ __launch_bounds__(256) void image_gat_kernel(
    const float* __restrict__ Wh, const int* __restrict__ adj,
    const float* __restrict__ ai, float* __restrict__ igf) {
  const int h = blockIdx.x, b = blockIdx.y;
  const int tid = threadIdx.x, lane = tid & 63, w = tid >> 6;
  __shared__ float Whs[196][65];
  __shared__ float srcs[196], dsts[196];
  __shared__ float atts[4][196];
  __shared__ float redc[4][64];
  __shared__ float asv[64], adv[64];

  if (tid < 64) { asv[tid] = ai[tid]; adv[tid] = ai[64 + tid]; }
  for (int idx = tid; idx < P * 64; idx += 256) {
    int n = idx >> 6, f = idx & 63;
    Whs[n][f] = Wh[((size_t)(b * P + n)) * D + h * 64 + f];
  }
  __syncthreads();

  for (int n = tid; n < P; n += 256) {
    float s = 0.f, dd = 0.f;
#pragma unroll 8
    for (int f = 0; f < 64; ++f) {
      float wv = Whs[n][f];
      s += wv * asv[f];
      dd += wv * adv[f];
    }
    srcs[n] = s;
    dsts[n] = dd;
  }
  __syncthreads();

  float macc = 0.f;
  for (int i0 = 0; i0 < 49; ++i0) {
    int i = i0 * 4 + w;  // 0..195, uniform loop count per wave
    float e0, e1, e2, e3;
    {
      float si = srcs[i];
      float x;
      x = si + dsts[lane];        e0 = (x >= 0.f) ? x : 0.2f * x;
      x = si + dsts[lane + 64];   e1 = (x >= 0.f) ? x : 0.2f * x;
      x = si + dsts[lane + 128];  e2 = (x >= 0.f) ? x : 0.2f * x;
      if (lane < 4) { x = si + dsts[lane + 192]; e3 = (x >= 0.f) ? x : 0.2f * x; }
      else e3 = -3.4e38f;
      const int* ar = adj + i * P;
      if (ar[lane] == 0) e0 = -9e15f;
      if (ar[lane + 64] == 0) e1 = -9e15f;
      if (ar[lane + 128] == 0) e2 = -9e15f;
      if (lane < 4 && ar[lane + 192] == 0) e3 = -9e15f;
    }
    float m = wave_max(fmaxf(fmaxf(e0, e1), fmaxf(e2, e3)));
    float p0e = expf(e0 - m), p1e = expf(e1 - m), p2e = expf(e2 - m);
    float p3e = (lane < 4) ? expf(e3 - m) : 0.f;
    float ssum = wave_sum(p0e + p1e + p2e + p3e);
    float inv = 1.0f / ssum;
    atts[w][lane] = p0e * inv;
    atts[w][lane + 64] = p1e * inv;
    atts[w][lane + 128] = p2e * inv;
    if (lane < 4) atts[w][lane + 192] = p3e * inv;
    __syncthreads();
    float hp = 0.f;
#pragma unroll 4
    for (int j = 0; j < P; ++j) hp += atts[w][j] * Whs[j][lane];
    macc += (hp > 0.f) ? hp : (expf(hp) - 1.0f);
    __syncthreads();
  }

  redc[w][lane] = macc;
  __syncthreads();
  if (w == 0) {
    float tot = redc[0][lane] + redc[1][lane] + redc[2][lane] + redc[3][lane];
    igf[b * D + h * 64 + lane] = tot * (1.0f / P);
  }
}

// ---------------- final fusion kernel: one block per b ----------------
__device__ __forceinline__ float block_sum(float v, float* red4) {
  v = wave_sum(v);
  __syncthreads();
  if ((threadIdx.x & 63) == 0) red4[threadIdx.x >> 6] = v;
  __syncthreads();
  return red4[0] + red4[1] + red4[2] + red4[3];
}

__global__ __launch_bounds__(256) void final_kernel(
    const float* __restrict__ tgf, const float* __restrict__ igf,
    const float* __restrict__ clip_t, const float* __restrict__ clip_i,
    const float* __restrict__ logit_scale, const float* __restrict__ s_token,
    const float* __restrict__ f_token,
    const float* __restrict__ Wp, const float* __restrict__ bp,
    const float* __restrict__ f1w, const float* __restrict__ f1b,
    const float* __restrict__ f2w, const float* __restrict__ f2b,
    const float* __restrict__ c1w, const float* __restrict__ c1b,
    const float* __restrict__ c2w, const float* __restrict__ c2b,
    float* __restrict__ out) {
  const int b = blockIdx.x, tid = threadIdx.x;
  __shared__ float red[4];
  __shared__ float sres[4];
  __shared__ float fagg[768];
  __shared__ float hid[384];

  float d0 = 0.f, d1 = 0.f, d2 = 0.f;
  for (int i = tid; i < D; i += 256) {
    float x = tgf[b * D + i], y = igf[b * D + i];
    d0 += x * y; d1 += x * x; d2 += y * y;
  }
  float dot_ti = block_sum(d0, red);
  float n_t = sqrtf(block_sum(d1, red));
  float n_i = sqrtf(block_sum(d2, red));
  float s_phrase = dot_ti / (fmaxf(n_t, 1e-8f) * fmaxf(n_i, 1e-8f));

  float c0 = 0.f, c1 = 0.f, c2 = 0.f;
  for (int i = tid; i < 512; i += 256) {
    float x = clip_t[b * 512 + i], y = clip_i[b * 512 + i];
    c0 += x * y; c1 += x * x; c2 += y * y;
  }
  float dc = block_sum(c0, red);
  float nt2 = sqrtf(block_sum(c1, red));
  float ni2 = sqrtf(block_sum(c2, red));
  float s_global = expf(logit_scale[0]) * dc / (fmaxf(nt2, 1e-8f) * fmaxf(ni2, 1e-8f));

  if (tid == 0) {
    float s3[3] = { s_token[b], s_phrase, s_global };
    float h1[16];
    for (int j = 0; j < 16; ++j) {
      float a = f1b[j];
      for (int i2 = 0; i2 < 3; ++i2) a += s3[i2] * f1w[i2 * 16 + j];
      h1[j] = 0.5f * a * (1.0f + erff(a * 0.70710678118654752f));
    }
    for (int j = 0; j < 3; ++j) {
      float a = f2b[j];
      for (int i2 = 0; i2 < 16; ++i2) a += h1[i2] * f2w[i2 * 3 + j];
      sres[j] = 1.0f / (1.0f + expf(-a));
    }
  }
  __syncthreads();
  float w0 = sres[0], w1 = sres[1], w2 = sres[2];

  for (int j = tid; j < D; j += 256) {
    float fg = bp[j];
    for (int k2 = 0; k2 < 512; ++k2) fg += clip_t[b * 512 + k2] * Wp[k2 * D + j];
    fagg[j] = w0 * f_token[b * D + j] + w1 * tgf[b * D + j] + w2 * fg;
  }
  __syncthreads();

  for (int j = tid; j < 384; j += 256) {
    float a = c1b[j];
    for (int k2 = 0; k2 < D; ++k2) a += fagg[k2] * c1w[k2 * 384 + j];
    hid[j] = fmaxf(a, 0.0f);
  }
  __syncthreads();

  float p0 = 0.f, p1 = 0.f;
  for (int k2 = tid; k2 < 384; k2 += 256) {
    p0 += hid[k2] * c2w[k2 * 2 + 0];
    p1 += hid[k2] * c2w[k2 * 2 + 1];
  }
  p0 = block_sum(p0, red);
  p1 = block_sum(p1, red);
  if (tid == 0) {
    out[b * 2 + 0] = p0 + c2b[0];
    out[b * 2 + 1] = p1 + c2b[1];
  }
}

// ---------------- launch ----------------
extern "C" void kernel_launch(void* const* d_in, const int* in_sizes, int n_in,
                              void* d_out, int out_size, void* d_ws, size_t ws_size,
                              hipStream_t stream) {
  const float* text   = (const float*)d_in[0];
  const float* img    = (const float*)d_in[1];
  const float* clip_t = (const float*)d_in[2];
  const float* clip_i = (const float*)d_in[3];
  const float* lscale = (const float*)d_in[4];
  const float* wq = (const float*)d_in[5];
  const float* bq = (const float*)d_in[6];
  const float* wk = (const float*)d_in[7];
  const float* bk = (const float*)d_in[8];
  const float* wv = (const float*)d_in[9];
  const float* bv = (const float*)d_in[10];
  const float* wo = (const float*)d_in[11];
  const float* bo = (const float*)d_in[12];
  const float* Wt = (const float*)d_in[13];
  const float* at = (const float*)d_in[14];
  const float* Wi = (const float*)d_in[15];
  const float* ai = (const float*)d_in[16];
  const float* Wp = (const float*)d_in[17];
  const float* bp = (const float*)d_in[18];
  const float* f1w = (const float*)d_in[19];
  const float* f1b = (const float*)d_in[20];
  const float* f2w = (const float*)d_in[21];
  const float* f2b = (const float*)d_in[22];
  const float* c1w = (const float*)d_in[23];
  const float* c1b = (const float*)d_in[24];
  const float* c2w = (const float*)d_in[25];
  const float* c2b = (const float*)d_in[26];
  const int* text_adj  = (const int*)d_in[27];
  const int* image_adj = (const int*)d_in[28];
  float* out = (float*)d_out;

  // workspace layout (floats)
  float* buf = (float*)d_ws;
  size_t o = 0;
  float* k_buf   = buf + o; o += (size_t)B * P * D;  // also reused as Wh_i
  float* v_buf   = buf + o; o += (size_t)B * P * D;
  float* q_buf   = buf + o; o += (size_t)B * T * D;  // also reused as Wh_t
  float* att_buf = buf + o; o += (size_t)B * T * D;
  float* upd_buf = buf + o; o += (size_t)B * T * D;
  float* ftok    = buf + o; o += (size_t)B * D;
  float* stok    = buf + o; o += 32;
  float* tgf     = buf + o; o += (size_t)B * D;
  float* igf     = buf + o; o += (size_t)B * D;

  const int MT = B * T;  // 2048
  const int MP = B * P;  // 6272

  gemm_bias_kernel<<<dim3(D / 64, MT / 64), 256, 0, stream>>>(text, wq, bq, q_buf, MT, D, D);
  gemm_bias_kernel<<<dim3(D / 64, MP / 64), 256, 0, stream>>>(img, wk, bk, k_buf, MP, D, D);
  gemm_bias_kernel<<<dim3(D / 64, MP / 64), 256, 0, stream>>>(img, wv, bv, v_buf, MP, D, D);
  cross_attn_kernel<<<dim3(T, H, B), 64, 0, stream>>>(q_buf, k_buf, v_buf, att_buf);
  gemm_bias_kernel<<<dim3(D / 64, MT / 64), 256, 0, stream>>>(att_buf, wo, bo, upd_buf, MT, D, D);
  // GAT projections (reuse q_buf for Wh_t, k_buf for Wh_i)
  gemm_bias_kernel<<<dim3(D / 64, MT / 64), 256, 0, stream>>>(text, Wt, nullptr, q_buf, MT, D, D);
  gemm_bias_kernel<<<dim3(D / 64, MP / 64), 256, 0, stream>>>(img, Wi, nullptr, k_buf, MP, D, D);
  token_kernel<<<B, 256, 0, stream>>>(upd_buf, img, ftok, stok);
  text_gat_kernel<<<dim3(H, B), 64, 0, stream>>>(q_buf, text_adj, at, tgf);
  image_gat_kernel<<<dim3(H, B), 256, 0, stream>>>(k_buf, image_adj, ai, igf);
  final_kernel<<<B, 256, 0, stream>>>(tgf, igf, clip_t, clip_i, lscale, stok, ftok,
                                      Wp, bp, f1w, f1b, f2w, f2b, c1w, c1b, c2w, c2b, out);
}

// Round 2
// 907.938 us; speedup vs baseline: 1.5891x; 1.5891x over previous
//
#include <hip/hip_runtime.h>
#include <hip/hip_bf16.h>
#include <math.h>

// Problem constants
#define B 32
#define T 64
#define P 196
#define D 768
#define H 12

typedef __attribute__((ext_vector_type(8))) short short8;
typedef __attribute__((ext_vector_type(4))) float floatx4;

// ---------------- helpers ----------------
__device__ __forceinline__ float wave_sum(float v) {
#pragma unroll
  for (int o = 32; o > 0; o >>= 1) v += __shfl_xor(v, o);
  return v;
}
__device__ __forceinline__ float wave_max(float v) {
#pragma unroll
  for (int o = 32; o > 0; o >>= 1) v = fmaxf(v, __shfl_xor(v, o));
  return v;
}
__device__ __forceinline__ unsigned short f2bf(float x) {
  unsigned u = __float_as_uint(x);
  u += 0x7FFFu + ((u >> 16) & 1u);   // round-to-nearest-even
  return (unsigned short)(u >> 16);
}
__device__ __forceinline__ float bflo2f(unsigned u) { return __uint_as_float(u << 16); }
__device__ __forceinline__ float bfhi2f(unsigned u) { return __uint_as_float(u & 0xFFFF0000u); }

// ---------------- cast kernels ----------------
__global__ __launch_bounds__(256) void cast_rows(const float* __restrict__ X,
                                                 unsigned short* __restrict__ Y, int n4) {
  int i = blockIdx.x * 256 + threadIdx.x;
  if (i < n4) {
    float4 vv = ((const float4*)X)[i];
    ushort4 o;
    o.x = f2bf(vv.x); o.y = f2bf(vv.y); o.z = f2bf(vv.z); o.w = f2bf(vv.w);
    ((ushort4*)Y)[i] = o;
  }
}

// W fp32 [K][N] -> Wt bf16 [N][K]
__global__ __launch_bounds__(256) void cast_transpose(const float* __restrict__ W,
                                                      unsigned short* __restrict__ Wt,
                                                      int K, int N) {
  __shared__ float tile[32][33];
  const int tx = threadIdx.x & 31, ty = threadIdx.x >> 5;  // ty 0..7
  const int n0 = blockIdx.x * 32, k0 = blockIdx.y * 32;
#pragma unroll
  for (int r = 0; r < 4; ++r)
    tile[ty + 8 * r][tx] = W[(size_t)(k0 + ty + 8 * r) * N + n0 + tx];
  __syncthreads();
#pragma unroll
  for (int r = 0; r < 4; ++r)
    Wt[(size_t)(n0 + ty + 8 * r) * K + k0 + tx] = f2bf(tile[tx][ty + 8 * r]);
}

// ---------------- bf16 MFMA GEMM: C[M,N] = A[M,K] @ Bt[N,K]^T (+bias) ----------------
// 128x128 tile, 256 threads (4 waves, each 64x64 via 4x4 grid of 16x16x32 MFMAs).
// M%128==0, N%128==0, K%32==0.
__global__ __launch_bounds__(256) void gemm_mfma(
    const unsigned short* __restrict__ A,   // [M][K] bf16
    const unsigned short* __restrict__ Bt,  // [N][K] bf16 (= W^T)
    const float* __restrict__ bias, float* __restrict__ C,
    int M, int N, int K) {
  __shared__ unsigned short As[128][40];  // stride 40 shorts = 80 B (16B-aligned rows)
  __shared__ unsigned short Bs[128][40];
  const int tid = threadIdx.x;
  const int lane = tid & 63;
  const int w = tid >> 6;
  const int quad = lane >> 4;
  const int l15 = lane & 15;
  const int row0 = blockIdx.y * 128;
  const int col0 = blockIdx.x * 128;
  const int m_off = (w & 1) * 64;
  const int n_off = (w >> 1) * 64;
  const int lr = tid >> 2;        // 0..63
  const int lc = (tid & 3) * 8;   // 0,8,16,24

  floatx4 acc[4][4] = {};

  for (int k0 = 0; k0 < K; k0 += 32) {
    const uint4 a0 = *(const uint4*)(A + (size_t)(row0 + lr) * K + k0 + lc);
    const uint4 a1 = *(const uint4*)(A + (size_t)(row0 + lr + 64) * K + k0 + lc);
    const uint4 b0 = *(const uint4*)(Bt + (size_t)(col0 + lr) * K + k0 + lc);
    const uint4 b1 = *(const uint4*)(Bt + (size_t)(col0 + lr + 64) * K + k0 + lc);
    __syncthreads();  // previous iteration's reads complete
    *(uint4*)&As[lr][lc] = a0;
    *(uint4*)&As[lr + 64][lc] = a1;
    *(uint4*)&Bs[lr][lc] = b0;
    *(uint4*)&Bs[lr + 64][lc] = b1;
    __syncthreads();
    short8 af[4], bfr[4];
#pragma unroll
    for (int i = 0; i < 4; ++i)
      af[i] = *(const short8*)&As[m_off + 16 * i + l15][quad * 8];
#pragma unroll
    for (int j = 0; j < 4; ++j)
      bfr[j] = *(const short8*)&Bs[n_off + 16 * j + l15][quad * 8];
#pragma unroll
    for (int i = 0; i < 4; ++i)
#pragma unroll
      for (int j = 0; j < 4; ++j)
        acc[i][j] = __builtin_amdgcn_mfma_f32_16x16x32_bf16(af[i], bfr[j], acc[i][j], 0, 0, 0);
  }

#pragma unroll
  for (int j = 0; j < 4; ++j) {
    const int cg = col0 + n_off + 16 * j + l15;
    const float bv = bias ? bias[cg] : 0.0f;
#pragma unroll
    for (int i = 0; i < 4; ++i) {
      const int rbase = row0 + m_off + 16 * i + quad * 4;
#pragma unroll
      for (int r = 0; r < 4; ++r)
        C[(size_t)(rbase + r) * N + cg] = acc[i][j][r] + bv;  // C/D: col=lane&15, row=quad*4+reg
    }
  }
}

// ---------------- cross attention v2: one block per (b,h) ----------------
// q,k,v fp32; output bf16 (feeds wo GEMM). K,V staged once as bf16 in LDS.
__global__ __launch_bounds__(256) void cross_attn2(
    const float* __restrict__ q, const float* __restrict__ k,
    const float* __restrict__ v, unsigned short* __restrict__ attout) {
  const int h = blockIdx.x, b = blockIdx.y;
  const int tid = threadIdx.x, lane = tid & 63, w = tid >> 6;
  __shared__ unsigned short Kt[64][202];  // Kt[d][p], 101-word row stride (conflict-free both ways)
  __shared__ unsigned short Vt[64][202];  // Vt[d][p]

  for (int i = tid; i < P * 64; i += 256) {
    int p = i >> 6, d = i & 63;  // lanes: consecutive d -> coalesced global reads
    Kt[d][p] = f2bf(k[((size_t)(b * P + p)) * D + h * 64 + d]);
    Vt[d][p] = f2bf(v[((size_t)(b * P + p)) * D + h * 64 + d]);
  }
  __syncthreads();

  const int pA = 2 * lane;                                 // keys pA, pA+1 (<128)
  const bool hasB = (lane < 34);                           // 128..195 = 68 keys = 34 pairs
  const int pB = hasB ? (128 + 2 * lane) : 0;

  for (int qi = 0; qi < 16; ++qi) {
    const int t = w * 16 + qi;
    const float qreg = q[((size_t)(b * T + t)) * D + h * 64 + lane];
    float a0 = 0.f, a1 = 0.f, a2 = 0.f, a3 = 0.f;
#pragma unroll 8
    for (int d = 0; d < 64; ++d) {
      const float qd = __shfl(qreg, d);
      const unsigned uA = *(const unsigned*)&Kt[d][pA];
      const unsigned uB = *(const unsigned*)&Kt[d][pB];
      a0 += qd * bflo2f(uA);
      a1 += qd * bfhi2f(uA);
      a2 += qd * bflo2f(uB);
      a3 += qd * bfhi2f(uB);
    }
    float s0 = a0 * 0.125f, s1 = a1 * 0.125f;
    float s2 = hasB ? a2 * 0.125f : -3.4e38f;
    float s3 = hasB ? a3 * 0.125f : -3.4e38f;
    const float m = wave_max(fmaxf(fmaxf(s0, s1), fmaxf(s2, s3)));
    float e0 = expf(s0 - m), e1 = expf(s1 - m);
    float e2 = hasB ? expf(s2 - m) : 0.f;
    float e3 = hasB ? expf(s3 - m) : 0.f;
    const float inv = 1.0f / wave_sum(e0 + e1 + e2 + e3);
    e0 *= inv; e1 *= inv; e2 *= inv; e3 *= inv;

    // out[t][d=lane] = sum_p prob[p] * V[p][lane]  (Vt[lane][p])
    float acc = 0.f;
#pragma unroll 8
    for (int pp = 0; pp < 64; ++pp) {
      const unsigned uv = *(const unsigned*)&Vt[lane][2 * pp];
      acc += __shfl(e0, pp) * bflo2f(uv) + __shfl(e1, pp) * bfhi2f(uv);
    }
#pragma unroll 2
    for (int pp = 0; pp < 34; ++pp) {
      const unsigned uv = *(const unsigned*)&Vt[lane][128 + 2 * pp];
      acc += __shfl(e2, pp) * bflo2f(uv) + __shfl(e3, pp) * bfhi2f(uv);
    }
    attout[((size_t)(b * T + t)) * D + h * 64 + lane] = f2bf(acc);
  }
}

// ---------------- s_token + f_token ----------------
__global__ __launch_bounds__(256) void token_kernel(
    const float* __restrict__ upd, const float* __restrict__ img,
    float* __restrict__ f_token, float* __restrict__ s_token) {
  const int b = blockIdx.x, tid = threadIdx.x;
  for (int d = tid; d < D; d += 256) {
    float s = 0.f;
    for (int t = 0; t < T; ++t) s += upd[((size_t)(b * T + t)) * D + d];
    f_token[b * D + d] = s * (1.0f / T);
  }
  float part = 0.f;
  for (int idx = tid; idx < T * D; idx += 256) {
    int t = idx / D, d = idx - t * D;
    part += upd[((size_t)(b * T + t)) * D + d] * img[((size_t)(b * P + t)) * D + d];
  }
  part = wave_sum(part);
  __shared__ float red[4];
  if ((tid & 63) == 0) red[tid >> 6] = part;
  __syncthreads();
  if (tid == 0) s_token[b] = (red[0] + red[1] + red[2] + red[3]) * (1.0f / T);
}

// ---------------- text GAT: one wave per (b,h). N=64 nodes ----------------
__global__ __launch_bounds__(64) void text_gat_kernel(
    const float* __restrict__ Wh, const int* __restrict__ adj,
    const float* __restrict__ at, float* __restrict__ tgf) {
  const int h = blockIdx.x, b = blockIdx.y;
  const int lane = threadIdx.x;
  __shared__ float Whs[64][65];
  __shared__ float srcs[64], dsts[64];

  for (int n = 0; n < 64; ++n)
    Whs[n][lane] = Wh[((size_t)(b * T + n)) * D + h * 64 + lane];
  float a_s = at[lane];
  float a_d = at[64 + lane];
  __syncthreads();

  float s = 0.f, dd = 0.f;
#pragma unroll 8
  for (int f = 0; f < 64; ++f) {
    float w = Whs[lane][f];
    s += w * __shfl(a_s, f);
    dd += w * __shfl(a_d, f);
  }
  srcs[lane] = s;
  dsts[lane] = dd;
  __syncthreads();

  const int* adjb = adj + b * T * T;
  float macc = 0.f;
  for (int i = 0; i < 64; ++i) {
    float e = srcs[i] + dsts[lane];
    e = (e >= 0.f) ? e : 0.2f * e;
    if (adjb[i * 64 + lane] == 0) e = -9e15f;
    float m = wave_max(e);
    float pp = expf(e - m);
    float ssum = wave_sum(pp);
    float att = pp / ssum;
    float hp = 0.f;
#pragma unroll 8
    for (int j = 0; j < 64; ++j) hp += __shfl(att, j) * Whs[j][lane];
    macc += (hp > 0.f) ? hp : (expf(hp) - 1.0f);
  }
  tgf[b * D + h * 64 + lane] = macc * (1.0f / T);
}

// ---------------- image GAT: one 256-thread block per (b,h). N=196 ----------------
__global__ __launch_bounds__(256) void image_gat_kernel(
    const float* __restrict__ Wh, const int* __restrict__ adj,
    const float* __restrict__ ai, float* __restrict__ igf) {
  const int h = blockIdx.x, b = blockIdx.y;
  const int tid = threadIdx.x, lane = tid & 63, w = tid >> 6;
  __shared__ float Whs[196][65];
  __shared__ float srcs[196], dsts[196];
  __shared__ float atts[4][196];
  __shared__ float redc[4][64];
  __shared__ float asv[64], adv[64];

  if (tid < 64) { asv[tid] = ai[tid]; adv[tid] = ai[64 + tid]; }
  for (int idx = tid; idx < P * 64; idx += 256) {
    int n = idx >> 6, f = idx & 63;
    Whs[n][f] = Wh[((size_t)(b * P + n)) * D + h * 64 + f];
  }
  __syncthreads();

  for (int n = tid; n < P; n += 256) {
    float s = 0.f, dd = 0.f;
#pragma unroll 8
    for (int f = 0; f < 64; ++f) {
      float wv = Whs[n][f];
      s += wv * asv[f];
      dd += wv * adv[f];
    }
    srcs[n] = s;
    dsts[n] = dd;
  }
  __syncthreads();

  float macc = 0.f;
  for (int i0 = 0; i0 < 49; ++i0) {
    int i = i0 * 4 + w;
    float e0, e1, e2, e3;
    {
      float si = srcs[i];
      float x;
      x = si + dsts[lane];        e0 = (x >= 0.f) ? x : 0.2f * x;
      x = si + dsts[lane + 64];   e1 = (x >= 0.f) ? x : 0.2f * x;
      x = si + dsts[lane + 128];  e2 = (x >= 0.f) ? x : 0.2f * x;
      if (lane < 4) { x = si + dsts[lane + 192]; e3 = (x >= 0.f) ? x : 0.2f * x; }
      else e3 = -3.4e38f;
      const int* ar = adj + i * P;
      if (ar[lane] == 0) e0 = -9e15f;
      if (ar[lane + 64] == 0) e1 = -9e15f;
      if (ar[lane + 128] == 0) e2 = -9e15f;
      if (lane < 4 && ar[lane + 192] == 0) e3 = -9e15f;
    }
    float m = wave_max(fmaxf(fmaxf(e0, e1), fmaxf(e2, e3)));
    float p0e = expf(e0 - m), p1e = expf(e1 - m), p2e = expf(e2 - m);
    float p3e = (lane < 4) ? expf(e3 - m) : 0.f;
    float ssum = wave_sum(p0e + p1e + p2e + p3e);
    float inv = 1.0f / ssum;
    atts[w][lane] = p0e * inv;
    atts[w][lane + 64] = p1e * inv;
    atts[w][lane + 128] = p2e * inv;
    if (lane < 4) atts[w][lane + 192] = p3e * inv;
    __syncthreads();
    float hp = 0.f;
#pragma unroll 4
    for (int j = 0; j < P; ++j) hp += atts[w][j] * Whs[j][lane];
    macc += (hp > 0.f) ? hp : (expf(hp) - 1.0f);
    __syncthreads();
  }

  redc[w][lane] = macc;
  __syncthreads();
  if (w == 0) {
    float tot = redc[0][lane] + redc[1][lane] + redc[2][lane] + redc[3][lane];
    igf[b * D + h * 64 + lane] = tot * (1.0f / P);
  }
}

// ---------------- final fusion kernel: one block per b ----------------
__device__ __forceinline__ float block_sum(float v, float* red4) {
  v = wave_sum(v);
  __syncthreads();
  if ((threadIdx.x & 63) == 0) red4[threadIdx.x >> 6] = v;
  __syncthreads();
  return red4[0] + red4[1] + red4[2] + red4[3];
}

__global__ __launch_bounds__(256) void final_kernel(
    const float* __restrict__ tgf, const float* __restrict__ igf,
    const float* __restrict__ clip_t, const float* __restrict__ clip_i,
    const float* __restrict__ logit_scale, const float* __restrict__ s_token,
    const float* __restrict__ f_token,
    const float* __restrict__ Wp, const float* __restrict__ bp,
    const float* __restrict__ f1w, const float* __restrict__ f1b,
    const float* __restrict__ f2w, const float* __restrict__ f2b,
    const float* __restrict__ c1w, const float* __restrict__ c1b,
    const float* __restrict__ c2w, const float* __restrict__ c2b,
    float* __restrict__ out) {
  const int b = blockIdx.x, tid = threadIdx.x;
  __shared__ float red[4];
  __shared__ float sres[4];
  __shared__ float fagg[768];
  __shared__ float hid[384];

  float d0 = 0.f, d1 = 0.f, d2 = 0.f;
  for (int i = tid; i < D; i += 256) {
    float x = tgf[b * D + i], y = igf[b * D + i];
    d0 += x * y; d1 += x * x; d2 += y * y;
  }
  float dot_ti = block_sum(d0, red);
  float n_t = sqrtf(block_sum(d1, red));
  float n_i = sqrtf(block_sum(d2, red));
  float s_phrase = dot_ti / (fmaxf(n_t, 1e-8f) * fmaxf(n_i, 1e-8f));

  float c0 = 0.f, c1 = 0.f, c2 = 0.f;
  for (int i = tid; i < 512; i += 256) {
    float x = clip_t[b * 512 + i], y = clip_i[b * 512 + i];
    c0 += x * y; c1 += x * x; c2 += y * y;
  }
  float dc = block_sum(c0, red);
  float nt2 = sqrtf(block_sum(c1, red));
  float ni2 = sqrtf(block_sum(c2, red));
  float s_global = expf(logit_scale[0]) * dc / (fmaxf(nt2, 1e-8f) * fmaxf(ni2, 1e-8f));

  if (tid == 0) {
    float s3[3] = { s_token[b], s_phrase, s_global };
    float h1[16];
    for (int j = 0; j < 16; ++j) {
      float a = f1b[j];
      for (int i2 = 0; i2 < 3; ++i2) a += s3[i2] * f1w[i2 * 16 + j];
      h1[j] = 0.5f * a * (1.0f + erff(a * 0.70710678118654752f));
    }
    for (int j = 0; j < 3; ++j) {
      float a = f2b[j];
      for (int i2 = 0; i2 < 16; ++i2) a += h1[i2] * f2w[i2 * 3 + j];
      sres[j] = 1.0f / (1.0f + expf(-a));
    }
  }
  __syncthreads();
  float w0 = sres[0], w1 = sres[1], w2 = sres[2];

  for (int j = tid; j < D; j += 256) {
    float fg = bp[j];
    for (int k2 = 0; k2 < 512; ++k2) fg += clip_t[b * 512 + k2] * Wp[k2 * D + j];
    fagg[j] = w0 * f_token[b * D + j] + w1 * tgf[b * D + j] + w2 * fg;
  }
  __syncthreads();

  for (int j = tid; j < 384; j += 256) {
    float a = c1b[j];
    for (int k2 = 0; k2 < D; ++k2) a += fagg[k2] * c1w[k2 * 384 + j];
    hid[j] = fmaxf(a, 0.0f);
  }
  __syncthreads();

  float p0 = 0.f, p1 = 0.f;
  for (int k2 = tid; k2 < 384; k2 += 256) {
    p0 += hid[k2] * c2w[k2 * 2 + 0];
    p1 += hid[k2] * c2w[k2 * 2 + 1];
  }
  p0 = block_sum(p0, red);
  p1 = block_sum(p1, red);
  if (tid == 0) {
    out[b * 2 + 0] = p0 + c2b[0];
    out[b * 2 + 1] = p1 + c2b[1];
  }
}

// ---------------- launch ----------------
extern "C" void kernel_launch(void* const* d_in, const int* in_sizes, int n_in,
                              void* d_out, int out_size, void* d_ws, size_t ws_size,
                              hipStream_t stream) {
  const float* text   = (const float*)d_in[0];
  const float* img    = (const float*)d_in[1];
  const float* clip_t = (const float*)d_in[2];
  const float* clip_i = (const float*)d_in[3];
  const float* lscale = (const float*)d_in[4];
  const float* wq = (const float*)d_in[5];
  const float* bq = (const float*)d_in[6];
  const float* wk = (const float*)d_in[7];
  const float* bk = (const float*)d_in[8];
  const float* wv = (const float*)d_in[9];
  const float* bv = (const float*)d_in[10];
  const float* wo = (const float*)d_in[11];
  const float* bo = (const float*)d_in[12];
  const float* Wt = (const float*)d_in[13];
  const float* at = (const float*)d_in[14];
  const float* Wi = (const float*)d_in[15];
  const float* ai = (const float*)d_in[16];
  const float* Wp = (const float*)d_in[17];
  const float* bp = (const float*)d_in[18];
  const float* f1w = (const float*)d_in[19];
  const float* f1b = (const float*)d_in[20];
  const float* f2w = (const float*)d_in[21];
  const float* f2b = (const float*)d_in[22];
  const float* c1w = (const float*)d_in[23];
  const float* c1b = (const float*)d_in[24];
  const float* c2w = (const float*)d_in[25];
  const float* c2b = (const float*)d_in[26];
  const int* text_adj  = (const int*)d_in[27];
  const int* image_adj = (const int*)d_in[28];
  float* out = (float*)d_out;

  const size_t nTD = (size_t)B * T * D;   // 1,572,864
  const size_t nPD = (size_t)B * P * D;   // 4,816,896
  const size_t nWW = (size_t)D * D;       // 589,824

  // workspace layout: fp32 buffers first, then bf16 buffers
  float* fbuf = (float*)d_ws;
  size_t o = 0;
  float* k_buf = fbuf + o; o += nPD;   // k; reused as Wh_i after attention
  float* v_buf = fbuf + o; o += nPD;   // v
  float* q_buf = fbuf + o; o += nTD;   // q; reused as Wh_t after attention
  float* upd   = fbuf + o; o += nTD;
  float* ftok  = fbuf + o; o += (size_t)B * D;
  float* stok  = fbuf + o; o += 32;
  float* tgf   = fbuf + o; o += (size_t)B * D;
  float* igf   = fbuf + o; o += (size_t)B * D;
  unsigned short* sbuf = (unsigned short*)(fbuf + o);
  size_t so = 0;
  unsigned short* text_bf = sbuf + so; so += nTD;
  unsigned short* img_bf  = sbuf + so; so += nPD;
  unsigned short* att_bf  = sbuf + so; so += nTD;
  unsigned short* wq_t = sbuf + so; so += nWW;
  unsigned short* wk_t = sbuf + so; so += nWW;
  unsigned short* wv_t = sbuf + so; so += nWW;
  unsigned short* wo_t = sbuf + so; so += nWW;
  unsigned short* wt_t = sbuf + so; so += nWW;
  unsigned short* wi_t = sbuf + so; so += nWW;

  // ---- weight + activation casts ----
  dim3 ctg(D / 32, D / 32);
  cast_transpose<<<ctg, 256, 0, stream>>>(wq, wq_t, D, D);
  cast_transpose<<<ctg, 256, 0, stream>>>(wk, wk_t, D, D);
  cast_transpose<<<ctg, 256, 0, stream>>>(wv, wv_t, D, D);
  cast_transpose<<<ctg, 256, 0, stream>>>(wo, wo_t, D, D);
  cast_transpose<<<ctg, 256, 0, stream>>>(Wt, wt_t, D, D);
  cast_transpose<<<ctg, 256, 0, stream>>>(Wi, wi_t, D, D);
  cast_rows<<<(int)(nTD / 4 + 255) / 256, 256, 0, stream>>>(text, text_bf, (int)(nTD / 4));
  cast_rows<<<(int)(nPD / 4 + 255) / 256, 256, 0, stream>>>(img, img_bf, (int)(nPD / 4));

  const int MT = B * T;   // 2048
  const int MP = B * P;   // 6272

  // ---- projections (bf16 MFMA) ----
  gemm_mfma<<<dim3(D / 128, MT / 128), 256, 0, stream>>>(text_bf, wq_t, bq, q_buf, MT, D, D);
  gemm_mfma<<<dim3(D / 128, MP / 128), 256, 0, stream>>>(img_bf, wk_t, bk, k_buf, MP, D, D);
  gemm_mfma<<<dim3(D / 128, MP / 128), 256, 0, stream>>>(img_bf, wv_t, bv, v_buf, MP, D, D);

  // ---- attention (writes bf16 directly for wo GEMM) ----
  cross_attn2<<<dim3(H, B), 256, 0, stream>>>(q_buf, k_buf, v_buf, att_bf);

  gemm_mfma<<<dim3(D / 128, MT / 128), 256, 0, stream>>>(att_bf, wo_t, bo, upd, MT, D, D);
  // GAT projections (reuse q_buf for Wh_t, k_buf for Wh_i — attention is done with them)
  gemm_mfma<<<dim3(D / 128, MT / 128), 256, 0, stream>>>(text_bf, wt_t, nullptr, q_buf, MT, D, D);
  gemm_mfma<<<dim3(D / 128, MP / 128), 256, 0, stream>>>(img_bf, wi_t, nullptr, k_buf, MP, D, D);

  token_kernel<<<B, 256, 0, stream>>>(upd, img, ftok, stok);
  text_gat_kernel<<<dim3(H, B), 64, 0, stream>>>(q_buf, text_adj, at, tgf);
  image_gat_kernel<<<dim3(H, B), 256, 0, stream>>>(k_buf, image_adj, ai, igf);
  final_kernel<<<B, 256, 0, stream>>>(tgf, igf, clip_t, clip_i, lscale, stok, ftok,
                                      Wp, bp, f1w, f1b, f2w, f2b, c1w, c1b, c2w, c2b, out);
}

// Round 3
// 680.740 us; speedup vs baseline: 2.1194x; 1.3338x over previous
//
#include <hip/hip_runtime.h>
#include <hip/hip_bf16.h>
#include <math.h>

// Problem constants
#define B 32
#define T 64
#define P 196
#define D 768
#define H 12

typedef __attribute__((ext_vector_type(8))) short short8;
typedef __attribute__((ext_vector_type(4))) float floatx4;

// ---------------- helpers ----------------
__device__ __forceinline__ float wave_sum(float v) {
#pragma unroll
  for (int o = 32; o > 0; o >>= 1) v += __shfl_xor(v, o);
  return v;
}
__device__ __forceinline__ float wave_max(float v) {
#pragma unroll
  for (int o = 32; o > 0; o >>= 1) v = fmaxf(v, __shfl_xor(v, o));
  return v;
}
__device__ __forceinline__ unsigned short f2bf(float x) {
  unsigned u = __float_as_uint(x);
  u += 0x7FFFu + ((u >> 16) & 1u);   // round-to-nearest-even
  return (unsigned short)(u >> 16);
}
__device__ __forceinline__ float bflo2f(unsigned u) { return __uint_as_float(u << 16); }
__device__ __forceinline__ float bfhi2f(unsigned u) { return __uint_as_float(u & 0xFFFF0000u); }

// ---------------- cast kernels ----------------
__global__ __launch_bounds__(256) void cast_rows(const float* __restrict__ X,
                                                 unsigned short* __restrict__ Y, int n4) {
  int i = blockIdx.x * 256 + threadIdx.x;
  if (i < n4) {
    float4 vv = ((const float4*)X)[i];
    ushort4 o;
    o.x = f2bf(vv.x); o.y = f2bf(vv.y); o.z = f2bf(vv.z); o.w = f2bf(vv.w);
    ((ushort4*)Y)[i] = o;
  }
}

// 6 weights fp32 [K][N] -> bf16 [N][K], one fused launch (grid.z = weight idx)
struct WPack {
  const float* src[6];
  unsigned short* dst[6];
};
__global__ __launch_bounds__(256) void cast_transpose6(WPack p, int K, int N) {
  __shared__ float tile[32][33];
  const float* W = p.src[blockIdx.z];
  unsigned short* Wt = p.dst[blockIdx.z];
  const int tx = threadIdx.x & 31, ty = threadIdx.x >> 5;  // ty 0..7
  const int n0 = blockIdx.x * 32, k0 = blockIdx.y * 32;
#pragma unroll
  for (int r = 0; r < 4; ++r)
    tile[ty + 8 * r][tx] = W[(size_t)(k0 + ty + 8 * r) * N + n0 + tx];
  __syncthreads();
#pragma unroll
  for (int r = 0; r < 4; ++r)
    Wt[(size_t)(n0 + ty + 8 * r) * K + k0 + tx] = f2bf(tile[tx][ty + 8 * r]);
}

// concat biases: bt = [bq, 0], bi = [bk, bv]
__global__ __launch_bounds__(256) void build_bias(const float* __restrict__ bq,
                                                  const float* __restrict__ bk,
                                                  const float* __restrict__ bv,
                                                  float* __restrict__ bt,
                                                  float* __restrict__ bi) {
  int i = blockIdx.x * 256 + threadIdx.x;
  if (i < 768) { bt[i] = bq[i]; bi[i] = bk[i]; }
  else if (i < 1536) { bt[i] = 0.f; bi[i] = bv[i - 768]; }
}

// ---------------- bf16 MFMA GEMM: C[M,N] = A[M,K] @ Bt[N,K]^T (+bias) ----------------
// 128x128 tile, 256 threads (4 waves, each 64x64 via 4x4 grid of 16x16x32 MFMAs).
__global__ __launch_bounds__(256) void gemm_mfma(
    const unsigned short* __restrict__ A,   // [M][K] bf16
    const unsigned short* __restrict__ Bt,  // [N][K] bf16 (= W^T)
    const float* __restrict__ bias, float* __restrict__ C,
    int M, int N, int K) {
  __shared__ unsigned short As[128][40];
  __shared__ unsigned short Bs[128][40];
  const int tid = threadIdx.x;
  const int lane = tid & 63;
  const int w = tid >> 6;
  const int quad = lane >> 4;
  const int l15 = lane & 15;
  const int row0 = blockIdx.y * 128;
  const int col0 = blockIdx.x * 128;
  const int m_off = (w & 1) * 64;
  const int n_off = (w >> 1) * 64;
  const int lr = tid >> 2;
  const int lc = (tid & 3) * 8;

  floatx4 acc[4][4] = {};

  for (int k0 = 0; k0 < K; k0 += 32) {
    const uint4 a0 = *(const uint4*)(A + (size_t)(row0 + lr) * K + k0 + lc);
    const uint4 a1 = *(const uint4*)(A + (size_t)(row0 + lr + 64) * K + k0 + lc);
    const uint4 b0 = *(const uint4*)(Bt + (size_t)(col0 + lr) * K + k0 + lc);
    const uint4 b1 = *(const uint4*)(Bt + (size_t)(col0 + lr + 64) * K + k0 + lc);
    __syncthreads();
    *(uint4*)&As[lr][lc] = a0;
    *(uint4*)&As[lr + 64][lc] = a1;
    *(uint4*)&Bs[lr][lc] = b0;
    *(uint4*)&Bs[lr + 64][lc] = b1;
    __syncthreads();
    short8 af[4], bfr[4];
#pragma unroll
    for (int i = 0; i < 4; ++i)
      af[i] = *(const short8*)&As[m_off + 16 * i + l15][quad * 8];
#pragma unroll
    for (int j = 0; j < 4; ++j)
      bfr[j] = *(const short8*)&Bs[n_off + 16 * j + l15][quad * 8];
#pragma unroll
    for (int i = 0; i < 4; ++i)
#pragma unroll
      for (int j = 0; j < 4; ++j)
        acc[i][j] = __builtin_amdgcn_mfma_f32_16x16x32_bf16(af[i], bfr[j], acc[i][j], 0, 0, 0);
  }

#pragma unroll
  for (int j = 0; j < 4; ++j) {
    const int cg = col0 + n_off + 16 * j + l15;
    const float bv = bias ? bias[cg] : 0.0f;
#pragma unroll
    for (int i = 0; i < 4; ++i) {
      const int rbase = row0 + m_off + 16 * i + quad * 4;
#pragma unroll
      for (int r = 0; r < 4; ++r)
        C[(size_t)(rbase + r) * N + cg] = acc[i][j][r] + bv;
    }
  }
}

// ---------------- cross attention: one block per (b,h) ----------------
// qa: [B*T][1536] (q in cols 0..767). kv: [B*P][1536] (k cols 0..767, v cols 768..1535).
__global__ __launch_bounds__(256) void cross_attn2(
    const float* __restrict__ qa, const float* __restrict__ kv,
    unsigned short* __restrict__ attout) {
  const int h = blockIdx.x, b = blockIdx.y;
  const int tid = threadIdx.x, lane = tid & 63, w = tid >> 6;
  __shared__ unsigned short Kt[64][202];
  __shared__ unsigned short Vt[64][202];

  for (int i = tid; i < P * 64; i += 256) {
    int p = i >> 6, d = i & 63;
    const float* row = kv + ((size_t)(b * P + p)) * 1536 + h * 64 + d;
    Kt[d][p] = f2bf(row[0]);
    Vt[d][p] = f2bf(row[768]);
  }
  __syncthreads();

  const int pA = 2 * lane;
  const bool hasB = (lane < 34);
  const int pB = hasB ? (128 + 2 * lane) : 0;

  for (int qi = 0; qi < 16; ++qi) {
    const int t = w * 16 + qi;
    const float qreg = qa[((size_t)(b * T + t)) * 1536 + h * 64 + lane];
    float a0 = 0.f, a1 = 0.f, a2 = 0.f, a3 = 0.f;
#pragma unroll 8
    for (int d = 0; d < 64; ++d) {
      const float qd = __shfl(qreg, d);
      const unsigned uA = *(const unsigned*)&Kt[d][pA];
      const unsigned uB = *(const unsigned*)&Kt[d][pB];
      a0 += qd * bflo2f(uA);
      a1 += qd * bfhi2f(uA);
      a2 += qd * bflo2f(uB);
      a3 += qd * bfhi2f(uB);
    }
    float s0 = a0 * 0.125f, s1 = a1 * 0.125f;
    float s2 = hasB ? a2 * 0.125f : -3.4e38f;
    float s3 = hasB ? a3 * 0.125f : -3.4e38f;
    const float m = wave_max(fmaxf(fmaxf(s0, s1), fmaxf(s2, s3)));
    float e0 = expf(s0 - m), e1 = expf(s1 - m);
    float e2 = hasB ? expf(s2 - m) : 0.f;
    float e3 = hasB ? expf(s3 - m) : 0.f;
    const float inv = 1.0f / wave_sum(e0 + e1 + e2 + e3);
    e0 *= inv; e1 *= inv; e2 *= inv; e3 *= inv;

    float acc = 0.f;
#pragma unroll 8
    for (int pp = 0; pp < 64; ++pp) {
      const unsigned uv = *(const unsigned*)&Vt[lane][2 * pp];
      acc += __shfl(e0, pp) * bflo2f(uv) + __shfl(e1, pp) * bfhi2f(uv);
    }
#pragma unroll 2
    for (int pp = 0; pp < 34; ++pp) {
      const unsigned uv = *(const unsigned*)&Vt[lane][128 + 2 * pp];
      acc += __shfl(e2, pp) * bflo2f(uv) + __shfl(e3, pp) * bfhi2f(uv);
    }
    attout[((size_t)(b * T + t)) * D + h * 64 + lane] = f2bf(acc);
  }
}

// ---------------- s_token + f_token ----------------
__global__ __launch_bounds__(256) void token_kernel(
    const float* __restrict__ upd, const float* __restrict__ img,
    float* __restrict__ f_token, float* __restrict__ s_token) {
  const int b = blockIdx.x, tid = threadIdx.x;
  for (int d = tid; d < D; d += 256) {
    float s = 0.f;
    for (int t = 0; t < T; ++t) s += upd[((size_t)(b * T + t)) * D + d];
    f_token[b * D + d] = s * (1.0f / T);
  }
  float part = 0.f;
  for (int idx = tid; idx < T * D; idx += 256) {
    int t = idx / D, d = idx - t * D;
    part += upd[((size_t)(b * T + t)) * D + d] * img[((size_t)(b * P + t)) * D + d];
  }
  part = wave_sum(part);
  __shared__ float red[4];
  if ((tid & 63) == 0) red[tid >> 6] = part;
  __syncthreads();
  if (tid == 0) s_token[b] = (red[0] + red[1] + red[2] + red[3]) * (1.0f / T);
}

// ---------------- text GAT v2: one block (2 waves) per (b,h). N=64 ----------------
// Wh base pointer with row stride ldw. Each wave owns 32 rows; groups of 8.
__global__ __launch_bounds__(128) void text_gat_kernel(
    const float* __restrict__ Wh, int ldw, const int* __restrict__ adj,
    const float* __restrict__ at, float* __restrict__ tgf) {
  const int h = blockIdx.x, b = blockIdx.y;
  const int tid = threadIdx.x, lane = tid & 63, w = tid >> 6;
  __shared__ float WhT[64][68];       // WhT[f][n]
  __shared__ float atts[2][8][68];
  __shared__ float srcs[64], dsts[64];
  __shared__ float redc[2][64];
  __shared__ float asv[64], adv[64];

  if (tid < 64) { asv[tid] = at[tid]; adv[tid] = at[64 + tid]; }
  for (int idx = tid; idx < 64 * 64; idx += 128) {
    int n = idx >> 6, f = idx & 63;
    WhT[f][n] = Wh[(size_t)(b * T + n) * ldw + h * 64 + f];
  }
  __syncthreads();

  if (tid < 64) {
    float s = 0.f, dd = 0.f;
#pragma unroll 8
    for (int f = 0; f < 64; ++f) {
      float wv = WhT[f][tid];
      s += wv * asv[f];
      dd += wv * adv[f];
    }
    srcs[tid] = s;
    dsts[tid] = dd;
  }
  __syncthreads();

  const int* adjb = adj + b * T * T;
  float macc = 0.f;
  for (int g = 0; g < 4; ++g) {
    // phase A: softmax for 8 rows -> atts[w]
#pragma unroll
    for (int r = 0; r < 8; ++r) {
      const int i = w * 32 + g * 8 + r;
      float e = srcs[i] + dsts[lane];
      e = (e >= 0.f) ? e : 0.2f * e;
      if (adjb[i * 64 + lane] == 0) e = -9e15f;
      const float m = wave_max(e);
      float pp = expf(e - m);
      const float inv = 1.0f / wave_sum(pp);
      atts[w][r][lane] = pp * inv;
    }
    // phase B: hp[i][lane] = sum_j att[i][j] * Wh[j][lane]
    float acc[8] = {};
    for (int jq = 0; jq < 16; ++jq) {
      const float4 whv = *(const float4*)&WhT[lane][4 * jq];
#pragma unroll
      for (int r = 0; r < 8; ++r) {
        const float4 av = *(const float4*)&atts[w][r][4 * jq];
        acc[r] += av.x * whv.x + av.y * whv.y + av.z * whv.z + av.w * whv.w;
      }
    }
#pragma unroll
    for (int r = 0; r < 8; ++r)
      macc += (acc[r] > 0.f) ? acc[r] : (expf(acc[r]) - 1.0f);
  }

  redc[w][lane] = macc;
  __syncthreads();
  if (w == 0)
    tgf[b * D + h * 64 + lane] = (redc[0][lane] + redc[1][lane]) * (1.0f / T);
}

// ---------------- image GAT v2: one block (4 waves) per (b,h). N=196 ----------------
// Each wave owns 49 rows; groups of 7. No barriers in the main loop.
__global__ __launch_bounds__(256) void image_gat_kernel(
    const float* __restrict__ Wh, int ldw, const int* __restrict__ adj,
    const float* __restrict__ ai, float* __restrict__ igf) {
  const int h = blockIdx.x, b = blockIdx.y;
  const int tid = threadIdx.x, lane = tid & 63, w = tid >> 6;
  __shared__ float WhT[64][204];      // WhT[f][n]; stride 204 words: b128 reads cover banks uniformly
  __shared__ float atts[4][7][204];
  __shared__ float srcs[196], dsts[196];
  __shared__ float redc[4][64];
  __shared__ float asv[64], adv[64];

  if (tid < 64) { asv[tid] = ai[tid]; adv[tid] = ai[64 + tid]; }
  for (int idx = tid; idx < P * 64; idx += 256) {
    int n = idx >> 6, f = idx & 63;
    WhT[f][n] = Wh[(size_t)(b * P + n) * ldw + h * 64 + f];
  }
  __syncthreads();

  for (int n = tid; n < P; n += 256) {
    float s = 0.f, dd = 0.f;
#pragma unroll 8
    for (int f = 0; f < 64; ++f) {
      float wv = WhT[f][n];
      s += wv * asv[f];
      dd += wv * adv[f];
    }
    srcs[n] = s;
    dsts[n] = dd;
  }
  __syncthreads();

  float macc = 0.f;
  for (int g = 0; g < 7; ++g) {
    // phase A: softmax for 7 rows -> atts[w]
#pragma unroll
    for (int r = 0; r < 7; ++r) {
      const int i = w * 49 + g * 7 + r;
      const float si = srcs[i];
      const int* ar = adj + i * P;
      float x, e0, e1, e2, e3;
      x = si + dsts[lane];        e0 = (x >= 0.f) ? x : 0.2f * x;
      x = si + dsts[lane + 64];   e1 = (x >= 0.f) ? x : 0.2f * x;
      x = si + dsts[lane + 128];  e2 = (x >= 0.f) ? x : 0.2f * x;
      if (lane < 4) { x = si + dsts[lane + 192]; e3 = (x >= 0.f) ? x : 0.2f * x; }
      else e3 = -3.4e38f;
      if (ar[lane] == 0) e0 = -9e15f;
      if (ar[lane + 64] == 0) e1 = -9e15f;
      if (ar[lane + 128] == 0) e2 = -9e15f;
      if (lane < 4 && ar[lane + 192] == 0) e3 = -9e15f;
      const float m = wave_max(fmaxf(fmaxf(e0, e1), fmaxf(e2, e3)));
      float p0e = expf(e0 - m), p1e = expf(e1 - m), p2e = expf(e2 - m);
      float p3e = (lane < 4) ? expf(e3 - m) : 0.f;
      const float inv = 1.0f / wave_sum(p0e + p1e + p2e + p3e);
      atts[w][r][lane] = p0e * inv;
      atts[w][r][lane + 64] = p1e * inv;
      atts[w][r][lane + 128] = p2e * inv;
      if (lane < 4) atts[w][r][lane + 192] = p3e * inv;
    }
    // phase B: hp[i][lane] = sum_j att[i][j] * Wh[j][lane]
    float acc[7] = {};
    for (int jq = 0; jq < 49; ++jq) {
      const float4 whv = *(const float4*)&WhT[lane][4 * jq];
#pragma unroll
      for (int r = 0; r < 7; ++r) {
        const float4 av = *(const float4*)&atts[w][r][4 * jq];
        acc[r] += av.x * whv.x + av.y * whv.y + av.z * whv.z + av.w * whv.w;
      }
    }
#pragma unroll
    for (int r = 0; r < 7; ++r)
      macc += (acc[r] > 0.f) ? acc[r] : (expf(acc[r]) - 1.0f);
  }

  redc[w][lane] = macc;
  __syncthreads();
  if (w == 0) {
    float tot = redc[0][lane] + redc[1][lane] + redc[2][lane] + redc[3][lane];
    igf[b * D + h * 64 + lane] = tot * (1.0f / P);
  }
}

// ---------------- f_global = clip_t @ Wp + bp : grid (12, B) ----------------
__global__ __launch_bounds__(256) void fglob_kernel(
    const float* __restrict__ clip_t, const float* __restrict__ Wp,
    const float* __restrict__ bp, float* __restrict__ fglob) {
  const int jt = blockIdx.x, b = blockIdx.y;
  const int j = threadIdx.x & 63, kc = threadIdx.x >> 6;
  float s = 0.f;
  const float* ct = clip_t + b * 512;
#pragma unroll 4
  for (int k = kc * 128; k < kc * 128 + 128; ++k)
    s += ct[k] * Wp[(size_t)k * D + jt * 64 + j];
  __shared__ float red[4][64];
  red[kc][j] = s;
  __syncthreads();
  if (kc == 0)
    fglob[b * D + jt * 64 + j] = red[0][j] + red[1][j] + red[2][j] + red[3][j] + bp[jt * 64 + j];
}

// ---------------- final fusion kernel: one block per b ----------------
__device__ __forceinline__ float block_sum(float v, float* red4) {
  v = wave_sum(v);
  __syncthreads();
  if ((threadIdx.x & 63) == 0) red4[threadIdx.x >> 6] = v;
  __syncthreads();
  return red4[0] + red4[1] + red4[2] + red4[3];
}

__global__ __launch_bounds__(256) void final_kernel(
    const float* __restrict__ tgf, const float* __restrict__ igf,
    const float* __restrict__ clip_t, const float* __restrict__ clip_i,
    const float* __restrict__ logit_scale, const float* __restrict__ s_token,
    const float* __restrict__ f_token, const float* __restrict__ fglob,
    const float* __restrict__ f1w, const float* __restrict__ f1b,
    const float* __restrict__ f2w, const float* __restrict__ f2b,
    const float* __restrict__ c1w, const float* __restrict__ c1b,
    const float* __restrict__ c2w, const float* __restrict__ c2b,
    float* __restrict__ out) {
  const int b = blockIdx.x, tid = threadIdx.x;
  __shared__ float red[4];
  __shared__ float sres[4];
  __shared__ float fagg[768];
  __shared__ float hid[384];

  float d0 = 0.f, d1 = 0.f, d2 = 0.f;
  for (int i = tid; i < D; i += 256) {
    float x = tgf[b * D + i], y = igf[b * D + i];
    d0 += x * y; d1 += x * x; d2 += y * y;
  }
  float dot_ti = block_sum(d0, red);
  float n_t = sqrtf(block_sum(d1, red));
  float n_i = sqrtf(block_sum(d2, red));
  float s_phrase = dot_ti / (fmaxf(n_t, 1e-8f) * fmaxf(n_i, 1e-8f));

  float c0 = 0.f, c1 = 0.f, c2 = 0.f;
  for (int i = tid; i < 512; i += 256) {
    float x = clip_t[b * 512 + i], y = clip_i[b * 512 + i];
    c0 += x * y; c1 += x * x; c2 += y * y;
  }
  float dc = block_sum(c0, red);
  float nt2 = sqrtf(block_sum(c1, red));
  float ni2 = sqrtf(block_sum(c2, red));
  float s_global = expf(logit_scale[0]) * dc / (fmaxf(nt2, 1e-8f) * fmaxf(ni2, 1e-8f));

  if (tid == 0) {
    float s3[3] = { s_token[b], s_phrase, s_global };
    float h1[16];
    for (int j = 0; j < 16; ++j) {
      float a = f1b[j];
      for (int i2 = 0; i2 < 3; ++i2) a += s3[i2] * f1w[i2 * 16 + j];
      h1[j] = 0.5f * a * (1.0f + erff(a * 0.70710678118654752f));
    }
    for (int j = 0; j < 3; ++j) {
      float a = f2b[j];
      for (int i2 = 0; i2 < 16; ++i2) a += h1[i2] * f2w[i2 * 3 + j];
      sres[j] = 1.0f / (1.0f + expf(-a));
    }
  }
  __syncthreads();
  float w0 = sres[0], w1 = sres[1], w2 = sres[2];

  for (int j = tid; j < D; j += 256)
    fagg[j] = w0 * f_token[b * D + j] + w1 * tgf[b * D + j] + w2 * fglob[b * D + j];
  __syncthreads();

  for (int j = tid; j < 384; j += 256) {
    float a = c1b[j];
    for (int k2 = 0; k2 < D; ++k2) a += fagg[k2] * c1w[k2 * 384 + j];
    hid[j] = fmaxf(a, 0.0f);
  }
  __syncthreads();

  float p0 = 0.f, p1 = 0.f;
  for (int k2 = tid; k2 < 384; k2 += 256) {
    p0 += hid[k2] * c2w[k2 * 2 + 0];
    p1 += hid[k2] * c2w[k2 * 2 + 1];
  }
  p0 = block_sum(p0, red);
  p1 = block_sum(p1, red);
  if (tid == 0) {
    out[b * 2 + 0] = p0 + c2b[0];
    out[b * 2 + 1] = p1 + c2b[1];
  }
}

// ---------------- launch ----------------
extern "C" void kernel_launch(void* const* d_in, const int* in_sizes, int n_in,
                              void* d_out, int out_size, void* d_ws, size_t ws_size,
                              hipStream_t stream) {
  const float* text   = (const float*)d_in[0];
  const float* img    = (const float*)d_in[1];
  const float* clip_t = (const float*)d_in[2];
  const float* clip_i = (const float*)d_in[3];
  const float* lscale = (const float*)d_in[4];
  const float* wq = (const float*)d_in[5];
  const float* bq = (const float*)d_in[6];
  const float* wk = (const float*)d_in[7];
  const float* bk = (const float*)d_in[8];
  const float* wv = (const float*)d_in[9];
  const float* bv = (const float*)d_in[10];
  const float* wo = (const float*)d_in[11];
  const float* bo = (const float*)d_in[12];
  const float* Wt = (const float*)d_in[13];
  const float* at = (const float*)d_in[14];
  const float* Wi = (const float*)d_in[15];
  const float* ai = (const float*)d_in[16];
  const float* Wp = (const float*)d_in[17];
  const float* bp = (const float*)d_in[18];
  const float* f1w = (const float*)d_in[19];
  const float* f1b = (const float*)d_in[20];
  const float* f2w = (const float*)d_in[21];
  const float* f2b = (const float*)d_in[22];
  const float* c1w = (const float*)d_in[23];
  const float* c1b = (const float*)d_in[24];
  const float* c2w = (const float*)d_in[25];
  const float* c2b = (const float*)d_in[26];
  const int* text_adj  = (const int*)d_in[27];
  const int* image_adj = (const int*)d_in[28];
  float* out = (float*)d_out;

  const size_t nTD = (size_t)B * T * D;   // 1,572,864
  const size_t nPD = (size_t)B * P * D;   // 4,816,896
  const size_t nWW = (size_t)D * D;       // 589,824

  // workspace layout: fp32 buffers first, then bf16
  float* fbuf = (float*)d_ws;
  size_t o = 0;
  float* kv_buf = fbuf + o; o += 2 * nPD;  // [B*P][1536]: k|v ; first nPD reused as Wh_i
  float* qa_buf = fbuf + o; o += 2 * nTD;  // [B*T][1536]: q|Wh_t
  float* upd    = fbuf + o; o += nTD;
  float* ftok   = fbuf + o; o += (size_t)B * D;
  float* stok   = fbuf + o; o += 32;
  float* tgf    = fbuf + o; o += (size_t)B * D;
  float* igf    = fbuf + o; o += (size_t)B * D;
  float* fglob  = fbuf + o; o += (size_t)B * D;
  float* bcat_t = fbuf + o; o += 1536;
  float* bcat_i = fbuf + o; o += 1536;
  unsigned short* sbuf = (unsigned short*)(fbuf + o);
  size_t so = 0;
  unsigned short* text_bf  = sbuf + so; so += nTD;
  unsigned short* img_bf   = sbuf + so; so += nPD;
  unsigned short* att_bf   = sbuf + so; so += nTD;
  unsigned short* wcat_txt = sbuf + so; so += 2 * nWW;  // wq^T | Wt^T
  unsigned short* wcat_img = sbuf + so; so += 2 * nWW;  // wk^T | wv^T
  unsigned short* wo_t     = sbuf + so; so += nWW;
  unsigned short* wi_t     = sbuf + so; so += nWW;

  // ---- weight casts (one fused launch) + bias concat ----
  WPack wp;
  wp.src[0] = wq; wp.dst[0] = wcat_txt;
  wp.src[1] = Wt; wp.dst[1] = wcat_txt + nWW;
  wp.src[2] = wk; wp.dst[2] = wcat_img;
  wp.src[3] = wv; wp.dst[3] = wcat_img + nWW;
  wp.src[4] = wo; wp.dst[4] = wo_t;
  wp.src[5] = Wi; wp.dst[5] = wi_t;
  cast_transpose6<<<dim3(D / 32, D / 32, 6), 256, 0, stream>>>(wp, D, D);
  build_bias<<<6, 256, 0, stream>>>(bq, bk, bv, bcat_t, bcat_i);
  cast_rows<<<(int)(nTD / 4 + 255) / 256, 256, 0, stream>>>(text, text_bf, (int)(nTD / 4));
  cast_rows<<<(int)(nPD / 4 + 255) / 256, 256, 0, stream>>>(img, img_bf, (int)(nPD / 4));

  const int MT = B * T;   // 2048
  const int MP = B * P;   // 6272

  // ---- fused projections ----
  gemm_mfma<<<dim3(1536 / 128, MT / 128), 256, 0, stream>>>(text_bf, wcat_txt, bcat_t, qa_buf, MT, 1536, D);
  gemm_mfma<<<dim3(1536 / 128, MP / 128), 256, 0, stream>>>(img_bf, wcat_img, bcat_i, kv_buf, MP, 1536, D);

  fglob_kernel<<<dim3(12, B), 256, 0, stream>>>(clip_t, Wp, bp, fglob);

  cross_attn2<<<dim3(H, B), 256, 0, stream>>>(qa_buf, kv_buf, att_bf);

  gemm_mfma<<<dim3(D / 128, MT / 128), 256, 0, stream>>>(att_bf, wo_t, bo, upd, MT, D, D);
  // Wh_i GEMM reuses kv_buf (attention done with k,v)
  float* whi = kv_buf;
  gemm_mfma<<<dim3(D / 128, MP / 128), 256, 0, stream>>>(img_bf, wi_t, nullptr, whi, MP, D, D);

  token_kernel<<<B, 256, 0, stream>>>(upd, img, ftok, stok);
  text_gat_kernel<<<dim3(H, B), 128, 0, stream>>>(qa_buf + 768, 1536, text_adj, at, tgf);
  image_gat_kernel<<<dim3(H, B), 256, 0, stream>>>(whi, 768, image_adj, ai, igf);
  final_kernel<<<B, 256, 0, stream>>>(tgf, igf, clip_t, clip_i, lscale, stok, ftok, fglob,
                                      f1w, f1b, f2w, f2b, c1w, c1b, c2w, c2b, out);
}

// Round 6
// 565.966 us; speedup vs baseline: 2.5492x; 1.2028x over previous
//
#include <hip/hip_runtime.h>
#include <hip/hip_bf16.h>
#include <math.h>

// Problem constants
#define B 32
#define T 64
#define P 196
#define D 768
#define H 12

typedef __attribute__((ext_vector_type(8))) short short8;
typedef __attribute__((ext_vector_type(4))) float floatx4;

// ---------------- helpers ----------------
__device__ __forceinline__ float wave_sum(float v) {
#pragma unroll
  for (int o = 32; o > 0; o >>= 1) v += __shfl_xor(v, o);
  return v;
}
__device__ __forceinline__ float wave_max(float v) {
#pragma unroll
  for (int o = 32; o > 0; o >>= 1) v = fmaxf(v, __shfl_xor(v, o));
  return v;
}
__device__ __forceinline__ unsigned short f2bf(float x) {
  unsigned u = __float_as_uint(x);
  u += 0x7FFFu + ((u >> 16) & 1u);   // round-to-nearest-even
  return (unsigned short)(u >> 16);
}

// ---------------- cast kernels ----------------
__global__ __launch_bounds__(256) void cast_rows(const float* __restrict__ X,
                                                 unsigned short* __restrict__ Y, int n4) {
  int i = blockIdx.x * 256 + threadIdx.x;
  if (i < n4) {
    float4 vv = ((const float4*)X)[i];
    ushort4 o;
    o.x = f2bf(vv.x); o.y = f2bf(vv.y); o.z = f2bf(vv.z); o.w = f2bf(vv.w);
    ((ushort4*)Y)[i] = o;
  }
}

// 6 weights fp32 [K][N] -> bf16 [N][K], one fused launch (grid.z = weight idx)
struct WPack {
  const float* src[6];
  unsigned short* dst[6];
};
__global__ __launch_bounds__(256) void cast_transpose6(WPack p, int K, int N) {
  __shared__ float tile[32][33];
  const float* W = p.src[blockIdx.z];
  unsigned short* Wt = p.dst[blockIdx.z];
  const int tx = threadIdx.x & 31, ty = threadIdx.x >> 5;  // ty 0..7
  const int n0 = blockIdx.x * 32, k0 = blockIdx.y * 32;
#pragma unroll
  for (int r = 0; r < 4; ++r)
    tile[ty + 8 * r][tx] = W[(size_t)(k0 + ty + 8 * r) * N + n0 + tx];
  __syncthreads();
#pragma unroll
  for (int r = 0; r < 4; ++r)
    Wt[(size_t)(n0 + ty + 8 * r) * K + k0 + tx] = f2bf(tile[tx][ty + 8 * r]);
}

// concat biases: bt = [bq, 0], bi = [bk, bv]
__global__ __launch_bounds__(256) void build_bias(const float* __restrict__ bq,
                                                  const float* __restrict__ bk,
                                                  const float* __restrict__ bv,
                                                  float* __restrict__ bt,
                                                  float* __restrict__ bi) {
  int i = blockIdx.x * 256 + threadIdx.x;
  if (i < 768) { bt[i] = bq[i]; bi[i] = bk[i]; }
  else if (i < 1536) { bt[i] = 0.f; bi[i] = bv[i - 768]; }
}

// ---------------- bf16 MFMA GEMM: C[M,N] = A[M,K] @ Bt[N,K]^T (+bias) ----------------
// 128x128 tile, 256 threads (4 waves, each 64x64 via 4x4 grid of 16x16x32 MFMAs).
__global__ __launch_bounds__(256) void gemm_mfma(
    const unsigned short* __restrict__ A,   // [M][K] bf16
    const unsigned short* __restrict__ Bt,  // [N][K] bf16 (= W^T)
    const float* __restrict__ bias, float* __restrict__ C,
    int M, int N, int K) {
  __shared__ unsigned short As[128][40];
  __shared__ unsigned short Bs[128][40];
  const int tid = threadIdx.x;
  const int lane = tid & 63;
  const int w = tid >> 6;
  const int quad = lane >> 4;
  const int l15 = lane & 15;
  const int row0 = blockIdx.y * 128;
  const int col0 = blockIdx.x * 128;
  const int m_off = (w & 1) * 64;
  const int n_off = (w >> 1) * 64;
  const int lr = tid >> 2;
  const int lc = (tid & 3) * 8;

  floatx4 acc[4][4] = {};

  for (int k0 = 0; k0 < K; k0 += 32) {
    const uint4 a0 = *(const uint4*)(A + (size_t)(row0 + lr) * K + k0 + lc);
    const uint4 a1 = *(const uint4*)(A + (size_t)(row0 + lr + 64) * K + k0 + lc);
    const uint4 b0 = *(const uint4*)(Bt + (size_t)(col0 + lr) * K + k0 + lc);
    const uint4 b1 = *(const uint4*)(Bt + (size_t)(col0 + lr + 64) * K + k0 + lc);
    __syncthreads();
    *(uint4*)&As[lr][lc] = a0;
    *(uint4*)&As[lr + 64][lc] = a1;
    *(uint4*)&Bs[lr][lc] = b0;
    *(uint4*)&Bs[lr + 64][lc] = b1;
    __syncthreads();
    short8 af[4], bfr[4];
#pragma unroll
    for (int i = 0; i < 4; ++i)
      af[i] = *(const short8*)&As[m_off + 16 * i + l15][quad * 8];
#pragma unroll
    for (int j = 0; j < 4; ++j)
      bfr[j] = *(const short8*)&Bs[n_off + 16 * j + l15][quad * 8];
#pragma unroll
    for (int i = 0; i < 4; ++i)
#pragma unroll
      for (int j = 0; j < 4; ++j)
        acc[i][j] = __builtin_amdgcn_mfma_f32_16x16x32_bf16(af[i], bfr[j], acc[i][j], 0, 0, 0);
  }

#pragma unroll
  for (int j = 0; j < 4; ++j) {
    const int cg = col0 + n_off + 16 * j + l15;
    const float bv = bias ? bias[cg] : 0.0f;
#pragma unroll
    for (int i = 0; i < 4; ++i) {
      const int rbase = row0 + m_off + 16 * i + quad * 4;
#pragma unroll
      for (int r = 0; r < 4; ++r)
        C[(size_t)(rbase + r) * N + cg] = acc[i][j][r] + bv;
    }
  }
}

// ---------------- MFMA cross attention: one block per (b,h), 4 waves ----------------
// qa: [B*T][1536] fp32 (q in cols 0..767). kv: [B*P][1536] fp32 (k 0..767, v 768..1535).
// Wave w computes t-rows [16w, 16w+16). attout bf16 [B*T][768].
__global__ __launch_bounds__(256) void attn_mfma(
    const float* __restrict__ qa, const float* __restrict__ kv,
    unsigned short* __restrict__ attout) {
  const int h = blockIdx.x, b = blockIdx.y;
  const int tid = threadIdx.x, lane = tid & 63, w = tid >> 6;
  const int quad = lane >> 4, l15 = lane & 15;

  __shared__ unsigned short Ks[196][72];     // K[p][d] bf16 (row pad to 72 shorts = 144 B)
  __shared__ unsigned short VT[64][232];     // V^T: VT[d][p]
  __shared__ unsigned short Ps[4][16][232];  // per-wave P (A-layout rows t_local)

  // ---- stage K and V^T from fp32 (convert to bf16) ----
  for (int i = tid; i < P * 64; i += 256) {
    const int p = i >> 6, d = i & 63;
    const float* row = kv + (size_t)(b * P + p) * 1536 + h * 64 + d;
    Ks[p][d] = f2bf(row[0]);
    VT[d][p] = f2bf(row[768]);
  }
  // zero-pad VT cols 196..223 (read by PV k-steps; P fragment is 0 there)
  if (tid < 64) {
    for (int c = 196; c < 224; ++c) VT[tid][c] = 0;
  }
  __syncthreads();

  // ---- Q fragments (fp32 -> bf16 pack), rows t = 16w + l15 ----
  short8 aq[2];
  {
    const float* qrow = qa + (size_t)(b * T + 16 * w + l15) * 1536 + h * 64;
#pragma unroll
    for (int ks = 0; ks < 2; ++ks) {
      const float4 x = *(const float4*)(qrow + 32 * ks + quad * 8);
      const float4 y = *(const float4*)(qrow + 32 * ks + quad * 8 + 4);
      short8 f;
      f[0] = (short)f2bf(x.x); f[1] = (short)f2bf(x.y);
      f[2] = (short)f2bf(x.z); f[3] = (short)f2bf(x.w);
      f[4] = (short)f2bf(y.x); f[5] = (short)f2bf(y.y);
      f[6] = (short)f2bf(y.z); f[7] = (short)f2bf(y.w);
      aq[ks] = f;
    }
  }

  // ---- QK^T: S[t][p], 13 p-tiles, K-dim 64 (2 k-steps) ----
  floatx4 sc[13];
#pragma unroll
  for (int tile = 0; tile < 13; ++tile) {
    int p = tile * 16 + l15;
    if (p > 195) p = 195;  // clamp (masked below)
    short8 bk0 = *(const short8*)&Ks[p][quad * 8];
    short8 bk1 = *(const short8*)&Ks[p][32 + quad * 8];
    floatx4 c = {};
    c = __builtin_amdgcn_mfma_f32_16x16x32_bf16(aq[0], bk0, c, 0, 0, 0);
    c = __builtin_amdgcn_mfma_f32_16x16x32_bf16(aq[1], bk1, c, 0, 0, 0);
    sc[tile] = c;
  }

  // ---- softmax over p (rows owned quad-locally: row = quad*4+r, col = l15) ----
  float mx[4] = {-3.4e38f, -3.4e38f, -3.4e38f, -3.4e38f};
#pragma unroll
  for (int tile = 0; tile < 13; ++tile)
#pragma unroll
    for (int r = 0; r < 4; ++r) {
      float s = sc[tile][r] * 0.125f;
      if (tile == 12 && l15 >= 4) s = -3.0e38f;  // p >= 196 invalid
      sc[tile][r] = s;
      mx[r] = fmaxf(mx[r], s);
    }
#pragma unroll
  for (int off = 1; off < 16; off <<= 1)
#pragma unroll
    for (int r = 0; r < 4; ++r) mx[r] = fmaxf(mx[r], __shfl_xor(mx[r], off));

  float sm[4] = {};
#pragma unroll
  for (int tile = 0; tile < 13; ++tile)
#pragma unroll
    for (int r = 0; r < 4; ++r) {
      float e = expf(sc[tile][r] - mx[r]);
      sc[tile][r] = e;
      sm[r] += e;
    }
#pragma unroll
  for (int off = 1; off < 16; off <<= 1)
#pragma unroll
    for (int r = 0; r < 4; ++r) sm[r] += __shfl_xor(sm[r], off);
  float inv[4];
#pragma unroll
  for (int r = 0; r < 4; ++r) inv[r] = 1.0f / sm[r];

  // ---- write P (bf16) into per-wave LDS in A-operand row layout ----
#pragma unroll
  for (int tile = 0; tile < 13; ++tile)
#pragma unroll
    for (int r = 0; r < 4; ++r)
      Ps[w][quad * 4 + r][tile * 16 + l15] = f2bf(sc[tile][r] * inv[r]);
#pragma unroll
  for (int r = 0; r < 4; ++r)
    Ps[w][quad * 4 + r][208 + l15] = 0;  // pad cols 208..223

  __syncthreads();

  // ---- PV: O[t][d] = sum_p P[t][p] V[p][d]; 4 d-tiles, 7 k-steps (k=p, padded 224) ----
  floatx4 oc[4] = {};
#pragma unroll
  for (int ks = 0; ks < 7; ++ks) {
    short8 pa = *(const short8*)&Ps[w][l15][ks * 32 + quad * 8];
#pragma unroll
    for (int nt = 0; nt < 4; ++nt) {
      short8 bv = *(const short8*)&VT[nt * 16 + l15][ks * 32 + quad * 8];
      oc[nt] = __builtin_amdgcn_mfma_f32_16x16x32_bf16(pa, bv, oc[nt], 0, 0, 0);
    }
  }

  // ---- epilogue: C-layout (col=l15 -> d_local, row=quad*4+r -> t_local) ----
#pragma unroll
  for (int nt = 0; nt < 4; ++nt)
#pragma unroll
    for (int r = 0; r < 4; ++r)
      attout[(size_t)(b * T + 16 * w + quad * 4 + r) * 768 + h * 64 + nt * 16 + l15] =
          f2bf(oc[nt][r]);
}

// ---------------- s_token + f_token ----------------
__global__ __launch_bounds__(256) void token_kernel(
    const float* __restrict__ upd, const float* __restrict__ img,
    float* __restrict__ f_token, float* __restrict__ s_token) {
  const int b = blockIdx.x, tid = threadIdx.x;
  for (int d = tid; d < D; d += 256) {
    float s = 0.f;
    for (int t = 0; t < T; ++t) s += upd[((size_t)(b * T + t)) * D + d];
    f_token[b * D + d] = s * (1.0f / T);
  }
  float part = 0.f;
  for (int idx = tid; idx < T * D; idx += 256) {
    int t = idx / D, d = idx - t * D;
    part += upd[((size_t)(b * T + t)) * D + d] * img[((size_t)(b * P + t)) * D + d];
  }
  part = wave_sum(part);
  __shared__ float red[4];
  if ((tid & 63) == 0) red[tid >> 6] = part;
  __syncthreads();
  if (tid == 0) s_token[b] = (red[0] + red[1] + red[2] + red[3]) * (1.0f / T);
}

// ---------------- text GAT: one block (2 waves) per (b,h). N=64 ----------------
__global__ __launch_bounds__(128) void text_gat_kernel(
    const float* __restrict__ Wh, int ldw, const int* __restrict__ adj,
    const float* __restrict__ at, float* __restrict__ tgf) {
  const int h = blockIdx.x, b = blockIdx.y;
  const int tid = threadIdx.x, lane = tid & 63, w = tid >> 6;
  __shared__ float WhT[64][68];       // WhT[f][n]
  __shared__ float atts[2][8][68];
  __shared__ float srcs[64], dsts[64];
  __shared__ float redc[2][64];
  __shared__ float asv[64], adv[64];

  if (tid < 64) { asv[tid] = at[tid]; adv[tid] = at[64 + tid]; }
  for (int idx = tid; idx < 64 * 64; idx += 128) {
    int n = idx >> 6, f = idx & 63;
    WhT[f][n] = Wh[(size_t)(b * T + n) * ldw + h * 64 + f];
  }
  __syncthreads();

  if (tid < 64) {
    float s = 0.f, dd = 0.f;
#pragma unroll 8
    for (int f = 0; f < 64; ++f) {
      float wv = WhT[f][tid];
      s += wv * asv[f];
      dd += wv * adv[f];
    }
    srcs[tid] = s;
    dsts[tid] = dd;
  }
  __syncthreads();

  const int* adjb = adj + b * T * T;
  float macc = 0.f;
  for (int g = 0; g < 4; ++g) {
#pragma unroll
    for (int r = 0; r < 8; ++r) {
      const int i = w * 32 + g * 8 + r;
      float e = srcs[i] + dsts[lane];
      e = (e >= 0.f) ? e : 0.2f * e;
      if (adjb[i * 64 + lane] == 0) e = -9e15f;
      const float m = wave_max(e);
      float pp = expf(e - m);
      const float inv = 1.0f / wave_sum(pp);
      atts[w][r][lane] = pp * inv;
    }
    float acc[8] = {};
    for (int jq = 0; jq < 16; ++jq) {
      const float4 whv = *(const float4*)&WhT[lane][4 * jq];
#pragma unroll
      for (int r = 0; r < 8; ++r) {
        const float4 av = *(const float4*)&atts[w][r][4 * jq];
        acc[r] += av.x * whv.x + av.y * whv.y + av.z * whv.z + av.w * whv.w;
      }
    }
#pragma unroll
    for (int r = 0; r < 8; ++r)
      macc += (acc[r] > 0.f) ? acc[r] : (expf(acc[r]) - 1.0f);
  }

  redc[w][lane] = macc;
  __syncthreads();
  if (w == 0)
    tgf[b * D + h * 64 + lane] = (redc[0][lane] + redc[1][lane]) * (1.0f / T);
}

// ---------------- image GAT: one block (4 waves) per (b,h). N=196 ----------------
__global__ __launch_bounds__(256) void image_gat_kernel(
    const float* __restrict__ Wh, int ldw, const int* __restrict__ adj,
    const float* __restrict__ ai, float* __restrict__ igf) {
  const int h = blockIdx.x, b = blockIdx.y;
  const int tid = threadIdx.x, lane = tid & 63, w = tid >> 6;
  __shared__ float WhT[64][204];
  __shared__ float atts[4][7][204];
  __shared__ float srcs[196], dsts[196];
  __shared__ float redc[4][64];
  __shared__ float asv[64], adv[64];

  if (tid < 64) { asv[tid] = ai[tid]; adv[tid] = ai[64 + tid]; }
  for (int idx = tid; idx < P * 64; idx += 256) {
    int n = idx >> 6, f = idx & 63;
    WhT[f][n] = Wh[(size_t)(b * P + n) * ldw + h * 64 + f];
  }
  __syncthreads();

  for (int n = tid; n < P; n += 256) {
    float s = 0.f, dd = 0.f;
#pragma unroll 8
    for (int f = 0; f < 64; ++f) {
      float wv = WhT[f][n];
      s += wv * asv[f];
      dd += wv * adv[f];
    }
    srcs[n] = s;
    dsts[n] = dd;
  }
  __syncthreads();

  float macc = 0.f;
  for (int g = 0; g < 7; ++g) {
#pragma unroll
    for (int r = 0; r < 7; ++r) {
      const int i = w * 49 + g * 7 + r;
      const float si = srcs[i];
      const int* ar = adj + i * P;
      float x, e0, e1, e2, e3;
      x = si + dsts[lane];        e0 = (x >= 0.f) ? x : 0.2f * x;
      x = si + dsts[lane + 64];   e1 = (x >= 0.f) ? x : 0.2f * x;
      x = si + dsts[lane + 128];  e2 = (x >= 0.f) ? x : 0.2f * x;
      if (lane < 4) { x = si + dsts[lane + 192]; e3 = (x >= 0.f) ? x : 0.2f * x; }
      else e3 = -3.4e38f;
      if (ar[lane] == 0) e0 = -9e15f;
      if (ar[lane + 64] == 0) e1 = -9e15f;
      if (ar[lane + 128] == 0) e2 = -9e15f;
      if (lane < 4 && ar[lane + 192] == 0) e3 = -9e15f;
      const float m = wave_max(fmaxf(fmaxf(e0, e1), fmaxf(e2, e3)));
      float p0e = expf(e0 - m), p1e = expf(e1 - m), p2e = expf(e2 - m);
      float p3e = (lane < 4) ? expf(e3 - m) : 0.f;
      const float inv = 1.0f / wave_sum(p0e + p1e + p2e + p3e);
      atts[w][r][lane] = p0e * inv;
      atts[w][r][lane + 64] = p1e * inv;
      atts[w][r][lane + 128] = p2e * inv;
      if (lane < 4) atts[w][r][lane + 192] = p3e * inv;
    }
    float acc[7] = {};
    for (int jq = 0; jq < 49; ++jq) {
      const float4 whv = *(const float4*)&WhT[lane][4 * jq];
#pragma unroll
      for (int r = 0; r < 7; ++r) {
        const float4 av = *(const float4*)&atts[w][r][4 * jq];
        acc[r] += av.x * whv.x + av.y * whv.y + av.z * whv.z + av.w * whv.w;
      }
    }
#pragma unroll
    for (int r = 0; r < 7; ++r)
      macc += (acc[r] > 0.f) ? acc[r] : (expf(acc[r]) - 1.0f);
  }

  redc[w][lane] = macc;
  __syncthreads();
  if (w == 0) {
    float tot = redc[0][lane] + redc[1][lane] + redc[2][lane] + redc[3][lane];
    igf[b * D + h * 64 + lane] = tot * (1.0f / P);
  }
}

// ---------------- f_global = clip_t @ Wp + bp : grid (12, B) ----------------
__global__ __launch_bounds__(256) void fglob_kernel(
    const float* __restrict__ clip_t, const float* __restrict__ Wp,
    const float* __restrict__ bp, float* __restrict__ fglob) {
  const int jt = blockIdx.x, b = blockIdx.y;
  const int j = threadIdx.x & 63, kc = threadIdx.x >> 6;
  float s = 0.f;
  const float* ct = clip_t + b * 512;
#pragma unroll 4
  for (int k = kc * 128; k < kc * 128 + 128; ++k)
    s += ct[k] * Wp[(size_t)k * D + jt * 64 + j];
  __shared__ float red[4][64];
  red[kc][j] = s;
  __syncthreads();
  if (kc == 0)
    fglob[b * D + jt * 64 + j] = red[0][j] + red[1][j] + red[2][j] + red[3][j] + bp[jt * 64 + j];
}

// ---------------- final fusion kernel: one block per b ----------------
__device__ __forceinline__ float block_sum(float v, float* red4) {
  v = wave_sum(v);
  __syncthreads();
  if ((threadIdx.x & 63) == 0) red4[threadIdx.x >> 6] = v;
  __syncthreads();
  return red4[0] + red4[1] + red4[2] + red4[3];
}

__global__ __launch_bounds__(256) void final_kernel(
    const float* __restrict__ tgf, const float* __restrict__ igf,
    const float* __restrict__ clip_t, const float* __restrict__ clip_i,
    const float* __restrict__ logit_scale, const float* __restrict__ s_token,
    const float* __restrict__ f_token, const float* __restrict__ fglob,
    const float* __restrict__ f1w, const float* __restrict__ f1b,
    const float* __restrict__ f2w, const float* __restrict__ f2b,
    const float* __restrict__ c1w, const float* __restrict__ c1b,
    const float* __restrict__ c2w, const float* __restrict__ c2b,
    float* __restrict__ out) {
  const int b = blockIdx.x, tid = threadIdx.x;
  __shared__ float red[4];
  __shared__ float sres[4];
  __shared__ float fagg[768];
  __shared__ float hid[384];

  float d0 = 0.f, d1 = 0.f, d2 = 0.f;
  for (int i = tid; i < D; i += 256) {
    float x = tgf[b * D + i], y = igf[b * D + i];
    d0 += x * y; d1 += x * x; d2 += y * y;
  }
  float dot_ti = block_sum(d0, red);
  float n_t = sqrtf(block_sum(d1, red));
  float n_i = sqrtf(block_sum(d2, red));
  float s_phrase = dot_ti / (fmaxf(n_t, 1e-8f) * fmaxf(n_i, 1e-8f));

  float c0 = 0.f, c1 = 0.f, c2 = 0.f;
  for (int i = tid; i < 512; i += 256) {
    float x = clip_t[b * 512 + i], y = clip_i[b * 512 + i];
    c0 += x * y; c1 += x * x; c2 += y * y;
  }
  float dc = block_sum(c0, red);
  float nt2 = sqrtf(block_sum(c1, red));
  float ni2 = sqrtf(block_sum(c2, red));
  float s_global = expf(logit_scale[0]) * dc / (fmaxf(nt2, 1e-8f) * fmaxf(ni2, 1e-8f));

  if (tid == 0) {
    float s3[3] = { s_token[b], s_phrase, s_global };
    float h1[16];
    for (int j = 0; j < 16; ++j) {
      float a = f1b[j];
      for (int i2 = 0; i2 < 3; ++i2) a += s3[i2] * f1w[i2 * 16 + j];
      h1[j] = 0.5f * a * (1.0f + erff(a * 0.70710678118654752f));
    }
    for (int j = 0; j < 3; ++j) {
      float a = f2b[j];
      for (int i2 = 0; i2 < 16; ++i2) a += h1[i2] * f2w[i2 * 3 + j];
      sres[j] = 1.0f / (1.0f + expf(-a));
    }
  }
  __syncthreads();
  float w0 = sres[0], w1 = sres[1], w2 = sres[2];

  for (int j = tid; j < D; j += 256)
    fagg[j] = w0 * f_token[b * D + j] + w1 * tgf[b * D + j] + w2 * fglob[b * D + j];
  __syncthreads();

  for (int j = tid; j < 384; j += 256) {
    float a = c1b[j];
    for (int k2 = 0; k2 < D; ++k2) a += fagg[k2] * c1w[k2 * 384 + j];
    hid[j] = fmaxf(a, 0.0f);
  }
  __syncthreads();

  float p0 = 0.f, p1 = 0.f;
  for (int k2 = tid; k2 < 384; k2 += 256) {
    p0 += hid[k2] * c2w[k2 * 2 + 0];
    p1 += hid[k2] * c2w[k2 * 2 + 1];
  }
  p0 = block_sum(p0, red);
  p1 = block_sum(p1, red);
  if (tid == 0) {
    out[b * 2 + 0] = p0 + c2b[0];
    out[b * 2 + 1] = p1 + c2b[1];
  }
}

// ---------------- launch ----------------
extern "C" void kernel_launch(void* const* d_in, const int* in_sizes, int n_in,
                              void* d_out, int out_size, void* d_ws, size_t ws_size,
                              hipStream_t stream) {
  const float* text   = (const float*)d_in[0];
  const float* img    = (const float*)d_in[1];
  const float* clip_t = (const float*)d_in[2];
  const float* clip_i = (const float*)d_in[3];
  const float* lscale = (const float*)d_in[4];
  const float* wq = (const float*)d_in[5];
  const float* bq = (const float*)d_in[6];
  const float* wk = (const float*)d_in[7];
  const float* bk = (const float*)d_in[8];
  const float* wv = (const float*)d_in[9];
  const float* bv = (const float*)d_in[10];
  const float* wo = (const float*)d_in[11];
  const float* bo = (const float*)d_in[12];
  const float* Wt = (const float*)d_in[13];
  const float* at = (const float*)d_in[14];
  const float* Wi = (const float*)d_in[15];
  const float* ai = (const float*)d_in[16];
  const float* Wp = (const float*)d_in[17];
  const float* bp = (const float*)d_in[18];
  const float* f1w = (const float*)d_in[19];
  const float* f1b = (const float*)d_in[20];
  const float* f2w = (const float*)d_in[21];
  const float* f2b = (const float*)d_in[22];
  const float* c1w = (const float*)d_in[23];
  const float* c1b = (const float*)d_in[24];
  const float* c2w = (const float*)d_in[25];
  const float* c2b = (const float*)d_in[26];
  const int* text_adj  = (const int*)d_in[27];
  const int* image_adj = (const int*)d_in[28];
  float* out = (float*)d_out;

  const size_t nTD = (size_t)B * T * D;   // 1,572,864
  const size_t nPD = (size_t)B * P * D;   // 4,816,896
  const size_t nWW = (size_t)D * D;       // 589,824

  // workspace layout: fp32 buffers first, then bf16 (identical to round 3)
  float* fbuf = (float*)d_ws;
  size_t o = 0;
  float* kv_buf = fbuf + o; o += 2 * nPD;  // [B*P][1536]: k|v ; first nPD reused as Wh_i
  float* qa_buf = fbuf + o; o += 2 * nTD;  // [B*T][1536]: q|Wh_t
  float* upd    = fbuf + o; o += nTD;
  float* ftok   = fbuf + o; o += (size_t)B * D;
  float* stok   = fbuf + o; o += 32;
  float* tgf    = fbuf + o; o += (size_t)B * D;
  float* igf    = fbuf + o; o += (size_t)B * D;
  float* fglob  = fbuf + o; o += (size_t)B * D;
  float* bcat_t = fbuf + o; o += 1536;
  float* bcat_i = fbuf + o; o += 1536;
  unsigned short* sbuf = (unsigned short*)(fbuf + o);
  size_t so = 0;
  unsigned short* text_bf  = sbuf + so; so += nTD;
  unsigned short* img_bf   = sbuf + so; so += nPD;
  unsigned short* att_bf   = sbuf + so; so += nTD;
  unsigned short* wcat_txt = sbuf + so; so += 2 * nWW;  // wq^T | Wt^T
  unsigned short* wcat_img = sbuf + so; so += 2 * nWW;  // wk^T | wv^T
  unsigned short* wo_t     = sbuf + so; so += nWW;
  unsigned short* wi_t     = sbuf + so; so += nWW;

  // ---- weight casts (one fused launch) + bias concat ----
  WPack wp;
  wp.src[0] = wq; wp.dst[0] = wcat_txt;
  wp.src[1] = Wt; wp.dst[1] = wcat_txt + nWW;
  wp.src[2] = wk; wp.dst[2] = wcat_img;
  wp.src[3] = wv; wp.dst[3] = wcat_img + nWW;
  wp.src[4] = wo; wp.dst[4] = wo_t;
  wp.src[5] = Wi; wp.dst[5] = wi_t;
  cast_transpose6<<<dim3(D / 32, D / 32, 6), 256, 0, stream>>>(wp, D, D);
  build_bias<<<6, 256, 0, stream>>>(bq, bk, bv, bcat_t, bcat_i);
  cast_rows<<<(int)(nTD / 4 + 255) / 256, 256, 0, stream>>>(text, text_bf, (int)(nTD / 4));
  cast_rows<<<(int)(nPD / 4 + 255) / 256, 256, 0, stream>>>(img, img_bf, (int)(nPD / 4));

  const int MT = B * T;   // 2048
  const int MP = B * P;   // 6272

  // ---- fused projections ----
  gemm_mfma<<<dim3(1536 / 128, MT / 128), 256, 0, stream>>>(text_bf, wcat_txt, bcat_t, qa_buf, MT, 1536, D);
  gemm_mfma<<<dim3(1536 / 128, MP / 128), 256, 0, stream>>>(img_bf, wcat_img, bcat_i, kv_buf, MP, 1536, D);

  fglob_kernel<<<dim3(12, B), 256, 0, stream>>>(clip_t, Wp, bp, fglob);

  // MFMA attention (reads fp32 q/kv, writes bf16 att) — the ONLY change vs round 3
  attn_mfma<<<dim3(H, B), 256, 0, stream>>>(qa_buf, kv_buf, att_bf);

  gemm_mfma<<<dim3(D / 128, MT / 128), 256, 0, stream>>>(att_bf, wo_t, bo, upd, MT, D, D);
  // Wh_i GEMM reuses kv_buf (attention done with k,v)
  float* whi = kv_buf;
  gemm_mfma<<<dim3(D / 128, MP / 128), 256, 0, stream>>>(img_bf, wi_t, nullptr, whi, MP, D, D);

  token_kernel<<<B, 256, 0, stream>>>(upd, img, ftok, stok);
  text_gat_kernel<<<dim3(H, B), 128, 0, stream>>>(qa_buf + 768, 1536, text_adj, at, tgf);
  image_gat_kernel<<<dim3(H, B), 256, 0, stream>>>(whi, 768, image_adj, ai, igf);
  final_kernel<<<B, 256, 0, stream>>>(tgf, igf, clip_t, clip_i, lscale, stok, ftok, fglob,
                                      f1w, f1b, f2w, f2b, c1w, c1b, c2w, c2b, out);
}

// Round 7
// 509.581 us; speedup vs baseline: 2.8313x; 1.1107x over previous
//
#include <hip/hip_runtime.h>
#include <hip/hip_bf16.h>
#include <math.h>

// Problem constants
#define B 32
#define T 64
#define P 196
#define D 768
#define H 12

typedef __attribute__((ext_vector_type(8))) short short8;
typedef __attribute__((ext_vector_type(4))) float floatx4;

// ---------------- helpers ----------------
__device__ __forceinline__ float wave_sum(float v) {
#pragma unroll
  for (int o = 32; o > 0; o >>= 1) v += __shfl_xor(v, o);
  return v;
}
__device__ __forceinline__ float wave_max(float v) {
#pragma unroll
  for (int o = 32; o > 0; o >>= 1) v = fmaxf(v, __shfl_xor(v, o));
  return v;
}
__device__ __forceinline__ unsigned short f2bf(float x) {
  unsigned u = __float_as_uint(x);
  u += 0x7FFFu + ((u >> 16) & 1u);   // round-to-nearest-even
  return (unsigned short)(u >> 16);
}

// ---------------- cast kernels ----------------
__global__ __launch_bounds__(256) void cast_rows(const float* __restrict__ X,
                                                 unsigned short* __restrict__ Y, int n4) {
  int i = blockIdx.x * 256 + threadIdx.x;
  if (i < n4) {
    float4 vv = ((const float4*)X)[i];
    ushort4 o;
    o.x = f2bf(vv.x); o.y = f2bf(vv.y); o.z = f2bf(vv.z); o.w = f2bf(vv.w);
    ((ushort4*)Y)[i] = o;
  }
}

// 6 weights fp32 [K][N] -> bf16 [N][K], one fused launch (grid.z = weight idx)
struct WPack {
  const float* src[6];
  unsigned short* dst[6];
};
__global__ __launch_bounds__(256) void cast_transpose6(WPack p, int K, int N) {
  __shared__ float tile[32][33];
  const float* W = p.src[blockIdx.z];
  unsigned short* Wt = p.dst[blockIdx.z];
  const int tx = threadIdx.x & 31, ty = threadIdx.x >> 5;  // ty 0..7
  const int n0 = blockIdx.x * 32, k0 = blockIdx.y * 32;
#pragma unroll
  for (int r = 0; r < 4; ++r)
    tile[ty + 8 * r][tx] = W[(size_t)(k0 + ty + 8 * r) * N + n0 + tx];
  __syncthreads();
#pragma unroll
  for (int r = 0; r < 4; ++r)
    Wt[(size_t)(n0 + ty + 8 * r) * K + k0 + tx] = f2bf(tile[tx][ty + 8 * r]);
}

// concat biases: bt = [bq, 0], bi = [bk, bv]
__global__ __launch_bounds__(256) void build_bias(const float* __restrict__ bq,
                                                  const float* __restrict__ bk,
                                                  const float* __restrict__ bv,
                                                  float* __restrict__ bt,
                                                  float* __restrict__ bi) {
  int i = blockIdx.x * 256 + threadIdx.x;
  if (i < 768) { bt[i] = bq[i]; bi[i] = bk[i]; }
  else if (i < 1536) { bt[i] = 0.f; bi[i] = bv[i - 768]; }
}

// ---------------- bf16 MFMA GEMM: C[M,N] = A[M,K] @ Bt[N,K]^T (+bias) ----------------
// 128x128 tile, 256 threads (4 waves, each 64x64 via 4x4 grid of 16x16x32 MFMAs).
__global__ __launch_bounds__(256) void gemm_mfma(
    const unsigned short* __restrict__ A,   // [M][K] bf16
    const unsigned short* __restrict__ Bt,  // [N][K] bf16 (= W^T)
    const float* __restrict__ bias, float* __restrict__ C,
    int M, int N, int K) {
  __shared__ unsigned short As[128][40];
  __shared__ unsigned short Bs[128][40];
  const int tid = threadIdx.x;
  const int lane = tid & 63;
  const int w = tid >> 6;
  const int quad = lane >> 4;
  const int l15 = lane & 15;
  const int row0 = blockIdx.y * 128;
  const int col0 = blockIdx.x * 128;
  const int m_off = (w & 1) * 64;
  const int n_off = (w >> 1) * 64;
  const int lr = tid >> 2;
  const int lc = (tid & 3) * 8;

  floatx4 acc[4][4] = {};

  for (int k0 = 0; k0 < K; k0 += 32) {
    const uint4 a0 = *(const uint4*)(A + (size_t)(row0 + lr) * K + k0 + lc);
    const uint4 a1 = *(const uint4*)(A + (size_t)(row0 + lr + 64) * K + k0 + lc);
    const uint4 b0 = *(const uint4*)(Bt + (size_t)(col0 + lr) * K + k0 + lc);
    const uint4 b1 = *(const uint4*)(Bt + (size_t)(col0 + lr + 64) * K + k0 + lc);
    __syncthreads();
    *(uint4*)&As[lr][lc] = a0;
    *(uint4*)&As[lr + 64][lc] = a1;
    *(uint4*)&Bs[lr][lc] = b0;
    *(uint4*)&Bs[lr + 64][lc] = b1;
    __syncthreads();
    short8 af[4], bfr[4];
#pragma unroll
    for (int i = 0; i < 4; ++i)
      af[i] = *(const short8*)&As[m_off + 16 * i + l15][quad * 8];
#pragma unroll
    for (int j = 0; j < 4; ++j)
      bfr[j] = *(const short8*)&Bs[n_off + 16 * j + l15][quad * 8];
#pragma unroll
    for (int i = 0; i < 4; ++i)
#pragma unroll
      for (int j = 0; j < 4; ++j)
        acc[i][j] = __builtin_amdgcn_mfma_f32_16x16x32_bf16(af[i], bfr[j], acc[i][j], 0, 0, 0);
  }

#pragma unroll
  for (int j = 0; j < 4; ++j) {
    const int cg = col0 + n_off + 16 * j + l15;
    const float bv = bias ? bias[cg] : 0.0f;
#pragma unroll
    for (int i = 0; i < 4; ++i) {
      const int rbase = row0 + m_off + 16 * i + quad * 4;
#pragma unroll
      for (int r = 0; r < 4; ++r)
        C[(size_t)(rbase + r) * N + cg] = acc[i][j][r] + bv;
    }
  }
}

// ---------------- MFMA cross attention: one block per (b,h), 4 waves ----------------
// qa: [B*T][1536] fp32 (q in cols 0..767). kv: [B*P][1536] fp32 (k 0..767, v 768..1535).
// Wave w computes t-rows [16w, 16w+16). attout bf16 [B*T][768].
__global__ __launch_bounds__(256) void attn_mfma(
    const float* __restrict__ qa, const float* __restrict__ kv,
    unsigned short* __restrict__ attout) {
  const int h = blockIdx.x, b = blockIdx.y;
  const int tid = threadIdx.x, lane = tid & 63, w = tid >> 6;
  const int quad = lane >> 4, l15 = lane & 15;

  __shared__ unsigned short Ks[196][72];     // K[p][d] bf16 (row pad to 72 shorts = 144 B)
  __shared__ unsigned short VT[64][232];     // V^T: VT[d][p]
  __shared__ unsigned short Ps[4][16][232];  // per-wave P (A-layout rows t_local)

  // ---- stage K and V^T from fp32 (convert to bf16) ----
  for (int i = tid; i < P * 64; i += 256) {
    const int p = i >> 6, d = i & 63;
    const float* row = kv + (size_t)(b * P + p) * 1536 + h * 64 + d;
    Ks[p][d] = f2bf(row[0]);
    VT[d][p] = f2bf(row[768]);
  }
  // zero-pad VT cols 196..223 (read by PV k-steps; P fragment is 0 there)
  if (tid < 64) {
    for (int c = 196; c < 224; ++c) VT[tid][c] = 0;
  }
  __syncthreads();

  // ---- Q fragments (fp32 -> bf16 pack), rows t = 16w + l15 ----
  short8 aq[2];
  {
    const float* qrow = qa + (size_t)(b * T + 16 * w + l15) * 1536 + h * 64;
#pragma unroll
    for (int ks = 0; ks < 2; ++ks) {
      const float4 x = *(const float4*)(qrow + 32 * ks + quad * 8);
      const float4 y = *(const float4*)(qrow + 32 * ks + quad * 8 + 4);
      short8 f;
      f[0] = (short)f2bf(x.x); f[1] = (short)f2bf(x.y);
      f[2] = (short)f2bf(x.z); f[3] = (short)f2bf(x.w);
      f[4] = (short)f2bf(y.x); f[5] = (short)f2bf(y.y);
      f[6] = (short)f2bf(y.z); f[7] = (short)f2bf(y.w);
      aq[ks] = f;
    }
  }

  // ---- QK^T: S[t][p], 13 p-tiles, K-dim 64 (2 k-steps) ----
  floatx4 sc[13];
#pragma unroll
  for (int tile = 0; tile < 13; ++tile) {
    int p = tile * 16 + l15;
    if (p > 195) p = 195;  // clamp (masked below)
    short8 bk0 = *(const short8*)&Ks[p][quad * 8];
    short8 bk1 = *(const short8*)&Ks[p][32 + quad * 8];
    floatx4 c = {};
    c = __builtin_amdgcn_mfma_f32_16x16x32_bf16(aq[0], bk0, c, 0, 0, 0);
    c = __builtin_amdgcn_mfma_f32_16x16x32_bf16(aq[1], bk1, c, 0, 0, 0);
    sc[tile] = c;
  }

  // ---- softmax over p (rows owned quad-locally: row = quad*4+r, col = l15) ----
  float mx[4] = {-3.4e38f, -3.4e38f, -3.4e38f, -3.4e38f};
#pragma unroll
  for (int tile = 0; tile < 13; ++tile)
#pragma unroll
    for (int r = 0; r < 4; ++r) {
      float s = sc[tile][r] * 0.125f;
      if (tile == 12 && l15 >= 4) s = -3.0e38f;  // p >= 196 invalid
      sc[tile][r] = s;
      mx[r] = fmaxf(mx[r], s);
    }
#pragma unroll
  for (int off = 1; off < 16; off <<= 1)
#pragma unroll
    for (int r = 0; r < 4; ++r) mx[r] = fmaxf(mx[r], __shfl_xor(mx[r], off));

  float sm[4] = {};
#pragma unroll
  for (int tile = 0; tile < 13; ++tile)
#pragma unroll
    for (int r = 0; r < 4; ++r) {
      float e = expf(sc[tile][r] - mx[r]);
      sc[tile][r] = e;
      sm[r] += e;
    }
#pragma unroll
  for (int off = 1; off < 16; off <<= 1)
#pragma unroll
    for (int r = 0; r < 4; ++r) sm[r] += __shfl_xor(sm[r], off);
  float inv[4];
#pragma unroll
  for (int r = 0; r < 4; ++r) inv[r] = 1.0f / sm[r];

  // ---- write P (bf16) into per-wave LDS in A-operand row layout ----
#pragma unroll
  for (int tile = 0; tile < 13; ++tile)
#pragma unroll
    for (int r = 0; r < 4; ++r)
      Ps[w][quad * 4 + r][tile * 16 + l15] = f2bf(sc[tile][r] * inv[r]);
#pragma unroll
  for (int r = 0; r < 4; ++r)
    Ps[w][quad * 4 + r][208 + l15] = 0;  // pad cols 208..223

  __syncthreads();

  // ---- PV: O[t][d] = sum_p P[t][p] V[p][d]; 4 d-tiles, 7 k-steps (k=p, padded 224) ----
  floatx4 oc[4] = {};
#pragma unroll
  for (int ks = 0; ks < 7; ++ks) {
    short8 pa = *(const short8*)&Ps[w][l15][ks * 32 + quad * 8];
#pragma unroll
    for (int nt = 0; nt < 4; ++nt) {
      short8 bv = *(const short8*)&VT[nt * 16 + l15][ks * 32 + quad * 8];
      oc[nt] = __builtin_amdgcn_mfma_f32_16x16x32_bf16(pa, bv, oc[nt], 0, 0, 0);
    }
  }

  // ---- epilogue: C-layout (col=l15 -> d_local, row=quad*4+r -> t_local) ----
#pragma unroll
  for (int nt = 0; nt < 4; ++nt)
#pragma unroll
    for (int r = 0; r < 4; ++r)
      attout[(size_t)(b * T + 16 * w + quad * 4 + r) * 768 + h * 64 + nt * 16 + l15] =
          f2bf(oc[nt][r]);
}

// ---------------- s_token + f_token ----------------
__global__ __launch_bounds__(256) void token_kernel(
    const float* __restrict__ upd, const float* __restrict__ img,
    float* __restrict__ f_token, float* __restrict__ s_token) {
  const int b = blockIdx.x, tid = threadIdx.x;
  for (int d = tid; d < D; d += 256) {
    float s = 0.f;
    for (int t = 0; t < T; ++t) s += upd[((size_t)(b * T + t)) * D + d];
    f_token[b * D + d] = s * (1.0f / T);
  }
  float part = 0.f;
  for (int idx = tid; idx < T * D; idx += 256) {
    int t = idx / D, d = idx - t * D;
    part += upd[((size_t)(b * T + t)) * D + d] * img[((size_t)(b * P + t)) * D + d];
  }
  part = wave_sum(part);
  __shared__ float red[4];
  if ((tid & 63) == 0) red[tid >> 6] = part;
  __syncthreads();
  if (tid == 0) s_token[b] = (red[0] + red[1] + red[2] + red[3]) * (1.0f / T);
}

// ---------------- text GAT: one block (2 waves) per (b,h). N=64 ----------------
__global__ __launch_bounds__(128) void text_gat_kernel(
    const float* __restrict__ Wh, int ldw, const int* __restrict__ adj,
    const float* __restrict__ at, float* __restrict__ tgf) {
  const int h = blockIdx.x, b = blockIdx.y;
  const int tid = threadIdx.x, lane = tid & 63, w = tid >> 6;
  __shared__ float WhT[64][68];       // WhT[f][n]
  __shared__ float atts[2][8][68];
  __shared__ float srcs[64], dsts[64];
  __shared__ float redc[2][64];
  __shared__ float asv[64], adv[64];

  if (tid < 64) { asv[tid] = at[tid]; adv[tid] = at[64 + tid]; }
  for (int idx = tid; idx < 64 * 64; idx += 128) {
    int n = idx >> 6, f = idx & 63;
    WhT[f][n] = Wh[(size_t)(b * T + n) * ldw + h * 64 + f];
  }
  __syncthreads();

  if (tid < 64) {
    float s = 0.f, dd = 0.f;
#pragma unroll 8
    for (int f = 0; f < 64; ++f) {
      float wv = WhT[f][tid];
      s += wv * asv[f];
      dd += wv * adv[f];
    }
    srcs[tid] = s;
    dsts[tid] = dd;
  }
  __syncthreads();

  const int* adjb = adj + b * T * T;
  float macc = 0.f;
  for (int g = 0; g < 4; ++g) {
#pragma unroll
    for (int r = 0; r < 8; ++r) {
      const int i = w * 32 + g * 8 + r;
      float e = srcs[i] + dsts[lane];
      e = (e >= 0.f) ? e : 0.2f * e;
      if (adjb[i * 64 + lane] == 0) e = -9e15f;
      const float m = wave_max(e);
      float pp = expf(e - m);
      const float inv = 1.0f / wave_sum(pp);
      atts[w][r][lane] = pp * inv;
    }
    float acc[8] = {};
    for (int jq = 0; jq < 16; ++jq) {
      const float4 whv = *(const float4*)&WhT[lane][4 * jq];
#pragma unroll
      for (int r = 0; r < 8; ++r) {
        const float4 av = *(const float4*)&atts[w][r][4 * jq];
        acc[r] += av.x * whv.x + av.y * whv.y + av.z * whv.z + av.w * whv.w;
      }
    }
#pragma unroll
    for (int r = 0; r < 8; ++r)
      macc += (acc[r] > 0.f) ? acc[r] : (expf(acc[r]) - 1.0f);
  }

  redc[w][lane] = macc;
  __syncthreads();
  if (w == 0)
    tgf[b * D + h * 64 + lane] = (redc[0][lane] + redc[1][lane]) * (1.0f / T);
}

// ---------------- image GAT via MFMA: one block (4 waves) per (b,h). N=196 ----------------
// hp = att @ Wh is the attention-PV pattern: unnormalized exp scores -> A-layout LDS,
// Wh^T bf16 as B-operand; row-normalization folded into epilogue (before elu).
__global__ __launch_bounds__(256) void image_gat_mfma(
    const float* __restrict__ Wh, const int* __restrict__ adj,
    const float* __restrict__ ai, float* __restrict__ igf) {
  const int h = blockIdx.x, b = blockIdx.y;
  const int tid = threadIdx.x, lane = tid & 63, w = tid >> 6;
  const int quad = lane >> 4, l15 = lane & 15;

  __shared__ unsigned short VT[64][232];     // Wh^T bf16: VT[f][n]
  __shared__ unsigned short Ps[4][16][232];  // per-wave unnormalized att rows (A-layout)
  __shared__ float srcs[196], dsts[196];
  __shared__ float winv[4][16];              // per-wave row inverse sums
  __shared__ float redc[4][64];
  __shared__ float asv[64], adv[64];

  if (tid < 64) { asv[tid] = ai[tid]; adv[tid] = ai[64 + tid]; }
  for (int i = tid; i < P * 64; i += 256) {
    const int n = i >> 6, f = i & 63;
    VT[f][n] = f2bf(Wh[(size_t)(b * P + n) * 768 + h * 64 + f]);
  }
  if (tid < 64)
    for (int c = 196; c < 224; ++c) VT[tid][c] = 0;  // pad for PV k-steps
  __syncthreads();

  // src/dst per node (196 threads active); |e| stays ~O(0.5) -> exp safe without max-sub
  if (tid < P) {
    float s = 0.f, dd = 0.f;
#pragma unroll 8
    for (int f = 0; f < 64; ++f) {
      const float wv = __uint_as_float((unsigned)VT[f][tid] << 16);
      s += wv * asv[f];
      dd += wv * adv[f];
    }
    srcs[tid] = s;
    dsts[tid] = dd;
  }
  __syncthreads();

  float accd[4] = {};  // col accumulators: d = nt*16 + l15, summed over rows

  // 13 row-tiles of 16; wave w handles tiles w, w+4, w+8 (, 12 for w==0)
  for (int tile = w; tile < 13; tile += 4) {
    const int i = tile * 16 + l15;           // score-phase row for this lane
    const bool irow_ok = (i < P);
    const int i_eff = irow_ok ? i : (P - 1);
    const float si = srcs[i_eff];
    const int* ar = adj + i_eff * P;

    // scores: lane covers j = 4*jj + quad; write unnormalized exp to Ps
    float sm = 0.f;
#pragma unroll 7
    for (int jj = 0; jj < 49; ++jj) {
      const int j = 4 * jj + quad;
      float e = si + dsts[j];
      e = (e >= 0.f) ? e : 0.2f * e;
      float p = (irow_ok && ar[j] != 0) ? expf(e) : 0.f;
      sm += p;
      Ps[w][l15][j] = f2bf(p);
    }
    // pad cols 196..223
#pragma unroll
    for (int c = 196 + quad; c < 224; c += 4) Ps[w][l15][c] = 0;

    // row sum across quads (lanes same l15)
    sm += __shfl_xor(sm, 16);
    sm += __shfl_xor(sm, 32);
    if (quad == 0) winv[w][l15] = (sm > 0.f) ? 1.0f / sm : 0.f;

    // PV-style MFMA: O[i_local][d] = sum_j p[i_local][j] * Wh[j][d]
    floatx4 oc[4] = {};
#pragma unroll
    for (int ks = 0; ks < 7; ++ks) {
      const short8 pa = *(const short8*)&Ps[w][l15][ks * 32 + quad * 8];
#pragma unroll
      for (int nt = 0; nt < 4; ++nt) {
        const short8 bv = *(const short8*)&VT[nt * 16 + l15][ks * 32 + quad * 8];
        oc[nt] = __builtin_amdgcn_mfma_f32_16x16x32_bf16(pa, bv, oc[nt], 0, 0, 0);
      }
    }

    // epilogue: lane's output rows io = tile*16 + quad*4 + r, col = nt*16 + l15.
    // normalize (linear) then elu, accumulate col sums.
#pragma unroll
    for (int r = 0; r < 4; ++r) {
      const int io = tile * 16 + quad * 4 + r;
      if (io < P) {
        const float inv = winv[w][quad * 4 + r];
#pragma unroll
        for (int nt = 0; nt < 4; ++nt) {
          const float hp = oc[nt][r] * inv;
          accd[nt] += (hp > 0.f) ? hp : (expf(hp) - 1.0f);
        }
      }
    }
  }

  // reduce across quads (same col), store per wave, then across waves
#pragma unroll
  for (int nt = 0; nt < 4; ++nt) {
    accd[nt] += __shfl_xor(accd[nt], 16);
    accd[nt] += __shfl_xor(accd[nt], 32);
  }
  if (quad == 0) {
#pragma unroll
    for (int nt = 0; nt < 4; ++nt) redc[w][nt * 16 + l15] = accd[nt];
  }
  __syncthreads();
  if (w == 0) {
    const float tot = redc[0][lane] + redc[1][lane] + redc[2][lane] + redc[3][lane];
    igf[b * D + h * 64 + lane] = tot * (1.0f / P);
  }
}

// ---------------- f_global = clip_t @ Wp + bp : grid (12, B) ----------------
__global__ __launch_bounds__(256) void fglob_kernel(
    const float* __restrict__ clip_t, const float* __restrict__ Wp,
    const float* __restrict__ bp, float* __restrict__ fglob) {
  const int jt = blockIdx.x, b = blockIdx.y;
  const int j = threadIdx.x & 63, kc = threadIdx.x >> 6;
  float s = 0.f;
  const float* ct = clip_t + b * 512;
#pragma unroll 4
  for (int k = kc * 128; k < kc * 128 + 128; ++k)
    s += ct[k] * Wp[(size_t)k * D + jt * 64 + j];
  __shared__ float red[4][64];
  red[kc][j] = s;
  __syncthreads();
  if (kc == 0)
    fglob[b * D + jt * 64 + j] = red[0][j] + red[1][j] + red[2][j] + red[3][j] + bp[jt * 64 + j];
}

// ---------------- final fusion kernel: one block per b ----------------
__device__ __forceinline__ float block_sum(float v, float* red4) {
  v = wave_sum(v);
  __syncthreads();
  if ((threadIdx.x & 63) == 0) red4[threadIdx.x >> 6] = v;
  __syncthreads();
  return red4[0] + red4[1] + red4[2] + red4[3];
}

__global__ __launch_bounds__(256) void final_kernel(
    const float* __restrict__ tgf, const float* __restrict__ igf,
    const float* __restrict__ clip_t, const float* __restrict__ clip_i,
    const float* __restrict__ logit_scale, const float* __restrict__ s_token,
    const float* __restrict__ f_token, const float* __restrict__ fglob,
    const float* __restrict__ f1w, const float* __restrict__ f1b,
    const float* __restrict__ f2w, const float* __restrict__ f2b,
    const float* __restrict__ c1w, const float* __restrict__ c1b,
    const float* __restrict__ c2w, const float* __restrict__ c2b,
    float* __restrict__ out) {
  const int b = blockIdx.x, tid = threadIdx.x;
  __shared__ float red[4];
  __shared__ float sres[4];
  __shared__ float fagg[768];
  __shared__ float hid[384];

  float d0 = 0.f, d1 = 0.f, d2 = 0.f;
  for (int i = tid; i < D; i += 256) {
    float x = tgf[b * D + i], y = igf[b * D + i];
    d0 += x * y; d1 += x * x; d2 += y * y;
  }
  float dot_ti = block_sum(d0, red);
  float n_t = sqrtf(block_sum(d1, red));
  float n_i = sqrtf(block_sum(d2, red));
  float s_phrase = dot_ti / (fmaxf(n_t, 1e-8f) * fmaxf(n_i, 1e-8f));

  float c0 = 0.f, c1 = 0.f, c2 = 0.f;
  for (int i = tid; i < 512; i += 256) {
    float x = clip_t[b * 512 + i], y = clip_i[b * 512 + i];
    c0 += x * y; c1 += x * x; c2 += y * y;
  }
  float dc = block_sum(c0, red);
  float nt2 = sqrtf(block_sum(c1, red));
  float ni2 = sqrtf(block_sum(c2, red));
  float s_global = expf(logit_scale[0]) * dc / (fmaxf(nt2, 1e-8f) * fmaxf(ni2, 1e-8f));

  if (tid == 0) {
    float s3[3] = { s_token[b], s_phrase, s_global };
    float h1[16];
    for (int j = 0; j < 16; ++j) {
      float a = f1b[j];
      for (int i2 = 0; i2 < 3; ++i2) a += s3[i2] * f1w[i2 * 16 + j];
      h1[j] = 0.5f * a * (1.0f + erff(a * 0.70710678118654752f));
    }
    for (int j = 0; j < 3; ++j) {
      float a = f2b[j];
      for (int i2 = 0; i2 < 16; ++i2) a += h1[i2] * f2w[i2 * 3 + j];
      sres[j] = 1.0f / (1.0f + expf(-a));
    }
  }
  __syncthreads();
  float w0 = sres[0], w1 = sres[1], w2 = sres[2];

  for (int j = tid; j < D; j += 256)
    fagg[j] = w0 * f_token[b * D + j] + w1 * tgf[b * D + j] + w2 * fglob[b * D + j];
  __syncthreads();

  for (int j = tid; j < 384; j += 256) {
    float a = c1b[j];
    for (int k2 = 0; k2 < D; ++k2) a += fagg[k2] * c1w[k2 * 384 + j];
    hid[j] = fmaxf(a, 0.0f);
  }
  __syncthreads();

  float p0 = 0.f, p1 = 0.f;
  for (int k2 = tid; k2 < 384; k2 += 256) {
    p0 += hid[k2] * c2w[k2 * 2 + 0];
    p1 += hid[k2] * c2w[k2 * 2 + 1];
  }
  p0 = block_sum(p0, red);
  p1 = block_sum(p1, red);
  if (tid == 0) {
    out[b * 2 + 0] = p0 + c2b[0];
    out[b * 2 + 1] = p1 + c2b[1];
  }
}

// ---------------- launch ----------------
extern "C" void kernel_launch(void* const* d_in, const int* in_sizes, int n_in,
                              void* d_out, int out_size, void* d_ws, size_t ws_size,
                              hipStream_t stream) {
  const float* text   = (const float*)d_in[0];
  const float* img    = (const float*)d_in[1];
  const float* clip_t = (const float*)d_in[2];
  const float* clip_i = (const float*)d_in[3];
  const float* lscale = (const float*)d_in[4];
  const float* wq = (const float*)d_in[5];
  const float* bq = (const float*)d_in[6];
  const float* wk = (const float*)d_in[7];
  const float* bk = (const float*)d_in[8];
  const float* wv = (const float*)d_in[9];
  const float* bv = (const float*)d_in[10];
  const float* wo = (const float*)d_in[11];
  const float* bo = (const float*)d_in[12];
  const float* Wt = (const float*)d_in[13];
  const float* at = (const float*)d_in[14];
  const float* Wi = (const float*)d_in[15];
  const float* ai = (const float*)d_in[16];
  const float* Wp = (const float*)d_in[17];
  const float* bp = (const float*)d_in[18];
  const float* f1w = (const float*)d_in[19];
  const float* f1b = (const float*)d_in[20];
  const float* f2w = (const float*)d_in[21];
  const float* f2b = (const float*)d_in[22];
  const float* c1w = (const float*)d_in[23];
  const float* c1b = (const float*)d_in[24];
  const float* c2w = (const float*)d_in[25];
  const float* c2b = (const float*)d_in[26];
  const int* text_adj  = (const int*)d_in[27];
  const int* image_adj = (const int*)d_in[28];
  float* out = (float*)d_out;

  const size_t nTD = (size_t)B * T * D;   // 1,572,864
  const size_t nPD = (size_t)B * P * D;   // 4,816,896
  const size_t nWW = (size_t)D * D;       // 589,824

  // workspace layout: fp32 buffers first, then bf16 (identical to round 3/6)
  float* fbuf = (float*)d_ws;
  size_t o = 0;
  float* kv_buf = fbuf + o; o += 2 * nPD;  // [B*P][1536]: k|v ; first nPD reused as Wh_i
  float* qa_buf = fbuf + o; o += 2 * nTD;  // [B*T][1536]: q|Wh_t
  float* upd    = fbuf + o; o += nTD;
  float* ftok   = fbuf + o; o += (size_t)B * D;
  float* stok   = fbuf + o; o += 32;
  float* tgf    = fbuf + o; o += (size_t)B * D;
  float* igf    = fbuf + o; o += (size_t)B * D;
  float* fglob  = fbuf + o; o += (size_t)B * D;
  float* bcat_t = fbuf + o; o += 1536;
  float* bcat_i = fbuf + o; o += 1536;
  unsigned short* sbuf = (unsigned short*)(fbuf + o);
  size_t so = 0;
  unsigned short* text_bf  = sbuf + so; so += nTD;
  unsigned short* img_bf   = sbuf + so; so += nPD;
  unsigned short* att_bf   = sbuf + so; so += nTD;
  unsigned short* wcat_txt = sbuf + so; so += 2 * nWW;  // wq^T | Wt^T
  unsigned short* wcat_img = sbuf + so; so += 2 * nWW;  // wk^T | wv^T
  unsigned short* wo_t     = sbuf + so; so += nWW;
  unsigned short* wi_t     = sbuf + so; so += nWW;

  // ---- weight casts (one fused launch) + bias concat ----
  WPack wp;
  wp.src[0] = wq; wp.dst[0] = wcat_txt;
  wp.src[1] = Wt; wp.dst[1] = wcat_txt + nWW;
  wp.src[2] = wk; wp.dst[2] = wcat_img;
  wp.src[3] = wv; wp.dst[3] = wcat_img + nWW;
  wp.src[4] = wo; wp.dst[4] = wo_t;
  wp.src[5] = Wi; wp.dst[5] = wi_t;
  cast_transpose6<<<dim3(D / 32, D / 32, 6), 256, 0, stream>>>(wp, D, D);
  build_bias<<<6, 256, 0, stream>>>(bq, bk, bv, bcat_t, bcat_i);
  cast_rows<<<(int)(nTD / 4 + 255) / 256, 256, 0, stream>>>(text, text_bf, (int)(nTD / 4));
  cast_rows<<<(int)(nPD / 4 + 255) / 256, 256, 0, stream>>>(img, img_bf, (int)(nPD / 4));

  const int MT = B * T;   // 2048
  const int MP = B * P;   // 6272

  // ---- fused projections ----
  gemm_mfma<<<dim3(1536 / 128, MT / 128), 256, 0, stream>>>(text_bf, wcat_txt, bcat_t, qa_buf, MT, 1536, D);
  gemm_mfma<<<dim3(1536 / 128, MP / 128), 256, 0, stream>>>(img_bf, wcat_img, bcat_i, kv_buf, MP, 1536, D);

  fglob_kernel<<<dim3(12, B), 256, 0, stream>>>(clip_t, Wp, bp, fglob);

  attn_mfma<<<dim3(H, B), 256, 0, stream>>>(qa_buf, kv_buf, att_bf);

  gemm_mfma<<<dim3(D / 128, MT / 128), 256, 0, stream>>>(att_bf, wo_t, bo, upd, MT, D, D);
  // Wh_i GEMM reuses kv_buf (attention done with k,v)
  float* whi = kv_buf;
  gemm_mfma<<<dim3(D / 128, MP / 128), 256, 0, stream>>>(img_bf, wi_t, nullptr, whi, MP, D, D);

  token_kernel<<<B, 256, 0, stream>>>(upd, img, ftok, stok);
  text_gat_kernel<<<dim3(H, B), 128, 0, stream>>>(qa_buf + 768, 1536, text_adj, at, tgf);
  // image GAT via MFMA — the ONLY change vs round 6
  image_gat_mfma<<<dim3(H, B), 256, 0, stream>>>(whi, image_adj, ai, igf);
  final_kernel<<<B, 256, 0, stream>>>(tgf, igf, clip_t, clip_i, lscale, stok, ftok, fglob,
                                      f1w, f1b, f2w, f2b, c1w, c1b, c2w, c2b, out);
}

// Round 8
// 416.311 us; speedup vs baseline: 3.4656x; 1.2240x over previous
//
#include <hip/hip_runtime.h>
#include <hip/hip_bf16.h>
#include <math.h>

// Problem constants
#define B 32
#define T 64
#define P 196
#define D 768
#define H 12

typedef __attribute__((ext_vector_type(8))) short short8;
typedef __attribute__((ext_vector_type(4))) float floatx4;

// ---------------- helpers ----------------
__device__ __forceinline__ float wave_sum(float v) {
#pragma unroll
  for (int o = 32; o > 0; o >>= 1) v += __shfl_xor(v, o);
  return v;
}
__device__ __forceinline__ float wave_max(float v) {
#pragma unroll
  for (int o = 32; o > 0; o >>= 1) v = fmaxf(v, __shfl_xor(v, o));
  return v;
}
__device__ __forceinline__ unsigned short f2bf(float x) {
  unsigned u = __float_as_uint(x);
  u += 0x7FFFu + ((u >> 16) & 1u);   // round-to-nearest-even
  return (unsigned short)(u >> 16);
}

// ---------------- cast kernels ----------------
__global__ __launch_bounds__(256) void cast_rows(const float* __restrict__ X,
                                                 unsigned short* __restrict__ Y, int n4) {
  int i = blockIdx.x * 256 + threadIdx.x;
  if (i < n4) {
    float4 vv = ((const float4*)X)[i];
    ushort4 o;
    o.x = f2bf(vv.x); o.y = f2bf(vv.y); o.z = f2bf(vv.z); o.w = f2bf(vv.w);
    ((ushort4*)Y)[i] = o;
  }
}

// 6 weights fp32 [K][N] -> bf16 [N][K], one fused launch (grid.z = weight idx)
struct WPack {
  const float* src[6];
  unsigned short* dst[6];
};
__global__ __launch_bounds__(256) void cast_transpose6(WPack p, int K, int N) {
  __shared__ float tile[32][33];
  const float* W = p.src[blockIdx.z];
  unsigned short* Wt = p.dst[blockIdx.z];
  const int tx = threadIdx.x & 31, ty = threadIdx.x >> 5;  // ty 0..7
  const int n0 = blockIdx.x * 32, k0 = blockIdx.y * 32;
#pragma unroll
  for (int r = 0; r < 4; ++r)
    tile[ty + 8 * r][tx] = W[(size_t)(k0 + ty + 8 * r) * N + n0 + tx];
  __syncthreads();
#pragma unroll
  for (int r = 0; r < 4; ++r)
    Wt[(size_t)(n0 + ty + 8 * r) * K + k0 + tx] = f2bf(tile[tx][ty + 8 * r]);
}

// concat biases: bt = [bq, 0], bi = [bk, bv]; also zero s_token accumulator
__global__ __launch_bounds__(256) void build_bias(const float* __restrict__ bq,
                                                  const float* __restrict__ bk,
                                                  const float* __restrict__ bv,
                                                  float* __restrict__ bt,
                                                  float* __restrict__ bi,
                                                  float* __restrict__ stok) {
  int i = blockIdx.x * 256 + threadIdx.x;
  if (i < 32) stok[i] = 0.f;
  if (i < 768) { bt[i] = bq[i]; bi[i] = bk[i]; }
  else if (i < 1536) { bt[i] = 0.f; bi[i] = bv[i - 768]; }
}

// ---------------- bf16 MFMA GEMM: C[M,N] = A[M,K] @ Bt[N,K]^T (+bias) ----------------
__global__ __launch_bounds__(256) void gemm_mfma(
    const unsigned short* __restrict__ A,   // [M][K] bf16
    const unsigned short* __restrict__ Bt,  // [N][K] bf16 (= W^T)
    const float* __restrict__ bias, float* __restrict__ C,
    int M, int N, int K) {
  __shared__ unsigned short As[128][40];
  __shared__ unsigned short Bs[128][40];
  const int tid = threadIdx.x;
  const int lane = tid & 63;
  const int w = tid >> 6;
  const int quad = lane >> 4;
  const int l15 = lane & 15;
  const int row0 = blockIdx.y * 128;
  const int col0 = blockIdx.x * 128;
  const int m_off = (w & 1) * 64;
  const int n_off = (w >> 1) * 64;
  const int lr = tid >> 2;
  const int lc = (tid & 3) * 8;

  floatx4 acc[4][4] = {};

  for (int k0 = 0; k0 < K; k0 += 32) {
    const uint4 a0 = *(const uint4*)(A + (size_t)(row0 + lr) * K + k0 + lc);
    const uint4 a1 = *(const uint4*)(A + (size_t)(row0 + lr + 64) * K + k0 + lc);
    const uint4 b0 = *(const uint4*)(Bt + (size_t)(col0 + lr) * K + k0 + lc);
    const uint4 b1 = *(const uint4*)(Bt + (size_t)(col0 + lr + 64) * K + k0 + lc);
    __syncthreads();
    *(uint4*)&As[lr][lc] = a0;
    *(uint4*)&As[lr + 64][lc] = a1;
    *(uint4*)&Bs[lr][lc] = b0;
    *(uint4*)&Bs[lr + 64][lc] = b1;
    __syncthreads();
    short8 af[4], bfr[4];
#pragma unroll
    for (int i = 0; i < 4; ++i)
      af[i] = *(const short8*)&As[m_off + 16 * i + l15][quad * 8];
#pragma unroll
    for (int j = 0; j < 4; ++j)
      bfr[j] = *(const short8*)&Bs[n_off + 16 * j + l15][quad * 8];
#pragma unroll
    for (int i = 0; i < 4; ++i)
#pragma unroll
      for (int j = 0; j < 4; ++j)
        acc[i][j] = __builtin_amdgcn_mfma_f32_16x16x32_bf16(af[i], bfr[j], acc[i][j], 0, 0, 0);
  }

#pragma unroll
  for (int j = 0; j < 4; ++j) {
    const int cg = col0 + n_off + 16 * j + l15;
    const float bv = bias ? bias[cg] : 0.0f;
#pragma unroll
    for (int i = 0; i < 4; ++i) {
      const int rbase = row0 + m_off + 16 * i + quad * 4;
#pragma unroll
      for (int r = 0; r < 4; ++r)
        C[(size_t)(rbase + r) * N + cg] = acc[i][j][r] + bv;
    }
  }
}

// ---------------- MFMA cross attention: one block per (b,h), 4 waves ----------------
__global__ __launch_bounds__(256) void attn_mfma(
    const float* __restrict__ qa, const float* __restrict__ kv,
    unsigned short* __restrict__ attout) {
  const int h = blockIdx.x, b = blockIdx.y;
  const int tid = threadIdx.x, lane = tid & 63, w = tid >> 6;
  const int quad = lane >> 4, l15 = lane & 15;

  __shared__ unsigned short Ks[196][72];     // K[p][d] bf16
  __shared__ unsigned short VT[64][232];     // V^T: VT[d][p]
  __shared__ unsigned short Ps[4][16][232];  // per-wave P (A-layout rows t_local)

  for (int i = tid; i < P * 64; i += 256) {
    const int p = i >> 6, d = i & 63;
    const float* row = kv + (size_t)(b * P + p) * 1536 + h * 64 + d;
    Ks[p][d] = f2bf(row[0]);
    VT[d][p] = f2bf(row[768]);
  }
  if (tid < 64) {
    for (int c = 196; c < 224; ++c) VT[tid][c] = 0;
  }
  __syncthreads();

  short8 aq[2];
  {
    const float* qrow = qa + (size_t)(b * T + 16 * w + l15) * 1536 + h * 64;
#pragma unroll
    for (int ks = 0; ks < 2; ++ks) {
      const float4 x = *(const float4*)(qrow + 32 * ks + quad * 8);
      const float4 y = *(const float4*)(qrow + 32 * ks + quad * 8 + 4);
      short8 f;
      f[0] = (short)f2bf(x.x); f[1] = (short)f2bf(x.y);
      f[2] = (short)f2bf(x.z); f[3] = (short)f2bf(x.w);
      f[4] = (short)f2bf(y.x); f[5] = (short)f2bf(y.y);
      f[6] = (short)f2bf(y.z); f[7] = (short)f2bf(y.w);
      aq[ks] = f;
    }
  }

  floatx4 sc[13];
#pragma unroll
  for (int tile = 0; tile < 13; ++tile) {
    int p = tile * 16 + l15;
    if (p > 195) p = 195;
    short8 bk0 = *(const short8*)&Ks[p][quad * 8];
    short8 bk1 = *(const short8*)&Ks[p][32 + quad * 8];
    floatx4 c = {};
    c = __builtin_amdgcn_mfma_f32_16x16x32_bf16(aq[0], bk0, c, 0, 0, 0);
    c = __builtin_amdgcn_mfma_f32_16x16x32_bf16(aq[1], bk1, c, 0, 0, 0);
    sc[tile] = c;
  }

  float mx[4] = {-3.4e38f, -3.4e38f, -3.4e38f, -3.4e38f};
#pragma unroll
  for (int tile = 0; tile < 13; ++tile)
#pragma unroll
    for (int r = 0; r < 4; ++r) {
      float s = sc[tile][r] * 0.125f;
      if (tile == 12 && l15 >= 4) s = -3.0e38f;
      sc[tile][r] = s;
      mx[r] = fmaxf(mx[r], s);
    }
#pragma unroll
  for (int off = 1; off < 16; off <<= 1)
#pragma unroll
    for (int r = 0; r < 4; ++r) mx[r] = fmaxf(mx[r], __shfl_xor(mx[r], off));

  float sm[4] = {};
#pragma unroll
  for (int tile = 0; tile < 13; ++tile)
#pragma unroll
    for (int r = 0; r < 4; ++r) {
      float e = expf(sc[tile][r] - mx[r]);
      sc[tile][r] = e;
      sm[r] += e;
    }
#pragma unroll
  for (int off = 1; off < 16; off <<= 1)
#pragma unroll
    for (int r = 0; r < 4; ++r) sm[r] += __shfl_xor(sm[r], off);
  float inv[4];
#pragma unroll
  for (int r = 0; r < 4; ++r) inv[r] = 1.0f / sm[r];

#pragma unroll
  for (int tile = 0; tile < 13; ++tile)
#pragma unroll
    for (int r = 0; r < 4; ++r)
      Ps[w][quad * 4 + r][tile * 16 + l15] = f2bf(sc[tile][r] * inv[r]);
#pragma unroll
  for (int r = 0; r < 4; ++r)
    Ps[w][quad * 4 + r][208 + l15] = 0;

  __syncthreads();

  floatx4 oc[4] = {};
#pragma unroll
  for (int ks = 0; ks < 7; ++ks) {
    short8 pa = *(const short8*)&Ps[w][l15][ks * 32 + quad * 8];
#pragma unroll
    for (int nt = 0; nt < 4; ++nt) {
      short8 bv = *(const short8*)&VT[nt * 16 + l15][ks * 32 + quad * 8];
      oc[nt] = __builtin_amdgcn_mfma_f32_16x16x32_bf16(pa, bv, oc[nt], 0, 0, 0);
    }
  }

#pragma unroll
  for (int nt = 0; nt < 4; ++nt)
#pragma unroll
    for (int r = 0; r < 4; ++r)
      attout[(size_t)(b * T + 16 * w + quad * 4 + r) * 768 + h * 64 + nt * 16 + l15] =
          f2bf(oc[nt][r]);
}

// ---------------- token: grid (12, B). f_token slice + s_token partial ----------------
__global__ __launch_bounds__(256) void token_kernel(
    const float* __restrict__ upd, const float* __restrict__ img,
    float* __restrict__ f_token, float* __restrict__ s_token) {
  const int jt = blockIdx.x, b = blockIdx.y;
  const int l = threadIdx.x & 63, tg = threadIdx.x >> 6;
  const int d = jt * 64 + l;
  float fs = 0.f, ss = 0.f;
#pragma unroll 4
  for (int tt = 0; tt < 16; ++tt) {
    const int t = tg * 16 + tt;
    const float u = upd[(size_t)(b * T + t) * D + d];
    fs += u;
    ss += u * img[(size_t)(b * P + t) * D + d];
  }
  __shared__ float red[4][64];
  __shared__ float sred[4];
  red[tg][l] = fs;
  const float sw = wave_sum(ss);  // over 64 d-lanes of this wave
  if (l == 0) sred[tg] = sw;
  __syncthreads();
  if (tg == 0) {
    f_token[(size_t)b * D + d] =
        (red[0][l] + red[1][l] + red[2][l] + red[3][l]) * (1.0f / T);
    if (threadIdx.x == 0)
      atomicAdd(&s_token[b], (sred[0] + sred[1] + sred[2] + sred[3]) * (1.0f / T));
  }
}

// ---------------- text GAT: one block (2 waves) per (b,h). N=64 ----------------
__global__ __launch_bounds__(128) void text_gat_kernel(
    const float* __restrict__ Wh, int ldw, const int* __restrict__ adj,
    const float* __restrict__ at, float* __restrict__ tgf) {
  const int h = blockIdx.x, b = blockIdx.y;
  const int tid = threadIdx.x, lane = tid & 63, w = tid >> 6;
  __shared__ float WhT[64][68];       // WhT[f][n]
  __shared__ float atts[2][8][68];
  __shared__ float srcs[64], dsts[64];
  __shared__ float redc[2][64];
  __shared__ float asv[64], adv[64];

  if (tid < 64) { asv[tid] = at[tid]; adv[tid] = at[64 + tid]; }
  for (int idx = tid; idx < 64 * 64; idx += 128) {
    int n = idx >> 6, f = idx & 63;
    WhT[f][n] = Wh[(size_t)(b * T + n) * ldw + h * 64 + f];
  }
  __syncthreads();

  if (tid < 64) {
    float s = 0.f, dd = 0.f;
#pragma unroll 8
    for (int f = 0; f < 64; ++f) {
      float wv = WhT[f][tid];
      s += wv * asv[f];
      dd += wv * adv[f];
    }
    srcs[tid] = s;
    dsts[tid] = dd;
  }
  __syncthreads();

  const int* adjb = adj + b * T * T;
  float macc = 0.f;
  for (int g = 0; g < 4; ++g) {
#pragma unroll
    for (int r = 0; r < 8; ++r) {
      const int i = w * 32 + g * 8 + r;
      float e = srcs[i] + dsts[lane];
      e = (e >= 0.f) ? e : 0.2f * e;
      if (adjb[i * 64 + lane] == 0) e = -9e15f;
      const float m = wave_max(e);
      float pp = expf(e - m);
      const float inv = 1.0f / wave_sum(pp);
      atts[w][r][lane] = pp * inv;
    }
    float acc[8] = {};
    for (int jq = 0; jq < 16; ++jq) {
      const float4 whv = *(const float4*)&WhT[lane][4 * jq];
#pragma unroll
      for (int r = 0; r < 8; ++r) {
        const float4 av = *(const float4*)&atts[w][r][4 * jq];
        acc[r] += av.x * whv.x + av.y * whv.y + av.z * whv.z + av.w * whv.w;
      }
    }
#pragma unroll
    for (int r = 0; r < 8; ++r)
      macc += (acc[r] > 0.f) ? acc[r] : (expf(acc[r]) - 1.0f);
  }

  redc[w][lane] = macc;
  __syncthreads();
  if (w == 0)
    tgf[b * D + h * 64 + lane] = (redc[0][lane] + redc[1][lane]) * (1.0f / T);
}

// ---------------- image GAT via MFMA: one block (4 waves) per (b,h). N=196 ----------------
__global__ __launch_bounds__(256) void image_gat_mfma(
    const float* __restrict__ Wh, const int* __restrict__ adj,
    const float* __restrict__ ai, float* __restrict__ igf) {
  const int h = blockIdx.x, b = blockIdx.y;
  const int tid = threadIdx.x, lane = tid & 63, w = tid >> 6;
  const int quad = lane >> 4, l15 = lane & 15;

  __shared__ unsigned short VT[64][232];     // Wh^T bf16: VT[f][n]
  __shared__ unsigned short Ps[4][16][232];  // per-wave unnormalized att rows (A-layout)
  __shared__ float srcs[196], dsts[196];
  __shared__ float winv[4][16];
  __shared__ float redc[4][64];
  __shared__ float asv[64], adv[64];

  if (tid < 64) { asv[tid] = ai[tid]; adv[tid] = ai[64 + tid]; }
  for (int i = tid; i < P * 64; i += 256) {
    const int n = i >> 6, f = i & 63;
    VT[f][n] = f2bf(Wh[(size_t)(b * P + n) * 768 + h * 64 + f]);
  }
  if (tid < 64)
    for (int c = 196; c < 224; ++c) VT[tid][c] = 0;
  __syncthreads();

  if (tid < P) {
    float s = 0.f, dd = 0.f;
#pragma unroll 8
    for (int f = 0; f < 64; ++f) {
      const float wv = __uint_as_float((unsigned)VT[f][tid] << 16);
      s += wv * asv[f];
      dd += wv * adv[f];
    }
    srcs[tid] = s;
    dsts[tid] = dd;
  }
  __syncthreads();

  float accd[4] = {};

  for (int tile = w; tile < 13; tile += 4) {
    const int i = tile * 16 + l15;
    const bool irow_ok = (i < P);
    const int i_eff = irow_ok ? i : (P - 1);
    const float si = srcs[i_eff];
    const int* ar = adj + i_eff * P;

    float sm = 0.f;
#pragma unroll 7
    for (int jj = 0; jj < 49; ++jj) {
      const int j = 4 * jj + quad;
      float e = si + dsts[j];
      e = (e >= 0.f) ? e : 0.2f * e;
      float p = (irow_ok && ar[j] != 0) ? expf(e) : 0.f;
      sm += p;
      Ps[w][l15][j] = f2bf(p);
    }
#pragma unroll
    for (int c = 196 + quad; c < 224; c += 4) Ps[w][l15][c] = 0;

    sm += __shfl_xor(sm, 16);
    sm += __shfl_xor(sm, 32);
    if (quad == 0) winv[w][l15] = (sm > 0.f) ? 1.0f / sm : 0.f;

    floatx4 oc[4] = {};
#pragma unroll
    for (int ks = 0; ks < 7; ++ks) {
      const short8 pa = *(const short8*)&Ps[w][l15][ks * 32 + quad * 8];
#pragma unroll
      for (int nt = 0; nt < 4; ++nt) {
        const short8 bv = *(const short8*)&VT[nt * 16 + l15][ks * 32 + quad * 8];
        oc[nt] = __builtin_amdgcn_mfma_f32_16x16x32_bf16(pa, bv, oc[nt], 0, 0, 0);
      }
    }

#pragma unroll
    for (int r = 0; r < 4; ++r) {
      const int io = tile * 16 + quad * 4 + r;
      if (io < P) {
        const float inv = winv[w][quad * 4 + r];
#pragma unroll
        for (int nt = 0; nt < 4; ++nt) {
          const float hp = oc[nt][r] * inv;
          accd[nt] += (hp > 0.f) ? hp : (expf(hp) - 1.0f);
        }
      }
    }
  }

#pragma unroll
  for (int nt = 0; nt < 4; ++nt) {
    accd[nt] += __shfl_xor(accd[nt], 16);
    accd[nt] += __shfl_xor(accd[nt], 32);
  }
  if (quad == 0) {
#pragma unroll
    for (int nt = 0; nt < 4; ++nt) redc[w][nt * 16 + l15] = accd[nt];
  }
  __syncthreads();
  if (w == 0) {
    const float tot = redc[0][lane] + redc[1][lane] + redc[2][lane] + redc[3][lane];
    igf[b * D + h * 64 + lane] = tot * (1.0f / P);
  }
}

// ---------------- f_global = clip_t @ Wp + bp : grid (12, B) ----------------
__global__ __launch_bounds__(256) void fglob_kernel(
    const float* __restrict__ clip_t, const float* __restrict__ Wp,
    const float* __restrict__ bp, float* __restrict__ fglob) {
  const int jt = blockIdx.x, b = blockIdx.y;
  const int j = threadIdx.x & 63, kc = threadIdx.x >> 6;
  float s = 0.f;
  const float* ct = clip_t + b * 512;
#pragma unroll 4
  for (int k = kc * 128; k < kc * 128 + 128; ++k)
    s += ct[k] * Wp[(size_t)k * D + jt * 64 + j];
  __shared__ float red[4][64];
  red[kc][j] = s;
  __syncthreads();
  if (kc == 0)
    fglob[b * D + jt * 64 + j] = red[0][j] + red[1][j] + red[2][j] + red[3][j] + bp[jt * 64 + j];
}

// ---------------- Xc = [f_token; tgf; fglob] @ c1w : grid (6, 96) ----------------
__global__ __launch_bounds__(256) void xc1_kernel(
    const float* __restrict__ ftok, const float* __restrict__ tgf,
    const float* __restrict__ fglob, const float* __restrict__ c1w,
    float* __restrict__ Xc) {
  const int jt = blockIdx.x;      // 64-col group (0..5)
  const int r = blockIdx.y;       // 0..95
  const int b = r & 31, which = r >> 5;
  const float* src = (which == 0 ? ftok : which == 1 ? tgf : fglob) + (size_t)b * D;
  const int j = threadIdx.x & 63, kc = threadIdx.x >> 6;
  const int col = jt * 64 + j;
  float s = 0.f;
#pragma unroll 4
  for (int k = kc * 192; k < kc * 192 + 192; ++k)
    s += src[k] * c1w[(size_t)k * 384 + col];
  __shared__ float red[4][64];
  red[kc][j] = s;
  __syncthreads();
  if (kc == 0)
    Xc[(size_t)r * 384 + col] = red[0][j] + red[1][j] + red[2][j] + red[3][j];
}

// ---------------- final fusion kernel: one block per b (light version) ----------------
__device__ __forceinline__ float block_sum(float v, float* red4) {
  v = wave_sum(v);
  __syncthreads();
  if ((threadIdx.x & 63) == 0) red4[threadIdx.x >> 6] = v;
  __syncthreads();
  return red4[0] + red4[1] + red4[2] + red4[3];
}

__global__ __launch_bounds__(256) void final_kernel(
    const float* __restrict__ tgf, const float* __restrict__ igf,
    const float* __restrict__ clip_t, const float* __restrict__ clip_i,
    const float* __restrict__ logit_scale, const float* __restrict__ s_token,
    const float* __restrict__ Xc,
    const float* __restrict__ f1w, const float* __restrict__ f1b,
    const float* __restrict__ f2w, const float* __restrict__ f2b,
    const float* __restrict__ c1b,
    const float* __restrict__ c2w, const float* __restrict__ c2b,
    float* __restrict__ out) {
  const int b = blockIdx.x, tid = threadIdx.x;
  __shared__ float red[4];
  __shared__ float sres[4];
  __shared__ float hid[384];

  float d0 = 0.f, d1 = 0.f, d2 = 0.f;
  for (int i = tid; i < D; i += 256) {
    float x = tgf[b * D + i], y = igf[b * D + i];
    d0 += x * y; d1 += x * x; d2 += y * y;
  }
  float dot_ti = block_sum(d0, red);
  float n_t = sqrtf(block_sum(d1, red));
  float n_i = sqrtf(block_sum(d2, red));
  float s_phrase = dot_ti / (fmaxf(n_t, 1e-8f) * fmaxf(n_i, 1e-8f));

  float c0 = 0.f, c1 = 0.f, c2 = 0.f;
  for (int i = tid; i < 512; i += 256) {
    float x = clip_t[b * 512 + i], y = clip_i[b * 512 + i];
    c0 += x * y; c1 += x * x; c2 += y * y;
  }
  float dc = block_sum(c0, red);
  float nt2 = sqrtf(block_sum(c1, red));
  float ni2 = sqrtf(block_sum(c2, red));
  float s_global = expf(logit_scale[0]) * dc / (fmaxf(nt2, 1e-8f) * fmaxf(ni2, 1e-8f));

  if (tid == 0) {
    float s3[3] = { s_token[b], s_phrase, s_global };
    float h1[16];
    for (int j = 0; j < 16; ++j) {
      float a = f1b[j];
      for (int i2 = 0; i2 < 3; ++i2) a += s3[i2] * f1w[i2 * 16 + j];
      h1[j] = 0.5f * a * (1.0f + erff(a * 0.70710678118654752f));
    }
    for (int j = 0; j < 3; ++j) {
      float a = f2b[j];
      for (int i2 = 0; i2 < 16; ++i2) a += h1[i2] * f2w[i2 * 3 + j];
      sres[j] = 1.0f / (1.0f + expf(-a));
    }
  }
  __syncthreads();
  const float w0 = sres[0], w1 = sres[1], w2 = sres[2];

  // hid = relu(w0*X0 + w1*X1 + w2*X2 + c1b)  (X rows: b, 32+b, 64+b)
  for (int j = tid; j < 384; j += 256) {
    const float a = w0 * Xc[(size_t)b * 384 + j] +
                    w1 * Xc[(size_t)(32 + b) * 384 + j] +
                    w2 * Xc[(size_t)(64 + b) * 384 + j] + c1b[j];
    hid[j] = fmaxf(a, 0.0f);
  }
  __syncthreads();

  float p0 = 0.f, p1 = 0.f;
  for (int k2 = tid; k2 < 384; k2 += 256) {
    p0 += hid[k2] * c2w[k2 * 2 + 0];
    p1 += hid[k2] * c2w[k2 * 2 + 1];
  }
  p0 = block_sum(p0, red);
  p1 = block_sum(p1, red);
  if (tid == 0) {
    out[b * 2 + 0] = p0 + c2b[0];
    out[b * 2 + 1] = p1 + c2b[1];
  }
}

// ---------------- launch ----------------
extern "C" void kernel_launch(void* const* d_in, const int* in_sizes, int n_in,
                              void* d_out, int out_size, void* d_ws, size_t ws_size,
                              hipStream_t stream) {
  const float* text   = (const float*)d_in[0];
  const float* img    = (const float*)d_in[1];
  const float* clip_t = (const float*)d_in[2];
  const float* clip_i = (const float*)d_in[3];
  const float* lscale = (const float*)d_in[4];
  const float* wq = (const float*)d_in[5];
  const float* bq = (const float*)d_in[6];
  const float* wk = (const float*)d_in[7];
  const float* bk = (const float*)d_in[8];
  const float* wv = (const float*)d_in[9];
  const float* bv = (const float*)d_in[10];
  const float* wo = (const float*)d_in[11];
  const float* bo = (const float*)d_in[12];
  const float* Wt = (const float*)d_in[13];
  const float* at = (const float*)d_in[14];
  const float* Wi = (const float*)d_in[15];
  const float* ai = (const float*)d_in[16];
  const float* Wp = (const float*)d_in[17];
  const float* bp = (const float*)d_in[18];
  const float* f1w = (const float*)d_in[19];
  const float* f1b = (const float*)d_in[20];
  const float* f2w = (const float*)d_in[21];
  const float* f2b = (const float*)d_in[22];
  const float* c1w = (const float*)d_in[23];
  const float* c1b = (const float*)d_in[24];
  const float* c2w = (const float*)d_in[25];
  const float* c2b = (const float*)d_in[26];
  const int* text_adj  = (const int*)d_in[27];
  const int* image_adj = (const int*)d_in[28];
  float* out = (float*)d_out;

  const size_t nTD = (size_t)B * T * D;   // 1,572,864
  const size_t nPD = (size_t)B * P * D;   // 4,816,896
  const size_t nWW = (size_t)D * D;       // 589,824

  // workspace layout: identical to round 6/7
  float* fbuf = (float*)d_ws;
  size_t o = 0;
  float* kv_buf = fbuf + o; o += 2 * nPD;  // [B*P][1536]: k|v ; first nPD reused as Wh_i
  float* qa_buf = fbuf + o; o += 2 * nTD;  // [B*T][1536]: q|Wh_t
  float* upd    = fbuf + o; o += nTD;
  float* ftok   = fbuf + o; o += (size_t)B * D;
  float* stok   = fbuf + o; o += 32;
  float* tgf    = fbuf + o; o += (size_t)B * D;
  float* igf    = fbuf + o; o += (size_t)B * D;
  float* fglob  = fbuf + o; o += (size_t)B * D;
  float* bcat_t = fbuf + o; o += 1536;
  float* bcat_i = fbuf + o; o += 1536;
  unsigned short* sbuf = (unsigned short*)(fbuf + o);
  size_t so = 0;
  unsigned short* text_bf  = sbuf + so; so += nTD;
  unsigned short* img_bf   = sbuf + so; so += nPD;
  unsigned short* att_bf   = sbuf + so; so += nTD;
  unsigned short* wcat_txt = sbuf + so; so += 2 * nWW;  // wq^T | Wt^T
  unsigned short* wcat_img = sbuf + so; so += 2 * nWW;  // wk^T | wv^T
  unsigned short* wo_t     = sbuf + so; so += nWW;
  unsigned short* wi_t     = sbuf + so; so += nWW;
  // Xc [96][384] fp32 aliases img_bf (dead after the Wi GEMM; xc1 runs later)
  float* Xc = (float*)img_bf;

  // ---- weight casts (one fused launch) + bias concat + stok zero ----
  WPack wp;
  wp.src[0] = wq; wp.dst[0] = wcat_txt;
  wp.src[1] = Wt; wp.dst[1] = wcat_txt + nWW;
  wp.src[2] = wk; wp.dst[2] = wcat_img;
  wp.src[3] = wv; wp.dst[3] = wcat_img + nWW;
  wp.src[4] = wo; wp.dst[4] = wo_t;
  wp.src[5] = Wi; wp.dst[5] = wi_t;
  cast_transpose6<<<dim3(D / 32, D / 32, 6), 256, 0, stream>>>(wp, D, D);
  build_bias<<<6, 256, 0, stream>>>(bq, bk, bv, bcat_t, bcat_i, stok);
  cast_rows<<<(int)(nTD / 4 + 255) / 256, 256, 0, stream>>>(text, text_bf, (int)(nTD / 4));
  cast_rows<<<(int)(nPD / 4 + 255) / 256, 256, 0, stream>>>(img, img_bf, (int)(nPD / 4));

  const int MT = B * T;   // 2048
  const int MP = B * P;   // 6272

  // ---- fused projections ----
  gemm_mfma<<<dim3(1536 / 128, MT / 128), 256, 0, stream>>>(text_bf, wcat_txt, bcat_t, qa_buf, MT, 1536, D);
  gemm_mfma<<<dim3(1536 / 128, MP / 128), 256, 0, stream>>>(img_bf, wcat_img, bcat_i, kv_buf, MP, 1536, D);

  fglob_kernel<<<dim3(12, B), 256, 0, stream>>>(clip_t, Wp, bp, fglob);

  attn_mfma<<<dim3(H, B), 256, 0, stream>>>(qa_buf, kv_buf, att_bf);

  gemm_mfma<<<dim3(D / 128, MT / 128), 256, 0, stream>>>(att_bf, wo_t, bo, upd, MT, D, D);
  // Wh_i GEMM reuses kv_buf (attention done with k,v); img_bf dead after this
  float* whi = kv_buf;
  gemm_mfma<<<dim3(D / 128, MP / 128), 256, 0, stream>>>(img_bf, wi_t, nullptr, whi, MP, D, D);

  token_kernel<<<dim3(12, B), 256, 0, stream>>>(upd, img, ftok, stok);
  text_gat_kernel<<<dim3(H, B), 128, 0, stream>>>(qa_buf + 768, 1536, text_adj, at, tgf);
  image_gat_mfma<<<dim3(H, B), 256, 0, stream>>>(whi, image_adj, ai, igf);
  // Xc = [f_token; tgf; fglob] @ c1w  (after token/text_gat/fglob)
  xc1_kernel<<<dim3(6, 96), 256, 0, stream>>>(ftok, tgf, fglob, c1w, Xc);
  final_kernel<<<B, 256, 0, stream>>>(tgf, igf, clip_t, clip_i, lscale, stok, Xc,
                                      f1w, f1b, f2w, f2b, c1b, c2w, c2b, out);
}

// Round 9
// 405.507 us; speedup vs baseline: 3.5580x; 1.0266x over previous
//
#include <hip/hip_runtime.h>
#include <hip/hip_bf16.h>
#include <math.h>

// Problem constants
#define B 32
#define T 64
#define P 196
#define D 768
#define H 12

typedef __attribute__((ext_vector_type(8))) short short8;
typedef __attribute__((ext_vector_type(4))) float floatx4;

// ---------------- helpers ----------------
__device__ __forceinline__ float wave_sum(float v) {
#pragma unroll
  for (int o = 32; o > 0; o >>= 1) v += __shfl_xor(v, o);
  return v;
}
__device__ __forceinline__ float wave_max(float v) {
#pragma unroll
  for (int o = 32; o > 0; o >>= 1) v = fmaxf(v, __shfl_xor(v, o));
  return v;
}
__device__ __forceinline__ unsigned short f2bf(float x) {
  unsigned u = __float_as_uint(x);
  u += 0x7FFFu + ((u >> 16) & 1u);   // round-to-nearest-even
  return (unsigned short)(u >> 16);
}

// ---------------- cast kernels ----------------
__global__ __launch_bounds__(256) void cast_rows(const float* __restrict__ X,
                                                 unsigned short* __restrict__ Y, int n4) {
  int i = blockIdx.x * 256 + threadIdx.x;
  if (i < n4) {
    float4 vv = ((const float4*)X)[i];
    ushort4 o;
    o.x = f2bf(vv.x); o.y = f2bf(vv.y); o.z = f2bf(vv.z); o.w = f2bf(vv.w);
    ((ushort4*)Y)[i] = o;
  }
}

// 6 weights fp32 [K][N] -> bf16 [N][K], one fused launch (grid.z = weight idx)
struct WPack {
  const float* src[6];
  unsigned short* dst[6];
};
__global__ __launch_bounds__(256) void cast_transpose6(WPack p, int K, int N) {
  __shared__ float tile[32][33];
  const float* W = p.src[blockIdx.z];
  unsigned short* Wt = p.dst[blockIdx.z];
  const int tx = threadIdx.x & 31, ty = threadIdx.x >> 5;  // ty 0..7
  const int n0 = blockIdx.x * 32, k0 = blockIdx.y * 32;
#pragma unroll
  for (int r = 0; r < 4; ++r)
    tile[ty + 8 * r][tx] = W[(size_t)(k0 + ty + 8 * r) * N + n0 + tx];
  __syncthreads();
#pragma unroll
  for (int r = 0; r < 4; ++r)
    Wt[(size_t)(n0 + ty + 8 * r) * K + k0 + tx] = f2bf(tile[tx][ty + 8 * r]);
}

// concat biases: bt = [bq, 0], bi = [bk, bv]; also zero s_token accumulator
__global__ __launch_bounds__(256) void build_bias(const float* __restrict__ bq,
                                                  const float* __restrict__ bk,
                                                  const float* __restrict__ bv,
                                                  float* __restrict__ bt,
                                                  float* __restrict__ bi,
                                                  float* __restrict__ stok) {
  int i = blockIdx.x * 256 + threadIdx.x;
  if (i < 32) stok[i] = 0.f;
  if (i < 768) { bt[i] = bq[i]; bi[i] = bk[i]; }
  else if (i < 1536) { bt[i] = 0.f; bi[i] = bv[i - 768]; }
}

// ---------------- bf16 MFMA GEMM: C[M,N] = A[M,K] @ Bt[N,K]^T (+bias) ----------------
__global__ __launch_bounds__(256) void gemm_mfma(
    const unsigned short* __restrict__ A,   // [M][K] bf16
    const unsigned short* __restrict__ Bt,  // [N][K] bf16 (= W^T)
    const float* __restrict__ bias, float* __restrict__ C,
    int M, int N, int K) {
  __shared__ unsigned short As[128][40];
  __shared__ unsigned short Bs[128][40];
  const int tid = threadIdx.x;
  const int lane = tid & 63;
  const int w = tid >> 6;
  const int quad = lane >> 4;
  const int l15 = lane & 15;
  const int row0 = blockIdx.y * 128;
  const int col0 = blockIdx.x * 128;
  const int m_off = (w & 1) * 64;
  const int n_off = (w >> 1) * 64;
  const int lr = tid >> 2;
  const int lc = (tid & 3) * 8;

  floatx4 acc[4][4] = {};

  for (int k0 = 0; k0 < K; k0 += 32) {
    const uint4 a0 = *(const uint4*)(A + (size_t)(row0 + lr) * K + k0 + lc);
    const uint4 a1 = *(const uint4*)(A + (size_t)(row0 + lr + 64) * K + k0 + lc);
    const uint4 b0 = *(const uint4*)(Bt + (size_t)(col0 + lr) * K + k0 + lc);
    const uint4 b1 = *(const uint4*)(Bt + (size_t)(col0 + lr + 64) * K + k0 + lc);
    __syncthreads();
    *(uint4*)&As[lr][lc] = a0;
    *(uint4*)&As[lr + 64][lc] = a1;
    *(uint4*)&Bs[lr][lc] = b0;
    *(uint4*)&Bs[lr + 64][lc] = b1;
    __syncthreads();
    short8 af[4], bfr[4];
#pragma unroll
    for (int i = 0; i < 4; ++i)
      af[i] = *(const short8*)&As[m_off + 16 * i + l15][quad * 8];
#pragma unroll
    for (int j = 0; j < 4; ++j)
      bfr[j] = *(const short8*)&Bs[n_off + 16 * j + l15][quad * 8];
#pragma unroll
    for (int i = 0; i < 4; ++i)
#pragma unroll
      for (int j = 0; j < 4; ++j)
        acc[i][j] = __builtin_amdgcn_mfma_f32_16x16x32_bf16(af[i], bfr[j], acc[i][j], 0, 0, 0);
  }

#pragma unroll
  for (int j = 0; j < 4; ++j) {
    const int cg = col0 + n_off + 16 * j + l15;
    const float bv = bias ? bias[cg] : 0.0f;
#pragma unroll
    for (int i = 0; i < 4; ++i) {
      const int rbase = row0 + m_off + 16 * i + quad * 4;
#pragma unroll
      for (int r = 0; r < 4; ++r)
        C[(size_t)(rbase + r) * N + cg] = acc[i][j][r] + bv;
    }
  }
}

// ---------------- MFMA cross attention: one block per (b,h), 4 waves ----------------
__global__ __launch_bounds__(256) void attn_mfma(
    const float* __restrict__ qa, const float* __restrict__ kv,
    unsigned short* __restrict__ attout) {
  const int h = blockIdx.x, b = blockIdx.y;
  const int tid = threadIdx.x, lane = tid & 63, w = tid >> 6;
  const int quad = lane >> 4, l15 = lane & 15;

  __shared__ unsigned short Ks[196][72];     // K[p][d] bf16
  __shared__ unsigned short VT[64][232];     // V^T: VT[d][p]
  __shared__ unsigned short Ps[4][16][232];  // per-wave P (A-layout rows t_local)

  for (int i = tid; i < P * 64; i += 256) {
    const int p = i >> 6, d = i & 63;
    const float* row = kv + (size_t)(b * P + p) * 1536 + h * 64 + d;
    Ks[p][d] = f2bf(row[0]);
    VT[d][p] = f2bf(row[768]);
  }
  if (tid < 64) {
    for (int c = 196; c < 224; ++c) VT[tid][c] = 0;
  }
  __syncthreads();

  short8 aq[2];
  {
    const float* qrow = qa + (size_t)(b * T + 16 * w + l15) * 1536 + h * 64;
#pragma unroll
    for (int ks = 0; ks < 2; ++ks) {
      const float4 x = *(const float4*)(qrow + 32 * ks + quad * 8);
      const float4 y = *(const float4*)(qrow + 32 * ks + quad * 8 + 4);
      short8 f;
      f[0] = (short)f2bf(x.x); f[1] = (short)f2bf(x.y);
      f[2] = (short)f2bf(x.z); f[3] = (short)f2bf(x.w);
      f[4] = (short)f2bf(y.x); f[5] = (short)f2bf(y.y);
      f[6] = (short)f2bf(y.z); f[7] = (short)f2bf(y.w);
      aq[ks] = f;
    }
  }

  floatx4 sc[13];
#pragma unroll
  for (int tile = 0; tile < 13; ++tile) {
    int p = tile * 16 + l15;
    if (p > 195) p = 195;
    short8 bk0 = *(const short8*)&Ks[p][quad * 8];
    short8 bk1 = *(const short8*)&Ks[p][32 + quad * 8];
    floatx4 c = {};
    c = __builtin_amdgcn_mfma_f32_16x16x32_bf16(aq[0], bk0, c, 0, 0, 0);
    c = __builtin_amdgcn_mfma_f32_16x16x32_bf16(aq[1], bk1, c, 0, 0, 0);
    sc[tile] = c;
  }

  float mx[4] = {-3.4e38f, -3.4e38f, -3.4e38f, -3.4e38f};
#pragma unroll
  for (int tile = 0; tile < 13; ++tile)
#pragma unroll
    for (int r = 0; r < 4; ++r) {
      float s = sc[tile][r] * 0.125f;
      if (tile == 12 && l15 >= 4) s = -3.0e38f;
      sc[tile][r] = s;
      mx[r] = fmaxf(mx[r], s);
    }
#pragma unroll
  for (int off = 1; off < 16; off <<= 1)
#pragma unroll
    for (int r = 0; r < 4; ++r) mx[r] = fmaxf(mx[r], __shfl_xor(mx[r], off));

  float sm[4] = {};
#pragma unroll
  for (int tile = 0; tile < 13; ++tile)
#pragma unroll
    for (int r = 0; r < 4; ++r) {
      float e = expf(sc[tile][r] - mx[r]);
      sc[tile][r] = e;
      sm[r] += e;
    }
#pragma unroll
  for (int off = 1; off < 16; off <<= 1)
#pragma unroll
    for (int r = 0; r < 4; ++r) sm[r] += __shfl_xor(sm[r], off);
  float inv[4];
#pragma unroll
  for (int r = 0; r < 4; ++r) inv[r] = 1.0f / sm[r];

#pragma unroll
  for (int tile = 0; tile < 13; ++tile)
#pragma unroll
    for (int r = 0; r < 4; ++r)
      Ps[w][quad * 4 + r][tile * 16 + l15] = f2bf(sc[tile][r] * inv[r]);
#pragma unroll
  for (int r = 0; r < 4; ++r)
    Ps[w][quad * 4 + r][208 + l15] = 0;

  __syncthreads();

  floatx4 oc[4] = {};
#pragma unroll
  for (int ks = 0; ks < 7; ++ks) {
    short8 pa = *(const short8*)&Ps[w][l15][ks * 32 + quad * 8];
#pragma unroll
    for (int nt = 0; nt < 4; ++nt) {
      short8 bv = *(const short8*)&VT[nt * 16 + l15][ks * 32 + quad * 8];
      oc[nt] = __builtin_amdgcn_mfma_f32_16x16x32_bf16(pa, bv, oc[nt], 0, 0, 0);
    }
  }

#pragma unroll
  for (int nt = 0; nt < 4; ++nt)
#pragma unroll
    for (int r = 0; r < 4; ++r)
      attout[(size_t)(b * T + 16 * w + quad * 4 + r) * 768 + h * 64 + nt * 16 + l15] =
          f2bf(oc[nt][r]);
}

// ---------------- token: grid (12, B). f_token slice + s_token partial ----------------
__global__ __launch_bounds__(256) void token_kernel(
    const float* __restrict__ upd, const float* __restrict__ img,
    float* __restrict__ f_token, float* __restrict__ s_token) {
  const int jt = blockIdx.x, b = blockIdx.y;
  const int l = threadIdx.x & 63, tg = threadIdx.x >> 6;
  const int d = jt * 64 + l;
  float fs = 0.f, ss = 0.f;
#pragma unroll 4
  for (int tt = 0; tt < 16; ++tt) {
    const int t = tg * 16 + tt;
    const float u = upd[(size_t)(b * T + t) * D + d];
    fs += u;
    ss += u * img[(size_t)(b * P + t) * D + d];
  }
  __shared__ float red[4][64];
  __shared__ float sred[4];
  red[tg][l] = fs;
  const float sw = wave_sum(ss);
  if (l == 0) sred[tg] = sw;
  __syncthreads();
  if (tg == 0) {
    f_token[(size_t)b * D + d] =
        (red[0][l] + red[1][l] + red[2][l] + red[3][l]) * (1.0f / T);
    if (threadIdx.x == 0)
      atomicAdd(&s_token[b], (sred[0] + sred[1] + sred[2] + sred[3]) * (1.0f / T));
  }
}

// ---------------- text GAT: one block (2 waves) per (b,h). N=64 ----------------
__global__ __launch_bounds__(128) void text_gat_kernel(
    const float* __restrict__ Wh, int ldw, const int* __restrict__ adj,
    const float* __restrict__ at, float* __restrict__ tgf) {
  const int h = blockIdx.x, b = blockIdx.y;
  const int tid = threadIdx.x, lane = tid & 63, w = tid >> 6;
  __shared__ float WhT[64][68];       // WhT[f][n]
  __shared__ float atts[2][8][68];
  __shared__ float srcs[64], dsts[64];
  __shared__ float redc[2][64];
  __shared__ float asv[64], adv[64];

  if (tid < 64) { asv[tid] = at[tid]; adv[tid] = at[64 + tid]; }
  for (int idx = tid; idx < 64 * 64; idx += 128) {
    int n = idx >> 6, f = idx & 63;
    WhT[f][n] = Wh[(size_t)(b * T + n) * ldw + h * 64 + f];
  }
  __syncthreads();

  if (tid < 64) {
    float s = 0.f, dd = 0.f;
#pragma unroll 8
    for (int f = 0; f < 64; ++f) {
      float wv = WhT[f][tid];
      s += wv * asv[f];
      dd += wv * adv[f];
    }
    srcs[tid] = s;
    dsts[tid] = dd;
  }
  __syncthreads();

  const int* adjb = adj + b * T * T;
  float macc = 0.f;
  for (int g = 0; g < 4; ++g) {
#pragma unroll
    for (int r = 0; r < 8; ++r) {
      const int i = w * 32 + g * 8 + r;
      float e = srcs[i] + dsts[lane];
      e = (e >= 0.f) ? e : 0.2f * e;
      if (adjb[i * 64 + lane] == 0) e = -9e15f;
      const float m = wave_max(e);
      float pp = expf(e - m);
      const float inv = 1.0f / wave_sum(pp);
      atts[w][r][lane] = pp * inv;
    }
    float acc[8] = {};
    for (int jq = 0; jq < 16; ++jq) {
      const float4 whv = *(const float4*)&WhT[lane][4 * jq];
#pragma unroll
      for (int r = 0; r < 8; ++r) {
        const float4 av = *(const float4*)&atts[w][r][4 * jq];
        acc[r] += av.x * whv.x + av.y * whv.y + av.z * whv.z + av.w * whv.w;
      }
    }
#pragma unroll
    for (int r = 0; r < 8; ++r)
      macc += (acc[r] > 0.f) ? acc[r] : (expf(acc[r]) - 1.0f);
  }

  redc[w][lane] = macc;
  __syncthreads();
  if (w == 0)
    tgf[b * D + h * 64 + lane] = (redc[0][lane] + redc[1][lane]) * (1.0f / T);
}

// ---------------- image GAT stage 1: src/dst per (node, head) ----------------
// One wave per (n_global, h). sd[(b*12+h)*392 + nn] = src, +196 = dst.
__global__ __launch_bounds__(256) void sd_kernel(
    const float* __restrict__ Wh, const float* __restrict__ ai,
    float* __restrict__ sd) {
  const int task = blockIdx.x * 4 + (threadIdx.x >> 6);  // 0 .. 75263
  const int lane = threadIdx.x & 63;
  const int n = task / 12, h = task - n * 12;            // n in [0, 6272)
  const float v = Wh[(size_t)n * 768 + h * 64 + lane];
  float s = v * ai[lane];
  float dd = v * ai[64 + lane];
#pragma unroll
  for (int o = 32; o > 0; o >>= 1) {
    s += __shfl_xor(s, o);
    dd += __shfl_xor(dd, o);
  }
  if (lane == 0) {
    const int b = n / P, nn = n - b * P;
    float* base = sd + (size_t)(b * 12 + h) * 392 + nn;
    base[0] = s;
    base[196] = dd;
  }
}

// ---------------- image GAT stage 2: normalized exp-scores -> S (A-layout) ----------------
// grid (49, H, B); one wave per row i. S[(b*12+h)][i][224 cols] bf16, cols 196.. zero.
__global__ __launch_bounds__(256) void score_kernel(
    const float* __restrict__ sd, const int* __restrict__ adj,
    unsigned short* __restrict__ S) {
  const int w = threadIdx.x >> 6, lane = threadIdx.x & 63;
  const int i = blockIdx.x * 4 + w;            // 0..195
  const int h = blockIdx.y, b = blockIdx.z;
  const float* sdp = sd + (size_t)(b * 12 + h) * 392;
  const float si = sdp[i];
  const int* ar = adj + i * P;

  float p0 = 0.f, p1 = 0.f, p2 = 0.f, p3 = 0.f;
  {
    float e;
    e = si + sdp[196 + lane];        e = (e >= 0.f) ? e : 0.2f * e;
    if (ar[lane] != 0) p0 = expf(e);
    e = si + sdp[196 + lane + 64];   e = (e >= 0.f) ? e : 0.2f * e;
    if (ar[lane + 64] != 0) p1 = expf(e);
    e = si + sdp[196 + lane + 128];  e = (e >= 0.f) ? e : 0.2f * e;
    if (ar[lane + 128] != 0) p2 = expf(e);
    if (lane < 4) {
      e = si + sdp[196 + lane + 192]; e = (e >= 0.f) ? e : 0.2f * e;
      if (ar[lane + 192] != 0) p3 = expf(e);
    }
  }
  const float inv = 1.0f / wave_sum(p0 + p1 + p2 + p3);  // diag always set -> sum > 0

  unsigned short* row = S + ((size_t)(b * 12 + h) * 196 + i) * 224;
  row[lane] = f2bf(p0 * inv);
  row[lane + 64] = f2bf(p1 * inv);
  row[lane + 128] = f2bf(p2 * inv);
  if (lane < 4) row[lane + 192] = f2bf(p3 * inv);
  else if (lane < 32) row[lane + 192] = 0;  // cols 196..223 zero
}

// ---------------- image GAT stage 3: hp = S @ Wh via MFMA, elu, mean ----------------
// One block (4 waves) per (b,h). LDS: only Wh^T (~31 KB) -> 5 blocks/CU.
__global__ __launch_bounds__(256) void image_gat_mfma(
    const float* __restrict__ Wh, const unsigned short* __restrict__ S,
    float* __restrict__ igf) {
  const int h = blockIdx.x, b = blockIdx.y;
  const int tid = threadIdx.x, lane = tid & 63, w = tid >> 6;
  const int quad = lane >> 4, l15 = lane & 15;

  __shared__ unsigned short VT[64][232];   // Wh^T bf16: VT[f][n]
  __shared__ float redc[4][64];

  for (int i = tid; i < P * 64; i += 256) {
    const int n = i >> 6, f = i & 63;
    VT[f][n] = f2bf(Wh[(size_t)(b * P + n) * 768 + h * 64 + f]);
  }
  if (tid < 64)
    for (int c = 196; c < 224; ++c) VT[tid][c] = 0;
  __syncthreads();

  const unsigned short* Sbh = S + (size_t)(b * 12 + h) * 196 * 224;
  float accd[4] = {};

  for (int tile = w; tile < 13; tile += 4) {
    const unsigned short* Srow = Sbh + (size_t)(tile * 16 + l15) * 224;  // rows 196..207 overrun: discarded
    floatx4 oc[4] = {};
#pragma unroll
    for (int ks = 0; ks < 7; ++ks) {
      const short8 pa = *(const short8*)(Srow + ks * 32 + quad * 8);
#pragma unroll
      for (int nt = 0; nt < 4; ++nt) {
        const short8 bv = *(const short8*)&VT[nt * 16 + l15][ks * 32 + quad * 8];
        oc[nt] = __builtin_amdgcn_mfma_f32_16x16x32_bf16(pa, bv, oc[nt], 0, 0, 0);
      }
    }
#pragma unroll
    for (int r = 0; r < 4; ++r) {
      const int io = tile * 16 + quad * 4 + r;
      if (io < P) {
#pragma unroll
        for (int nt = 0; nt < 4; ++nt) {
          const float hp = oc[nt][r];
          accd[nt] += (hp > 0.f) ? hp : (expf(hp) - 1.0f);
        }
      }
    }
  }

#pragma unroll
  for (int nt = 0; nt < 4; ++nt) {
    accd[nt] += __shfl_xor(accd[nt], 16);
    accd[nt] += __shfl_xor(accd[nt], 32);
  }
  if (quad == 0) {
#pragma unroll
    for (int nt = 0; nt < 4; ++nt) redc[w][nt * 16 + l15] = accd[nt];
  }
  __syncthreads();
  if (w == 0) {
    const float tot = redc[0][lane] + redc[1][lane] + redc[2][lane] + redc[3][lane];
    igf[b * D + h * 64 + lane] = tot * (1.0f / P);
  }
}

// ---------------- f_global = clip_t @ Wp + bp : grid (12, B) ----------------
__global__ __launch_bounds__(256) void fglob_kernel(
    const float* __restrict__ clip_t, const float* __restrict__ Wp,
    const float* __restrict__ bp, float* __restrict__ fglob) {
  const int jt = blockIdx.x, b = blockIdx.y;
  const int j = threadIdx.x & 63, kc = threadIdx.x >> 6;
  float s = 0.f;
  const float* ct = clip_t + b * 512;
#pragma unroll 4
  for (int k = kc * 128; k < kc * 128 + 128; ++k)
    s += ct[k] * Wp[(size_t)k * D + jt * 64 + j];
  __shared__ float red[4][64];
  red[kc][j] = s;
  __syncthreads();
  if (kc == 0)
    fglob[b * D + jt * 64 + j] = red[0][j] + red[1][j] + red[2][j] + red[3][j] + bp[jt * 64 + j];
}

// ---------------- Xc = [f_token; tgf; fglob] @ c1w : grid (6, 96) ----------------
__global__ __launch_bounds__(256) void xc1_kernel(
    const float* __restrict__ ftok, const float* __restrict__ tgf,
    const float* __restrict__ fglob, const float* __restrict__ c1w,
    float* __restrict__ Xc) {
  const int jt = blockIdx.x;
  const int r = blockIdx.y;
  const int b = r & 31, which = r >> 5;
  const float* src = (which == 0 ? ftok : which == 1 ? tgf : fglob) + (size_t)b * D;
  const int j = threadIdx.x & 63, kc = threadIdx.x >> 6;
  const int col = jt * 64 + j;
  float s = 0.f;
#pragma unroll 4
  for (int k = kc * 192; k < kc * 192 + 192; ++k)
    s += src[k] * c1w[(size_t)k * 384 + col];
  __shared__ float red[4][64];
  red[kc][j] = s;
  __syncthreads();
  if (kc == 0)
    Xc[(size_t)r * 384 + col] = red[0][j] + red[1][j] + red[2][j] + red[3][j];
}

// ---------------- final fusion kernel: one block per b ----------------
__device__ __forceinline__ float block_sum(float v, float* red4) {
  v = wave_sum(v);
  __syncthreads();
  if ((threadIdx.x & 63) == 0) red4[threadIdx.x >> 6] = v;
  __syncthreads();
  return red4[0] + red4[1] + red4[2] + red4[3];
}

__global__ __launch_bounds__(256) void final_kernel(
    const float* __restrict__ tgf, const float* __restrict__ igf,
    const float* __restrict__ clip_t, const float* __restrict__ clip_i,
    const float* __restrict__ logit_scale, const float* __restrict__ s_token,
    const float* __restrict__ Xc,
    const float* __restrict__ f1w, const float* __restrict__ f1b,
    const float* __restrict__ f2w, const float* __restrict__ f2b,
    const float* __restrict__ c1b,
    const float* __restrict__ c2w, const float* __restrict__ c2b,
    float* __restrict__ out) {
  const int b = blockIdx.x, tid = threadIdx.x;
  __shared__ float red[4];
  __shared__ float sres[4];
  __shared__ float hid[384];

  float d0 = 0.f, d1 = 0.f, d2 = 0.f;
  for (int i = tid; i < D; i += 256) {
    float x = tgf[b * D + i], y = igf[b * D + i];
    d0 += x * y; d1 += x * x; d2 += y * y;
  }
  float dot_ti = block_sum(d0, red);
  float n_t = sqrtf(block_sum(d1, red));
  float n_i = sqrtf(block_sum(d2, red));
  float s_phrase = dot_ti / (fmaxf(n_t, 1e-8f) * fmaxf(n_i, 1e-8f));

  float c0 = 0.f, c1 = 0.f, c2 = 0.f;
  for (int i = tid; i < 512; i += 256) {
    float x = clip_t[b * 512 + i], y = clip_i[b * 512 + i];
    c0 += x * y; c1 += x * x; c2 += y * y;
  }
  float dc = block_sum(c0, red);
  float nt2 = sqrtf(block_sum(c1, red));
  float ni2 = sqrtf(block_sum(c2, red));
  float s_global = expf(logit_scale[0]) * dc / (fmaxf(nt2, 1e-8f) * fmaxf(ni2, 1e-8f));

  if (tid == 0) {
    float s3[3] = { s_token[b], s_phrase, s_global };
    float h1[16];
    for (int j = 0; j < 16; ++j) {
      float a = f1b[j];
      for (int i2 = 0; i2 < 3; ++i2) a += s3[i2] * f1w[i2 * 16 + j];
      h1[j] = 0.5f * a * (1.0f + erff(a * 0.70710678118654752f));
    }
    for (int j = 0; j < 3; ++j) {
      float a = f2b[j];
      for (int i2 = 0; i2 < 16; ++i2) a += h1[i2] * f2w[i2 * 3 + j];
      sres[j] = 1.0f / (1.0f + expf(-a));
    }
  }
  __syncthreads();
  const float w0 = sres[0], w1 = sres[1], w2 = sres[2];

  for (int j = tid; j < 384; j += 256) {
    const float a = w0 * Xc[(size_t)b * 384 + j] +
                    w1 * Xc[(size_t)(32 + b) * 384 + j] +
                    w2 * Xc[(size_t)(64 + b) * 384 + j] + c1b[j];
    hid[j] = fmaxf(a, 0.0f);
  }
  __syncthreads();

  float p0 = 0.f, p1 = 0.f;
  for (int k2 = tid; k2 < 384; k2 += 256) {
    p0 += hid[k2] * c2w[k2 * 2 + 0];
    p1 += hid[k2] * c2w[k2 * 2 + 1];
  }
  p0 = block_sum(p0, red);
  p1 = block_sum(p1, red);
  if (tid == 0) {
    out[b * 2 + 0] = p0 + c2b[0];
    out[b * 2 + 1] = p1 + c2b[1];
  }
}

// ---------------- launch ----------------
extern "C" void kernel_launch(void* const* d_in, const int* in_sizes, int n_in,
                              void* d_out, int out_size, void* d_ws, size_t ws_size,
                              hipStream_t stream) {
  const float* text   = (const float*)d_in[0];
  const float* img    = (const float*)d_in[1];
  const float* clip_t = (const float*)d_in[2];
  const float* clip_i = (const float*)d_in[3];
  const float* lscale = (const float*)d_in[4];
  const float* wq = (const float*)d_in[5];
  const float* bq = (const float*)d_in[6];
  const float* wk = (const float*)d_in[7];
  const float* bk = (const float*)d_in[8];
  const float* wv = (const float*)d_in[9];
  const float* bv = (const float*)d_in[10];
  const float* wo = (const float*)d_in[11];
  const float* bo = (const float*)d_in[12];
  const float* Wt = (const float*)d_in[13];
  const float* at = (const float*)d_in[14];
  const float* Wi = (const float*)d_in[15];
  const float* ai = (const float*)d_in[16];
  const float* Wp = (const float*)d_in[17];
  const float* bp = (const float*)d_in[18];
  const float* f1w = (const float*)d_in[19];
  const float* f1b = (const float*)d_in[20];
  const float* f2w = (const float*)d_in[21];
  const float* f2b = (const float*)d_in[22];
  const float* c1w = (const float*)d_in[23];
  const float* c1b = (const float*)d_in[24];
  const float* c2w = (const float*)d_in[25];
  const float* c2b = (const float*)d_in[26];
  const int* text_adj  = (const int*)d_in[27];
  const int* image_adj = (const int*)d_in[28];
  float* out = (float*)d_out;

  const size_t nTD = (size_t)B * T * D;   // 1,572,864
  const size_t nPD = (size_t)B * P * D;   // 4,816,896
  const size_t nWW = (size_t)D * D;       // 589,824

  // workspace layout: identical footprint to round 8
  float* fbuf = (float*)d_ws;
  size_t o = 0;
  float* kv_buf = fbuf + o; o += 2 * nPD;  // [B*P][1536]: k|v ; first nPD reused as Wh_i
  float* qa_buf = fbuf + o; o += 2 * nTD;  // [B*T][1536]: q|Wh_t
  float* upd    = fbuf + o; o += nTD;
  float* ftok   = fbuf + o; o += (size_t)B * D;
  float* stok   = fbuf + o; o += 32;
  float* tgf    = fbuf + o; o += (size_t)B * D;
  float* igf    = fbuf + o; o += (size_t)B * D;
  float* fglob  = fbuf + o; o += (size_t)B * D;
  float* bcat_t = fbuf + o; o += 1536;
  float* bcat_i = fbuf + o; o += 1536;
  unsigned short* sbuf = (unsigned short*)(fbuf + o);
  size_t so = 0;
  unsigned short* text_bf  = sbuf + so; so += nTD;
  unsigned short* img_bf   = sbuf + so; so += nPD;
  unsigned short* att_bf   = sbuf + so; so += nTD;
  unsigned short* wcat_txt = sbuf + so; so += 2 * nWW;  // wq^T | Wt^T
  unsigned short* wcat_img = sbuf + so; so += 2 * nWW;  // wk^T | wv^T
  unsigned short* wo_t     = sbuf + so; so += nWW;
  unsigned short* wi_t     = sbuf + so; so += nWW;
  // Aliases (lifetime-based, no footprint growth):
  float* Xc = (float*)img_bf;                       // [96][384] after whi GEMM
  float* sd = (float*)text_bf;                      // [384][392] after text proj GEMM
  unsigned short* S = (unsigned short*)(fbuf + nPD); // [384][196][224] bf16 over v-half+qa_buf+upd
                                                     // (needs 8.43M floats < 9.53M available)

  // ---- weight casts + bias concat + stok zero ----
  WPack wp;
  wp.src[0] = wq; wp.dst[0] = wcat_txt;
  wp.src[1] = Wt; wp.dst[1] = wcat_txt + nWW;
  wp.src[2] = wk; wp.dst[2] = wcat_img;
  wp.src[3] = wv; wp.dst[3] = wcat_img + nWW;
  wp.src[4] = wo; wp.dst[4] = wo_t;
  wp.src[5] = Wi; wp.dst[5] = wi_t;
  cast_transpose6<<<dim3(D / 32, D / 32, 6), 256, 0, stream>>>(wp, D, D);
  build_bias<<<6, 256, 0, stream>>>(bq, bk, bv, bcat_t, bcat_i, stok);
  cast_rows<<<(int)(nTD / 4 + 255) / 256, 256, 0, stream>>>(text, text_bf, (int)(nTD / 4));
  cast_rows<<<(int)(nPD / 4 + 255) / 256, 256, 0, stream>>>(img, img_bf, (int)(nPD / 4));

  const int MT = B * T;   // 2048
  const int MP = B * P;   // 6272

  // ---- fused projections ----
  gemm_mfma<<<dim3(1536 / 128, MT / 128), 256, 0, stream>>>(text_bf, wcat_txt, bcat_t, qa_buf, MT, 1536, D);
  gemm_mfma<<<dim3(1536 / 128, MP / 128), 256, 0, stream>>>(img_bf, wcat_img, bcat_i, kv_buf, MP, 1536, D);

  fglob_kernel<<<dim3(12, B), 256, 0, stream>>>(clip_t, Wp, bp, fglob);

  attn_mfma<<<dim3(H, B), 256, 0, stream>>>(qa_buf, kv_buf, att_bf);

  gemm_mfma<<<dim3(D / 128, MT / 128), 256, 0, stream>>>(att_bf, wo_t, bo, upd, MT, D, D);
  // Wh_i GEMM reuses kv_buf first half (k region); v-half becomes free
  float* whi = kv_buf;
  gemm_mfma<<<dim3(D / 128, MP / 128), 256, 0, stream>>>(img_bf, wi_t, nullptr, whi, MP, D, D);

  // consume upd and qa_buf BEFORE score_kernel overwrites them (S spans v-half+qa+upd)
  token_kernel<<<dim3(12, B), 256, 0, stream>>>(upd, img, ftok, stok);
  text_gat_kernel<<<dim3(H, B), 128, 0, stream>>>(qa_buf + 768, 1536, text_adj, at, tgf);

  // ---- image GAT: 3-stage parallel pipeline ----
  sd_kernel<<<MP * 12 / 4, 256, 0, stream>>>(whi, ai, sd);
  score_kernel<<<dim3(49, H, B), 256, 0, stream>>>(sd, image_adj, S);
  image_gat_mfma<<<dim3(H, B), 256, 0, stream>>>(whi, S, igf);

  xc1_kernel<<<dim3(6, 96), 256, 0, stream>>>(ftok, tgf, fglob, c1w, Xc);
  final_kernel<<<B, 256, 0, stream>>>(tgf, igf, clip_t, clip_i, lscale, stok, Xc,
                                      f1w, f1b, f2w, f2b, c1b, c2w, c2b, out);
}

// Round 10
// 371.919 us; speedup vs baseline: 3.8793x; 1.0903x over previous
//
#include <hip/hip_runtime.h>
#include <hip/hip_bf16.h>
#include <math.h>

// Problem constants
#define B 32
#define T 64
#define P 196
#define D 768
#define H 12

typedef __attribute__((ext_vector_type(8))) short short8;
typedef __attribute__((ext_vector_type(4))) float floatx4;

// ---------------- helpers ----------------
__device__ __forceinline__ float wave_sum(float v) {
#pragma unroll
  for (int o = 32; o > 0; o >>= 1) v += __shfl_xor(v, o);
  return v;
}
__device__ __forceinline__ float wave_max(float v) {
#pragma unroll
  for (int o = 32; o > 0; o >>= 1) v = fmaxf(v, __shfl_xor(v, o));
  return v;
}
__device__ __forceinline__ unsigned short f2bf(float x) {
  unsigned u = __float_as_uint(x);
  u += 0x7FFFu + ((u >> 16) & 1u);   // round-to-nearest-even
  return (unsigned short)(u >> 16);
}

// ---------------- cast kernels ----------------
__global__ __launch_bounds__(256) void cast_rows(const float* __restrict__ X,
                                                 unsigned short* __restrict__ Y, int n4) {
  int i = blockIdx.x * 256 + threadIdx.x;
  if (i < n4) {
    float4 vv = ((const float4*)X)[i];
    ushort4 o;
    o.x = f2bf(vv.x); o.y = f2bf(vv.y); o.z = f2bf(vv.z); o.w = f2bf(vv.w);
    ((ushort4*)Y)[i] = o;
  }
}

// 6 weights fp32 [K][N] -> bf16 [N][K], one fused launch (grid.z = weight idx)
struct WPack {
  const float* src[6];
  unsigned short* dst[6];
};
__global__ __launch_bounds__(256) void cast_transpose6(WPack p, int K, int N) {
  __shared__ float tile[32][33];
  const float* W = p.src[blockIdx.z];
  unsigned short* Wt = p.dst[blockIdx.z];
  const int tx = threadIdx.x & 31, ty = threadIdx.x >> 5;  // ty 0..7
  const int n0 = blockIdx.x * 32, k0 = blockIdx.y * 32;
#pragma unroll
  for (int r = 0; r < 4; ++r)
    tile[ty + 8 * r][tx] = W[(size_t)(k0 + ty + 8 * r) * N + n0 + tx];
  __syncthreads();
#pragma unroll
  for (int r = 0; r < 4; ++r)
    Wt[(size_t)(n0 + ty + 8 * r) * K + k0 + tx] = f2bf(tile[tx][ty + 8 * r]);
}

// concat biases: bt = [bq, 0], bi = [bk, bv]; also zero s_token accumulator
__global__ __launch_bounds__(256) void build_bias(const float* __restrict__ bq,
                                                  const float* __restrict__ bk,
                                                  const float* __restrict__ bv,
                                                  float* __restrict__ bt,
                                                  float* __restrict__ bi,
                                                  float* __restrict__ stok) {
  int i = blockIdx.x * 256 + threadIdx.x;
  if (i < 32) stok[i] = 0.f;
  if (i < 768) { bt[i] = bq[i]; bi[i] = bk[i]; }
  else if (i < 1536) { bt[i] = 0.f; bi[i] = bv[i - 768]; }
}

// ---------------- bf16 MFMA GEMM: C[M,N] = A[M,K] @ Bt[N,K]^T (+bias) ----------------
__global__ __launch_bounds__(256) void gemm_mfma(
    const unsigned short* __restrict__ A,   // [M][K] bf16
    const unsigned short* __restrict__ Bt,  // [N][K] bf16 (= W^T)
    const float* __restrict__ bias, float* __restrict__ C,
    int M, int N, int K) {
  __shared__ unsigned short As[128][40];
  __shared__ unsigned short Bs[128][40];
  const int tid = threadIdx.x;
  const int lane = tid & 63;
  const int w = tid >> 6;
  const int quad = lane >> 4;
  const int l15 = lane & 15;
  const int row0 = blockIdx.y * 128;
  const int col0 = blockIdx.x * 128;
  const int m_off = (w & 1) * 64;
  const int n_off = (w >> 1) * 64;
  const int lr = tid >> 2;
  const int lc = (tid & 3) * 8;

  floatx4 acc[4][4] = {};

  for (int k0 = 0; k0 < K; k0 += 32) {
    const uint4 a0 = *(const uint4*)(A + (size_t)(row0 + lr) * K + k0 + lc);
    const uint4 a1 = *(const uint4*)(A + (size_t)(row0 + lr + 64) * K + k0 + lc);
    const uint4 b0 = *(const uint4*)(Bt + (size_t)(col0 + lr) * K + k0 + lc);
    const uint4 b1 = *(const uint4*)(Bt + (size_t)(col0 + lr + 64) * K + k0 + lc);
    __syncthreads();
    *(uint4*)&As[lr][lc] = a0;
    *(uint4*)&As[lr + 64][lc] = a1;
    *(uint4*)&Bs[lr][lc] = b0;
    *(uint4*)&Bs[lr + 64][lc] = b1;
    __syncthreads();
    short8 af[4], bfr[4];
#pragma unroll
    for (int i = 0; i < 4; ++i)
      af[i] = *(const short8*)&As[m_off + 16 * i + l15][quad * 8];
#pragma unroll
    for (int j = 0; j < 4; ++j)
      bfr[j] = *(const short8*)&Bs[n_off + 16 * j + l15][quad * 8];
#pragma unroll
    for (int i = 0; i < 4; ++i)
#pragma unroll
      for (int j = 0; j < 4; ++j)
        acc[i][j] = __builtin_amdgcn_mfma_f32_16x16x32_bf16(af[i], bfr[j], acc[i][j], 0, 0, 0);
  }

#pragma unroll
  for (int j = 0; j < 4; ++j) {
    const int cg = col0 + n_off + 16 * j + l15;
    const float bv = bias ? bias[cg] : 0.0f;
#pragma unroll
    for (int i = 0; i < 4; ++i) {
      const int rbase = row0 + m_off + 16 * i + quad * 4;
#pragma unroll
      for (int r = 0; r < 4; ++r)
        C[(size_t)(rbase + r) * N + cg] = acc[i][j][r] + bv;
    }
  }
}

// ---------------- MFMA cross attention: one block per (b,h), 4 waves ----------------
__global__ __launch_bounds__(256) void attn_mfma(
    const float* __restrict__ qa, const float* __restrict__ kv,
    unsigned short* __restrict__ attout) {
  const int h = blockIdx.x, b = blockIdx.y;
  const int tid = threadIdx.x, lane = tid & 63, w = tid >> 6;
  const int quad = lane >> 4, l15 = lane & 15;

  __shared__ unsigned short Ks[196][72];     // K[p][d] bf16
  __shared__ unsigned short VT[64][232];     // V^T: VT[d][p]
  __shared__ unsigned short Ps[4][16][232];  // per-wave P (A-layout rows t_local)

  for (int i = tid; i < P * 64; i += 256) {
    const int p = i >> 6, d = i & 63;
    const float* row = kv + (size_t)(b * P + p) * 1536 + h * 64 + d;
    Ks[p][d] = f2bf(row[0]);
    VT[d][p] = f2bf(row[768]);
  }
  if (tid < 64) {
    for (int c = 196; c < 224; ++c) VT[tid][c] = 0;
  }
  __syncthreads();

  short8 aq[2];
  {
    const float* qrow = qa + (size_t)(b * T + 16 * w + l15) * 1536 + h * 64;
#pragma unroll
    for (int ks = 0; ks < 2; ++ks) {
      const float4 x = *(const float4*)(qrow + 32 * ks + quad * 8);
      const float4 y = *(const float4*)(qrow + 32 * ks + quad * 8 + 4);
      short8 f;
      f[0] = (short)f2bf(x.x); f[1] = (short)f2bf(x.y);
      f[2] = (short)f2bf(x.z); f[3] = (short)f2bf(x.w);
      f[4] = (short)f2bf(y.x); f[5] = (short)f2bf(y.y);
      f[6] = (short)f2bf(y.z); f[7] = (short)f2bf(y.w);
      aq[ks] = f;
    }
  }

  floatx4 sc[13];
#pragma unroll
  for (int tile = 0; tile < 13; ++tile) {
    int p = tile * 16 + l15;
    if (p > 195) p = 195;
    short8 bk0 = *(const short8*)&Ks[p][quad * 8];
    short8 bk1 = *(const short8*)&Ks[p][32 + quad * 8];
    floatx4 c = {};
    c = __builtin_amdgcn_mfma_f32_16x16x32_bf16(aq[0], bk0, c, 0, 0, 0);
    c = __builtin_amdgcn_mfma_f32_16x16x32_bf16(aq[1], bk1, c, 0, 0, 0);
    sc[tile] = c;
  }

  float mx[4] = {-3.4e38f, -3.4e38f, -3.4e38f, -3.4e38f};
#pragma unroll
  for (int tile = 0; tile < 13; ++tile)
#pragma unroll
    for (int r = 0; r < 4; ++r) {
      float s = sc[tile][r] * 0.125f;
      if (tile == 12 && l15 >= 4) s = -3.0e38f;
      sc[tile][r] = s;
      mx[r] = fmaxf(mx[r], s);
    }
#pragma unroll
  for (int off = 1; off < 16; off <<= 1)
#pragma unroll
    for (int r = 0; r < 4; ++r) mx[r] = fmaxf(mx[r], __shfl_xor(mx[r], off));

  float sm[4] = {};
#pragma unroll
  for (int tile = 0; tile < 13; ++tile)
#pragma unroll
    for (int r = 0; r < 4; ++r) {
      float e = expf(sc[tile][r] - mx[r]);
      sc[tile][r] = e;
      sm[r] += e;
    }
#pragma unroll
  for (int off = 1; off < 16; off <<= 1)
#pragma unroll
    for (int r = 0; r < 4; ++r) sm[r] += __shfl_xor(sm[r], off);
  float inv[4];
#pragma unroll
  for (int r = 0; r < 4; ++r) inv[r] = 1.0f / sm[r];

#pragma unroll
  for (int tile = 0; tile < 13; ++tile)
#pragma unroll
    for (int r = 0; r < 4; ++r)
      Ps[w][quad * 4 + r][tile * 16 + l15] = f2bf(sc[tile][r] * inv[r]);
#pragma unroll
  for (int r = 0; r < 4; ++r)
    Ps[w][quad * 4 + r][208 + l15] = 0;

  __syncthreads();

  floatx4 oc[4] = {};
#pragma unroll
  for (int ks = 0; ks < 7; ++ks) {
    short8 pa = *(const short8*)&Ps[w][l15][ks * 32 + quad * 8];
#pragma unroll
    for (int nt = 0; nt < 4; ++nt) {
      short8 bv = *(const short8*)&VT[nt * 16 + l15][ks * 32 + quad * 8];
      oc[nt] = __builtin_amdgcn_mfma_f32_16x16x32_bf16(pa, bv, oc[nt], 0, 0, 0);
    }
  }

#pragma unroll
  for (int nt = 0; nt < 4; ++nt)
#pragma unroll
    for (int r = 0; r < 4; ++r)
      attout[(size_t)(b * T + 16 * w + quad * 4 + r) * 768 + h * 64 + nt * 16 + l15] =
          f2bf(oc[nt][r]);
}

// ---------------- token: grid (12, B). f_token slice + s_token partial ----------------
__global__ __launch_bounds__(256) void token_kernel(
    const float* __restrict__ upd, const float* __restrict__ img,
    float* __restrict__ f_token, float* __restrict__ s_token) {
  const int jt = blockIdx.x, b = blockIdx.y;
  const int l = threadIdx.x & 63, tg = threadIdx.x >> 6;
  const int d = jt * 64 + l;
  float fs = 0.f, ss = 0.f;
#pragma unroll 4
  for (int tt = 0; tt < 16; ++tt) {
    const int t = tg * 16 + tt;
    const float u = upd[(size_t)(b * T + t) * D + d];
    fs += u;
    ss += u * img[(size_t)(b * P + t) * D + d];
  }
  __shared__ float red[4][64];
  __shared__ float sred[4];
  red[tg][l] = fs;
  const float sw = wave_sum(ss);
  if (l == 0) sred[tg] = sw;
  __syncthreads();
  if (tg == 0) {
    f_token[(size_t)b * D + d] =
        (red[0][l] + red[1][l] + red[2][l] + red[3][l]) * (1.0f / T);
    if (threadIdx.x == 0)
      atomicAdd(&s_token[b], (sred[0] + sred[1] + sred[2] + sred[3]) * (1.0f / T));
  }
}

// ---------------- text GAT via MFMA: one block (4 waves) per (b,h). N=64 ----------------
// Same recipe as image GAT / attention PV: normalized exp-scores -> per-wave A-layout
// LDS, Wh^T bf16 as B-operand, 8 MFMAs per wave, elu+mean in epilogue.
__global__ __launch_bounds__(256) void text_gat_mfma(
    const float* __restrict__ Wh, int ldw, const int* __restrict__ adj,
    const float* __restrict__ at, float* __restrict__ tgf) {
  const int h = blockIdx.x, b = blockIdx.y;
  const int tid = threadIdx.x, lane = tid & 63, w = tid >> 6;
  const int quad = lane >> 4, l15 = lane & 15;

  __shared__ unsigned short VT[64][72];    // Wh^T bf16: VT[f][n]
  __shared__ unsigned short Ps[4][16][72]; // per-wave normalized att rows (A-layout)
  __shared__ float srcs[64], dsts[64];
  __shared__ float redc[4][64];
  __shared__ float asv[64], adv[64];

  if (tid < 64) { asv[tid] = at[tid]; adv[tid] = at[64 + tid]; }
  for (int i = tid; i < 64 * 64; i += 256) {
    const int n = i >> 6, f = i & 63;
    VT[f][n] = f2bf(Wh[(size_t)(b * T + n) * ldw + h * 64 + f]);
  }
  __syncthreads();

  if (tid < 64) {
    float s = 0.f, dd = 0.f;
#pragma unroll 8
    for (int f = 0; f < 64; ++f) {
      const float wv = __uint_as_float((unsigned)VT[f][tid] << 16);
      s += wv * asv[f];
      dd += wv * adv[f];
    }
    srcs[tid] = s;
    dsts[tid] = dd;
  }
  __syncthreads();

  // score phase: wave w owns rows i = 16w + l15; lane covers j = 4*jj + quad
  const int i = 16 * w + l15;
  const float si = srcs[i];
  const int* ar = adj + (size_t)b * T * T + i * 64;
  float sm = 0.f;
#pragma unroll 8
  for (int jj = 0; jj < 16; ++jj) {
    const int j = 4 * jj + quad;
    float e = si + dsts[j];
    e = (e >= 0.f) ? e : 0.2f * e;
    const float p = (ar[j] != 0) ? expf(e) : 0.f;
    sm += p;
    Ps[w][l15][j] = f2bf(p);
  }
  sm += __shfl_xor(sm, 16);
  sm += __shfl_xor(sm, 32);
  const float inv = 1.0f / sm;  // diag always set -> sm > 0
  // normalize in place (each lane rescales its own entries)
#pragma unroll 8
  for (int jj = 0; jj < 16; ++jj) {
    const int j = 4 * jj + quad;
    Ps[w][l15][j] = f2bf(__uint_as_float((unsigned)Ps[w][l15][j] << 16) * inv);
  }

  // MFMA: hp[i][f] = sum_j P[i][j] Wh[j][f]; 2 k-steps, 4 f-tiles
  floatx4 oc[4] = {};
#pragma unroll
  for (int ks = 0; ks < 2; ++ks) {
    const short8 pa = *(const short8*)&Ps[w][l15][ks * 32 + quad * 8];
#pragma unroll
    for (int nt = 0; nt < 4; ++nt) {
      const short8 bv = *(const short8*)&VT[nt * 16 + l15][ks * 32 + quad * 8];
      oc[nt] = __builtin_amdgcn_mfma_f32_16x16x32_bf16(pa, bv, oc[nt], 0, 0, 0);
    }
  }

  // epilogue: elu + accumulate row-sums (C layout: col=nt*16+l15, row=16w+quad*4+r)
  float accd[4] = {};
#pragma unroll
  for (int r = 0; r < 4; ++r)
#pragma unroll
    for (int nt = 0; nt < 4; ++nt) {
      const float hp = oc[nt][r];
      accd[nt] += (hp > 0.f) ? hp : (expf(hp) - 1.0f);
    }
#pragma unroll
  for (int nt = 0; nt < 4; ++nt) {
    accd[nt] += __shfl_xor(accd[nt], 16);
    accd[nt] += __shfl_xor(accd[nt], 32);
  }
  if (quad == 0) {
#pragma unroll
    for (int nt = 0; nt < 4; ++nt) redc[w][nt * 16 + l15] = accd[nt];
  }
  __syncthreads();
  if (w == 0) {
    const float tot = redc[0][lane] + redc[1][lane] + redc[2][lane] + redc[3][lane];
    tgf[b * D + h * 64 + lane] = tot * (1.0f / T);
  }
}

// ---------------- image GAT stage 1: src/dst per (node, head) ----------------
__global__ __launch_bounds__(256) void sd_kernel(
    const float* __restrict__ Wh, const float* __restrict__ ai,
    float* __restrict__ sd) {
  const int task = blockIdx.x * 4 + (threadIdx.x >> 6);  // 0 .. 75263
  const int lane = threadIdx.x & 63;
  const int n = task / 12, h = task - n * 12;            // n in [0, 6272)
  const float v = Wh[(size_t)n * 768 + h * 64 + lane];
  float s = v * ai[lane];
  float dd = v * ai[64 + lane];
#pragma unroll
  for (int o = 32; o > 0; o >>= 1) {
    s += __shfl_xor(s, o);
    dd += __shfl_xor(dd, o);
  }
  if (lane == 0) {
    const int b = n / P, nn = n - b * P;
    float* base = sd + (size_t)(b * 12 + h) * 392 + nn;
    base[0] = s;
    base[196] = dd;
  }
}

// ---------------- image GAT stage 2: normalized exp-scores -> S (A-layout) ----------------
__global__ __launch_bounds__(256) void score_kernel(
    const float* __restrict__ sd, const int* __restrict__ adj,
    unsigned short* __restrict__ S) {
  const int w = threadIdx.x >> 6, lane = threadIdx.x & 63;
  const int i = blockIdx.x * 4 + w;            // 0..195
  const int h = blockIdx.y, b = blockIdx.z;
  const float* sdp = sd + (size_t)(b * 12 + h) * 392;
  const float si = sdp[i];
  const int* ar = adj + i * P;

  float p0 = 0.f, p1 = 0.f, p2 = 0.f, p3 = 0.f;
  {
    float e;
    e = si + sdp[196 + lane];        e = (e >= 0.f) ? e : 0.2f * e;
    if (ar[lane] != 0) p0 = expf(e);
    e = si + sdp[196 + lane + 64];   e = (e >= 0.f) ? e : 0.2f * e;
    if (ar[lane + 64] != 0) p1 = expf(e);
    e = si + sdp[196 + lane + 128];  e = (e >= 0.f) ? e : 0.2f * e;
    if (ar[lane + 128] != 0) p2 = expf(e);
    if (lane < 4) {
      e = si + sdp[196 + lane + 192]; e = (e >= 0.f) ? e : 0.2f * e;
      if (ar[lane + 192] != 0) p3 = expf(e);
    }
  }
  const float inv = 1.0f / wave_sum(p0 + p1 + p2 + p3);

  unsigned short* row = S + ((size_t)(b * 12 + h) * 196 + i) * 224;
  row[lane] = f2bf(p0 * inv);
  row[lane + 64] = f2bf(p1 * inv);
  row[lane + 128] = f2bf(p2 * inv);
  if (lane < 4) row[lane + 192] = f2bf(p3 * inv);
  else if (lane < 32) row[lane + 192] = 0;
}

// ---------------- image GAT stage 3: hp = S @ Wh via MFMA, elu, mean ----------------
__global__ __launch_bounds__(256) void image_gat_mfma(
    const float* __restrict__ Wh, const unsigned short* __restrict__ S,
    float* __restrict__ igf) {
  const int h = blockIdx.x, b = blockIdx.y;
  const int tid = threadIdx.x, lane = tid & 63, w = tid >> 6;
  const int quad = lane >> 4, l15 = lane & 15;

  __shared__ unsigned short VT[64][232];   // Wh^T bf16: VT[f][n]
  __shared__ float redc[4][64];

  for (int i = tid; i < P * 64; i += 256) {
    const int n = i >> 6, f = i & 63;
    VT[f][n] = f2bf(Wh[(size_t)(b * P + n) * 768 + h * 64 + f]);
  }
  if (tid < 64)
    for (int c = 196; c < 224; ++c) VT[tid][c] = 0;
  __syncthreads();

  const unsigned short* Sbh = S + (size_t)(b * 12 + h) * 196 * 224;
  float accd[4] = {};

  for (int tile = w; tile < 13; tile += 4) {
    const unsigned short* Srow = Sbh + (size_t)(tile * 16 + l15) * 224;
    floatx4 oc[4] = {};
#pragma unroll
    for (int ks = 0; ks < 7; ++ks) {
      const short8 pa = *(const short8*)(Srow + ks * 32 + quad * 8);
#pragma unroll
      for (int nt = 0; nt < 4; ++nt) {
        const short8 bv = *(const short8*)&VT[nt * 16 + l15][ks * 32 + quad * 8];
        oc[nt] = __builtin_amdgcn_mfma_f32_16x16x32_bf16(pa, bv, oc[nt], 0, 0, 0);
      }
    }
#pragma unroll
    for (int r = 0; r < 4; ++r) {
      const int io = tile * 16 + quad * 4 + r;
      if (io < P) {
#pragma unroll
        for (int nt = 0; nt < 4; ++nt) {
          const float hp = oc[nt][r];
          accd[nt] += (hp > 0.f) ? hp : (expf(hp) - 1.0f);
        }
      }
    }
  }

#pragma unroll
  for (int nt = 0; nt < 4; ++nt) {
    accd[nt] += __shfl_xor(accd[nt], 16);
    accd[nt] += __shfl_xor(accd[nt], 32);
  }
  if (quad == 0) {
#pragma unroll
    for (int nt = 0; nt < 4; ++nt) redc[w][nt * 16 + l15] = accd[nt];
  }
  __syncthreads();
  if (w == 0) {
    const float tot = redc[0][lane] + redc[1][lane] + redc[2][lane] + redc[3][lane];
    igf[b * D + h * 64 + lane] = tot * (1.0f / P);
  }
}

// ---------------- f_global = clip_t @ Wp + bp : grid (12, B) ----------------
__global__ __launch_bounds__(256) void fglob_kernel(
    const float* __restrict__ clip_t, const float* __restrict__ Wp,
    const float* __restrict__ bp, float* __restrict__ fglob) {
  const int jt = blockIdx.x, b = blockIdx.y;
  const int j = threadIdx.x & 63, kc = threadIdx.x >> 6;
  float s = 0.f;
  const float* ct = clip_t + b * 512;
#pragma unroll 4
  for (int k = kc * 128; k < kc * 128 + 128; ++k)
    s += ct[k] * Wp[(size_t)k * D + jt * 64 + j];
  __shared__ float red[4][64];
  red[kc][j] = s;
  __syncthreads();
  if (kc == 0)
    fglob[b * D + jt * 64 + j] = red[0][j] + red[1][j] + red[2][j] + red[3][j] + bp[jt * 64 + j];
}

// ---------------- Xc = [f_token; tgf; fglob] @ c1w : grid (6, 96) ----------------
__global__ __launch_bounds__(256) void xc1_kernel(
    const float* __restrict__ ftok, const float* __restrict__ tgf,
    const float* __restrict__ fglob, const float* __restrict__ c1w,
    float* __restrict__ Xc) {
  const int jt = blockIdx.x;
  const int r = blockIdx.y;
  const int b = r & 31, which = r >> 5;
  const float* src = (which == 0 ? ftok : which == 1 ? tgf : fglob) + (size_t)b * D;
  const int j = threadIdx.x & 63, kc = threadIdx.x >> 6;
  const int col = jt * 64 + j;
  float s = 0.f;
#pragma unroll 4
  for (int k = kc * 192; k < kc * 192 + 192; ++k)
    s += src[k] * c1w[(size_t)k * 384 + col];
  __shared__ float red[4][64];
  red[kc][j] = s;
  __syncthreads();
  if (kc == 0)
    Xc[(size_t)r * 384 + col] = red[0][j] + red[1][j] + red[2][j] + red[3][j];
}

// ---------------- final fusion kernel: one block per b ----------------
__device__ __forceinline__ float block_sum(float v, float* red4) {
  v = wave_sum(v);
  __syncthreads();
  if ((threadIdx.x & 63) == 0) red4[threadIdx.x >> 6] = v;
  __syncthreads();
  return red4[0] + red4[1] + red4[2] + red4[3];
}

__global__ __launch_bounds__(256) void final_kernel(
    const float* __restrict__ tgf, const float* __restrict__ igf,
    const float* __restrict__ clip_t, const float* __restrict__ clip_i,
    const float* __restrict__ logit_scale, const float* __restrict__ s_token,
    const float* __restrict__ Xc,
    const float* __restrict__ f1w, const float* __restrict__ f1b,
    const float* __restrict__ f2w, const float* __restrict__ f2b,
    const float* __restrict__ c1b,
    const float* __restrict__ c2w, const float* __restrict__ c2b,
    float* __restrict__ out) {
  const int b = blockIdx.x, tid = threadIdx.x;
  __shared__ float red[4];
  __shared__ float sres[4];
  __shared__ float hid[384];

  float d0 = 0.f, d1 = 0.f, d2 = 0.f;
  for (int i = tid; i < D; i += 256) {
    float x = tgf[b * D + i], y = igf[b * D + i];
    d0 += x * y; d1 += x * x; d2 += y * y;
  }
  float dot_ti = block_sum(d0, red);
  float n_t = sqrtf(block_sum(d1, red));
  float n_i = sqrtf(block_sum(d2, red));
  float s_phrase = dot_ti / (fmaxf(n_t, 1e-8f) * fmaxf(n_i, 1e-8f));

  float c0 = 0.f, c1 = 0.f, c2 = 0.f;
  for (int i = tid; i < 512; i += 256) {
    float x = clip_t[b * 512 + i], y = clip_i[b * 512 + i];
    c0 += x * y; c1 += x * x; c2 += y * y;
  }
  float dc = block_sum(c0, red);
  float nt2 = sqrtf(block_sum(c1, red));
  float ni2 = sqrtf(block_sum(c2, red));
  float s_global = expf(logit_scale[0]) * dc / (fmaxf(nt2, 1e-8f) * fmaxf(ni2, 1e-8f));

  if (tid == 0) {
    float s3[3] = { s_token[b], s_phrase, s_global };
    float h1[16];
    for (int j = 0; j < 16; ++j) {
      float a = f1b[j];
      for (int i2 = 0; i2 < 3; ++i2) a += s3[i2] * f1w[i2 * 16 + j];
      h1[j] = 0.5f * a * (1.0f + erff(a * 0.70710678118654752f));
    }
    for (int j = 0; j < 3; ++j) {
      float a = f2b[j];
      for (int i2 = 0; i2 < 16; ++i2) a += h1[i2] * f2w[i2 * 3 + j];
      sres[j] = 1.0f / (1.0f + expf(-a));
    }
  }
  __syncthreads();
  const float w0 = sres[0], w1 = sres[1], w2 = sres[2];

  for (int j = tid; j < 384; j += 256) {
    const float a = w0 * Xc[(size_t)b * 384 + j] +
                    w1 * Xc[(size_t)(32 + b) * 384 + j] +
                    w2 * Xc[(size_t)(64 + b) * 384 + j] + c1b[j];
    hid[j] = fmaxf(a, 0.0f);
  }
  __syncthreads();

  float p0 = 0.f, p1 = 0.f;
  for (int k2 = tid; k2 < 384; k2 += 256) {
    p0 += hid[k2] * c2w[k2 * 2 + 0];
    p1 += hid[k2] * c2w[k2 * 2 + 1];
  }
  p0 = block_sum(p0, red);
  p1 = block_sum(p1, red);
  if (tid == 0) {
    out[b * 2 + 0] = p0 + c2b[0];
    out[b * 2 + 1] = p1 + c2b[1];
  }
}

// ---------------- launch ----------------
extern "C" void kernel_launch(void* const* d_in, const int* in_sizes, int n_in,
                              void* d_out, int out_size, void* d_ws, size_t ws_size,
                              hipStream_t stream) {
  const float* text   = (const float*)d_in[0];
  const float* img    = (const float*)d_in[1];
  const float* clip_t = (const float*)d_in[2];
  const float* clip_i = (const float*)d_in[3];
  const float* lscale = (const float*)d_in[4];
  const float* wq = (const float*)d_in[5];
  const float* bq = (const float*)d_in[6];
  const float* wk = (const float*)d_in[7];
  const float* bk = (const float*)d_in[8];
  const float* wv = (const float*)d_in[9];
  const float* bv = (const float*)d_in[10];
  const float* wo = (const float*)d_in[11];
  const float* bo = (const float*)d_in[12];
  const float* Wt = (const float*)d_in[13];
  const float* at = (const float*)d_in[14];
  const float* Wi = (const float*)d_in[15];
  const float* ai = (const float*)d_in[16];
  const float* Wp = (const float*)d_in[17];
  const float* bp = (const float*)d_in[18];
  const float* f1w = (const float*)d_in[19];
  const float* f1b = (const float*)d_in[20];
  const float* f2w = (const float*)d_in[21];
  const float* f2b = (const float*)d_in[22];
  const float* c1w = (const float*)d_in[23];
  const float* c1b = (const float*)d_in[24];
  const float* c2w = (const float*)d_in[25];
  const float* c2b = (const float*)d_in[26];
  const int* text_adj  = (const int*)d_in[27];
  const int* image_adj = (const int*)d_in[28];
  float* out = (float*)d_out;

  const size_t nTD = (size_t)B * T * D;   // 1,572,864
  const size_t nPD = (size_t)B * P * D;   // 4,816,896
  const size_t nWW = (size_t)D * D;       // 589,824

  // workspace layout: identical footprint to rounds 8/9
  float* fbuf = (float*)d_ws;
  size_t o = 0;
  float* kv_buf = fbuf + o; o += 2 * nPD;  // [B*P][1536]: k|v ; first nPD reused as Wh_i
  float* qa_buf = fbuf + o; o += 2 * nTD;  // [B*T][1536]: q|Wh_t
  float* upd    = fbuf + o; o += nTD;
  float* ftok   = fbuf + o; o += (size_t)B * D;
  float* stok   = fbuf + o; o += 32;
  float* tgf    = fbuf + o; o += (size_t)B * D;
  float* igf    = fbuf + o; o += (size_t)B * D;
  float* fglob  = fbuf + o; o += (size_t)B * D;
  float* bcat_t = fbuf + o; o += 1536;
  float* bcat_i = fbuf + o; o += 1536;
  unsigned short* sbuf = (unsigned short*)(fbuf + o);
  size_t so = 0;
  unsigned short* text_bf  = sbuf + so; so += nTD;
  unsigned short* img_bf   = sbuf + so; so += nPD;
  unsigned short* att_bf   = sbuf + so; so += nTD;
  unsigned short* wcat_txt = sbuf + so; so += 2 * nWW;  // wq^T | Wt^T
  unsigned short* wcat_img = sbuf + so; so += 2 * nWW;  // wk^T | wv^T
  unsigned short* wo_t     = sbuf + so; so += nWW;
  unsigned short* wi_t     = sbuf + so; so += nWW;
  // Aliases (lifetime-based):
  float* Xc = (float*)img_bf;                        // [96][384] after whi GEMM
  float* sd = (float*)text_bf;                       // [384][392] after text proj GEMM
  unsigned short* S = (unsigned short*)(fbuf + nPD); // [384][196][224] bf16 over v-half+qa+upd

  // ---- weight casts + bias concat + stok zero ----
  WPack wp;
  wp.src[0] = wq; wp.dst[0] = wcat_txt;
  wp.src[1] = Wt; wp.dst[1] = wcat_txt + nWW;
  wp.src[2] = wk; wp.dst[2] = wcat_img;
  wp.src[3] = wv; wp.dst[3] = wcat_img + nWW;
  wp.src[4] = wo; wp.dst[4] = wo_t;
  wp.src[5] = Wi; wp.dst[5] = wi_t;
  cast_transpose6<<<dim3(D / 32, D / 32, 6), 256, 0, stream>>>(wp, D, D);
  build_bias<<<6, 256, 0, stream>>>(bq, bk, bv, bcat_t, bcat_i, stok);
  cast_rows<<<(int)(nTD / 4 + 255) / 256, 256, 0, stream>>>(text, text_bf, (int)(nTD / 4));
  cast_rows<<<(int)(nPD / 4 + 255) / 256, 256, 0, stream>>>(img, img_bf, (int)(nPD / 4));

  const int MT = B * T;   // 2048
  const int MP = B * P;   // 6272

  // ---- fused projections ----
  gemm_mfma<<<dim3(1536 / 128, MT / 128), 256, 0, stream>>>(text_bf, wcat_txt, bcat_t, qa_buf, MT, 1536, D);
  gemm_mfma<<<dim3(1536 / 128, MP / 128), 256, 0, stream>>>(img_bf, wcat_img, bcat_i, kv_buf, MP, 1536, D);

  fglob_kernel<<<dim3(12, B), 256, 0, stream>>>(clip_t, Wp, bp, fglob);

  attn_mfma<<<dim3(H, B), 256, 0, stream>>>(qa_buf, kv_buf, att_bf);

  gemm_mfma<<<dim3(D / 128, MT / 128), 256, 0, stream>>>(att_bf, wo_t, bo, upd, MT, D, D);
  // Wh_i GEMM reuses kv_buf first half; v-half becomes free
  float* whi = kv_buf;
  gemm_mfma<<<dim3(D / 128, MP / 128), 256, 0, stream>>>(img_bf, wi_t, nullptr, whi, MP, D, D);

  // consume upd and qa_buf BEFORE score_kernel overwrites them (S spans v-half+qa+upd)
  token_kernel<<<dim3(12, B), 256, 0, stream>>>(upd, img, ftok, stok);
  // text GAT via MFMA — the ONLY change vs round 9
  text_gat_mfma<<<dim3(H, B), 256, 0, stream>>>(qa_buf + 768, 1536, text_adj, at, tgf);

  // ---- image GAT: 3-stage parallel pipeline ----
  sd_kernel<<<MP * 12 / 4, 256, 0, stream>>>(whi, ai, sd);
  score_kernel<<<dim3(49, H, B), 256, 0, stream>>>(sd, image_adj, S);
  image_gat_mfma<<<dim3(H, B), 256, 0, stream>>>(whi, S, igf);

  xc1_kernel<<<dim3(6, 96), 256, 0, stream>>>(ftok, tgf, fglob, c1w, Xc);
  final_kernel<<<B, 256, 0, stream>>>(tgf, igf, clip_t, clip_i, lscale, stok, Xc,
                                      f1w, f1b, f2w, f2b, c1b, c2w, c2b, out);
}

// Round 11
// 349.545 us; speedup vs baseline: 4.1276x; 1.0640x over previous
//
#include <hip/hip_runtime.h>
#include <hip/hip_bf16.h>
#include <math.h>

// Problem constants
#define B 32
#define T 64
#define P 196
#define D 768
#define H 12

typedef __attribute__((ext_vector_type(8))) short short8;
typedef __attribute__((ext_vector_type(4))) float floatx4;

// ---------------- helpers ----------------
__device__ __forceinline__ float wave_sum(float v) {
#pragma unroll
  for (int o = 32; o > 0; o >>= 1) v += __shfl_xor(v, o);
  return v;
}
__device__ __forceinline__ float wave_max(float v) {
#pragma unroll
  for (int o = 32; o > 0; o >>= 1) v = fmaxf(v, __shfl_xor(v, o));
  return v;
}
__device__ __forceinline__ unsigned short f2bf(float x) {
  unsigned u = __float_as_uint(x);
  u += 0x7FFFu + ((u >> 16) & 1u);   // round-to-nearest-even
  return (unsigned short)(u >> 16);
}

// ---------------- cast kernels ----------------
// both activation casts in one launch
__global__ __launch_bounds__(256) void cast_rows2(
    const float* __restrict__ X0, unsigned short* __restrict__ Y0, int n40,
    const float* __restrict__ X1, unsigned short* __restrict__ Y1, int n41) {
  int i = blockIdx.x * 256 + threadIdx.x;
  const float* X;
  unsigned short* Y;
  int idx;
  if (i < n40) { X = X0; Y = Y0; idx = i; }
  else if (i < n40 + n41) { X = X1; Y = Y1; idx = i - n40; }
  else return;
  float4 vv = ((const float4*)X)[idx];
  ushort4 o;
  o.x = f2bf(vv.x); o.y = f2bf(vv.y); o.z = f2bf(vv.z); o.w = f2bf(vv.w);
  ((ushort4*)Y)[idx] = o;
}

// 6 weights fp32 [K][N] -> bf16 [N][K], one fused launch (grid.z = weight idx)
struct WPack {
  const float* src[6];
  unsigned short* dst[6];
};
__global__ __launch_bounds__(256) void cast_transpose6(WPack p, int K, int N) {
  __shared__ float tile[32][33];
  const float* W = p.src[blockIdx.z];
  unsigned short* Wt = p.dst[blockIdx.z];
  const int tx = threadIdx.x & 31, ty = threadIdx.x >> 5;  // ty 0..7
  const int n0 = blockIdx.x * 32, k0 = blockIdx.y * 32;
#pragma unroll
  for (int r = 0; r < 4; ++r)
    tile[ty + 8 * r][tx] = W[(size_t)(k0 + ty + 8 * r) * N + n0 + tx];
  __syncthreads();
#pragma unroll
  for (int r = 0; r < 4; ++r)
    Wt[(size_t)(n0 + ty + 8 * r) * K + k0 + tx] = f2bf(tile[tx][ty + 8 * r]);
}

// biases: bt = [bq, 0] (1536), bi = [bk, bv, 0] (2304); also zero s_token
__global__ __launch_bounds__(256) void build_bias(const float* __restrict__ bq,
                                                  const float* __restrict__ bk,
                                                  const float* __restrict__ bv,
                                                  float* __restrict__ bt,
                                                  float* __restrict__ bi,
                                                  float* __restrict__ stok) {
  int i = blockIdx.x * 256 + threadIdx.x;
  if (i < 32) stok[i] = 0.f;
  if (i < 768) { bt[i] = bq[i]; bi[i] = bk[i]; }
  else if (i < 1536) { bt[i] = 0.f; bi[i] = bv[i - 768]; }
  else if (i < 2304) { bi[i] = 0.f; }
}

// ---------------- bf16 MFMA GEMM body (shared by single & dual) ----------------
struct GemmJob {
  const unsigned short* A;   // [M][K] bf16
  const unsigned short* Bt;  // [N][K] bf16
  const float* bias;
  float* C;
  int N, K, colTiles;
};

__device__ __forceinline__ void gemm_body(const GemmJob& j, int bx, int by, int tid) {
  __shared__ unsigned short As[128][40];
  __shared__ unsigned short Bs[128][40];
  const int lane = tid & 63;
  const int w = tid >> 6;
  const int quad = lane >> 4;
  const int l15 = lane & 15;
  const int row0 = by * 128;
  const int col0 = bx * 128;
  const int m_off = (w & 1) * 64;
  const int n_off = (w >> 1) * 64;
  const int lr = tid >> 2;
  const int lc = (tid & 3) * 8;
  const int N = j.N, K = j.K;

  floatx4 acc[4][4] = {};

  for (int k0 = 0; k0 < K; k0 += 32) {
    const uint4 a0 = *(const uint4*)(j.A + (size_t)(row0 + lr) * K + k0 + lc);
    const uint4 a1 = *(const uint4*)(j.A + (size_t)(row0 + lr + 64) * K + k0 + lc);
    const uint4 b0 = *(const uint4*)(j.Bt + (size_t)(col0 + lr) * K + k0 + lc);
    const uint4 b1 = *(const uint4*)(j.Bt + (size_t)(col0 + lr + 64) * K + k0 + lc);
    __syncthreads();
    *(uint4*)&As[lr][lc] = a0;
    *(uint4*)&As[lr + 64][lc] = a1;
    *(uint4*)&Bs[lr][lc] = b0;
    *(uint4*)&Bs[lr + 64][lc] = b1;
    __syncthreads();
    short8 af[4], bfr[4];
#pragma unroll
    for (int i = 0; i < 4; ++i)
      af[i] = *(const short8*)&As[m_off + 16 * i + l15][quad * 8];
#pragma unroll
    for (int jj = 0; jj < 4; ++jj)
      bfr[jj] = *(const short8*)&Bs[n_off + 16 * jj + l15][quad * 8];
#pragma unroll
    for (int i = 0; i < 4; ++i)
#pragma unroll
      for (int jj = 0; jj < 4; ++jj)
        acc[i][jj] = __builtin_amdgcn_mfma_f32_16x16x32_bf16(af[i], bfr[jj], acc[i][jj], 0, 0, 0);
  }

#pragma unroll
  for (int jj = 0; jj < 4; ++jj) {
    const int cg = col0 + n_off + 16 * jj + l15;
    const float bv = j.bias ? j.bias[cg] : 0.0f;
#pragma unroll
    for (int i = 0; i < 4; ++i) {
      const int rbase = row0 + m_off + 16 * i + quad * 4;
#pragma unroll
      for (int r = 0; r < 4; ++r)
        j.C[(size_t)(rbase + r) * N + cg] = acc[i][jj][r] + bv;
    }
  }
}

__global__ __launch_bounds__(256) void gemm_mfma(GemmJob j) {
  gemm_body(j, blockIdx.x, blockIdx.y, threadIdx.x);
}

// two independent GEMMs in one launch; blockIdx.x < split -> job0 else job1
__global__ __launch_bounds__(256) void gemm_mfma_dual(GemmJob j0, GemmJob j1, int split) {
  const bool first = ((int)blockIdx.x < split);
  const GemmJob& j = first ? j0 : j1;
  const int bid = first ? blockIdx.x : (blockIdx.x - split);
  const int bx = bid % j.colTiles;
  const int by = bid / j.colTiles;
  gemm_body(j, bx, by, threadIdx.x);
}

// ---------------- MFMA cross attention: one block per (b,h), 4 waves ----------------
// qa: [B*T][1536] fp32 (q cols 0..767). kvw: [B*P][2304] fp32 (k 0..767, v 768..1535).
__global__ __launch_bounds__(256) void attn_mfma(
    const float* __restrict__ qa, const float* __restrict__ kvw,
    unsigned short* __restrict__ attout) {
  const int h = blockIdx.x, b = blockIdx.y;
  const int tid = threadIdx.x, lane = tid & 63, w = tid >> 6;
  const int quad = lane >> 4, l15 = lane & 15;

  __shared__ unsigned short Ks[196][72];     // K[p][d] bf16
  __shared__ unsigned short VT[64][232];     // V^T: VT[d][p]
  __shared__ unsigned short Ps[4][16][232];  // per-wave P (A-layout rows t_local)

  for (int i = tid; i < P * 64; i += 256) {
    const int p = i >> 6, d = i & 63;
    const float* row = kvw + (size_t)(b * P + p) * 2304 + h * 64 + d;
    Ks[p][d] = f2bf(row[0]);
    VT[d][p] = f2bf(row[768]);
  }
  if (tid < 64) {
    for (int c = 196; c < 224; ++c) VT[tid][c] = 0;
  }
  __syncthreads();

  short8 aq[2];
  {
    const float* qrow = qa + (size_t)(b * T + 16 * w + l15) * 1536 + h * 64;
#pragma unroll
    for (int ks = 0; ks < 2; ++ks) {
      const float4 x = *(const float4*)(qrow + 32 * ks + quad * 8);
      const float4 y = *(const float4*)(qrow + 32 * ks + quad * 8 + 4);
      short8 f;
      f[0] = (short)f2bf(x.x); f[1] = (short)f2bf(x.y);
      f[2] = (short)f2bf(x.z); f[3] = (short)f2bf(x.w);
      f[4] = (short)f2bf(y.x); f[5] = (short)f2bf(y.y);
      f[6] = (short)f2bf(y.z); f[7] = (short)f2bf(y.w);
      aq[ks] = f;
    }
  }

  floatx4 sc[13];
#pragma unroll
  for (int tile = 0; tile < 13; ++tile) {
    int p = tile * 16 + l15;
    if (p > 195) p = 195;
    short8 bk0 = *(const short8*)&Ks[p][quad * 8];
    short8 bk1 = *(const short8*)&Ks[p][32 + quad * 8];
    floatx4 c = {};
    c = __builtin_amdgcn_mfma_f32_16x16x32_bf16(aq[0], bk0, c, 0, 0, 0);
    c = __builtin_amdgcn_mfma_f32_16x16x32_bf16(aq[1], bk1, c, 0, 0, 0);
    sc[tile] = c;
  }

  float mx[4] = {-3.4e38f, -3.4e38f, -3.4e38f, -3.4e38f};
#pragma unroll
  for (int tile = 0; tile < 13; ++tile)
#pragma unroll
    for (int r = 0; r < 4; ++r) {
      float s = sc[tile][r] * 0.125f;
      if (tile == 12 && l15 >= 4) s = -3.0e38f;
      sc[tile][r] = s;
      mx[r] = fmaxf(mx[r], s);
    }
#pragma unroll
  for (int off = 1; off < 16; off <<= 1)
#pragma unroll
    for (int r = 0; r < 4; ++r) mx[r] = fmaxf(mx[r], __shfl_xor(mx[r], off));

  float sm[4] = {};
#pragma unroll
  for (int tile = 0; tile < 13; ++tile)
#pragma unroll
    for (int r = 0; r < 4; ++r) {
      float e = expf(sc[tile][r] - mx[r]);
      sc[tile][r] = e;
      sm[r] += e;
    }
#pragma unroll
  for (int off = 1; off < 16; off <<= 1)
#pragma unroll
    for (int r = 0; r < 4; ++r) sm[r] += __shfl_xor(sm[r], off);
  float inv[4];
#pragma unroll
  for (int r = 0; r < 4; ++r) inv[r] = 1.0f / sm[r];

#pragma unroll
  for (int tile = 0; tile < 13; ++tile)
#pragma unroll
    for (int r = 0; r < 4; ++r)
      Ps[w][quad * 4 + r][tile * 16 + l15] = f2bf(sc[tile][r] * inv[r]);
#pragma unroll
  for (int r = 0; r < 4; ++r)
    Ps[w][quad * 4 + r][208 + l15] = 0;

  __syncthreads();

  floatx4 oc[4] = {};
#pragma unroll
  for (int ks = 0; ks < 7; ++ks) {
    short8 pa = *(const short8*)&Ps[w][l15][ks * 32 + quad * 8];
#pragma unroll
    for (int nt = 0; nt < 4; ++nt) {
      short8 bv = *(const short8*)&VT[nt * 16 + l15][ks * 32 + quad * 8];
      oc[nt] = __builtin_amdgcn_mfma_f32_16x16x32_bf16(pa, bv, oc[nt], 0, 0, 0);
    }
  }

#pragma unroll
  for (int nt = 0; nt < 4; ++nt)
#pragma unroll
    for (int r = 0; r < 4; ++r)
      attout[(size_t)(b * T + 16 * w + quad * 4 + r) * 768 + h * 64 + nt * 16 + l15] =
          f2bf(oc[nt][r]);
}

// ---------------- token: grid (12, B). f_token slice + s_token partial ----------------
__global__ __launch_bounds__(256) void token_kernel(
    const float* __restrict__ upd, const float* __restrict__ img,
    float* __restrict__ f_token, float* __restrict__ s_token) {
  const int jt = blockIdx.x, b = blockIdx.y;
  const int l = threadIdx.x & 63, tg = threadIdx.x >> 6;
  const int d = jt * 64 + l;
  float fs = 0.f, ss = 0.f;
#pragma unroll 4
  for (int tt = 0; tt < 16; ++tt) {
    const int t = tg * 16 + tt;
    const float u = upd[(size_t)(b * T + t) * D + d];
    fs += u;
    ss += u * img[(size_t)(b * P + t) * D + d];
  }
  __shared__ float red[4][64];
  __shared__ float sred[4];
  red[tg][l] = fs;
  const float sw = wave_sum(ss);
  if (l == 0) sred[tg] = sw;
  __syncthreads();
  if (tg == 0) {
    f_token[(size_t)b * D + d] =
        (red[0][l] + red[1][l] + red[2][l] + red[3][l]) * (1.0f / T);
    if (threadIdx.x == 0)
      atomicAdd(&s_token[b], (sred[0] + sred[1] + sred[2] + sred[3]) * (1.0f / T));
  }
}

// ---------------- text GAT via MFMA: one block (4 waves) per (b,h). N=64 ----------------
__global__ __launch_bounds__(256) void text_gat_mfma(
    const float* __restrict__ Wh, int ldw, const int* __restrict__ adj,
    const float* __restrict__ at, float* __restrict__ tgf) {
  const int h = blockIdx.x, b = blockIdx.y;
  const int tid = threadIdx.x, lane = tid & 63, w = tid >> 6;
  const int quad = lane >> 4, l15 = lane & 15;

  __shared__ unsigned short VT[64][72];    // Wh^T bf16: VT[f][n]
  __shared__ unsigned short Ps[4][16][72]; // per-wave normalized att rows (A-layout)
  __shared__ float srcs[64], dsts[64];
  __shared__ float redc[4][64];
  __shared__ float asv[64], adv[64];

  if (tid < 64) { asv[tid] = at[tid]; adv[tid] = at[64 + tid]; }
  for (int i = tid; i < 64 * 64; i += 256) {
    const int n = i >> 6, f = i & 63;
    VT[f][n] = f2bf(Wh[(size_t)(b * T + n) * ldw + h * 64 + f]);
  }
  __syncthreads();

  if (tid < 64) {
    float s = 0.f, dd = 0.f;
#pragma unroll 8
    for (int f = 0; f < 64; ++f) {
      const float wv = __uint_as_float((unsigned)VT[f][tid] << 16);
      s += wv * asv[f];
      dd += wv * adv[f];
    }
    srcs[tid] = s;
    dsts[tid] = dd;
  }
  __syncthreads();

  const int i = 16 * w + l15;
  const float si = srcs[i];
  const int* ar = adj + (size_t)b * T * T + i * 64;
  float sm = 0.f;
#pragma unroll 8
  for (int jj = 0; jj < 16; ++jj) {
    const int j = 4 * jj + quad;
    float e = si + dsts[j];
    e = (e >= 0.f) ? e : 0.2f * e;
    const float p = (ar[j] != 0) ? expf(e) : 0.f;
    sm += p;
    Ps[w][l15][j] = f2bf(p);
  }
  sm += __shfl_xor(sm, 16);
  sm += __shfl_xor(sm, 32);
  const float inv = 1.0f / sm;
#pragma unroll 8
  for (int jj = 0; jj < 16; ++jj) {
    const int j = 4 * jj + quad;
    Ps[w][l15][j] = f2bf(__uint_as_float((unsigned)Ps[w][l15][j] << 16) * inv);
  }

  floatx4 oc[4] = {};
#pragma unroll
  for (int ks = 0; ks < 2; ++ks) {
    const short8 pa = *(const short8*)&Ps[w][l15][ks * 32 + quad * 8];
#pragma unroll
    for (int nt = 0; nt < 4; ++nt) {
      const short8 bv = *(const short8*)&VT[nt * 16 + l15][ks * 32 + quad * 8];
      oc[nt] = __builtin_amdgcn_mfma_f32_16x16x32_bf16(pa, bv, oc[nt], 0, 0, 0);
    }
  }

  float accd[4] = {};
#pragma unroll
  for (int r = 0; r < 4; ++r)
#pragma unroll
    for (int nt = 0; nt < 4; ++nt) {
      const float hp = oc[nt][r];
      accd[nt] += (hp > 0.f) ? hp : (expf(hp) - 1.0f);
    }
#pragma unroll
  for (int nt = 0; nt < 4; ++nt) {
    accd[nt] += __shfl_xor(accd[nt], 16);
    accd[nt] += __shfl_xor(accd[nt], 32);
  }
  if (quad == 0) {
#pragma unroll
    for (int nt = 0; nt < 4; ++nt) redc[w][nt * 16 + l15] = accd[nt];
  }
  __syncthreads();
  if (w == 0) {
    const float tot = redc[0][lane] + redc[1][lane] + redc[2][lane] + redc[3][lane];
    tgf[b * D + h * 64 + lane] = tot * (1.0f / T);
  }
}

// ---------------- image GAT stage 1: src/dst per (node, head) ----------------
__global__ __launch_bounds__(256) void sd_kernel(
    const float* __restrict__ Wh, int ldw, const float* __restrict__ ai,
    float* __restrict__ sd) {
  const int task = blockIdx.x * 4 + (threadIdx.x >> 6);  // 0 .. 75263
  const int lane = threadIdx.x & 63;
  const int n = task / 12, h = task - n * 12;            // n in [0, 6272)
  const float v = Wh[(size_t)n * ldw + h * 64 + lane];
  float s = v * ai[lane];
  float dd = v * ai[64 + lane];
#pragma unroll
  for (int o = 32; o > 0; o >>= 1) {
    s += __shfl_xor(s, o);
    dd += __shfl_xor(dd, o);
  }
  if (lane == 0) {
    const int b = n / P, nn = n - b * P;
    float* base = sd + (size_t)(b * 12 + h) * 392 + nn;
    base[0] = s;
    base[196] = dd;
  }
}

// ---------------- image GAT stage 2: normalized exp-scores -> S (A-layout) ----------------
__global__ __launch_bounds__(256) void score_kernel(
    const float* __restrict__ sd, const int* __restrict__ adj,
    unsigned short* __restrict__ S) {
  const int w = threadIdx.x >> 6, lane = threadIdx.x & 63;
  const int i = blockIdx.x * 4 + w;            // 0..195
  const int h = blockIdx.y, b = blockIdx.z;
  const float* sdp = sd + (size_t)(b * 12 + h) * 392;
  const float si = sdp[i];
  const int* ar = adj + i * P;

  float p0 = 0.f, p1 = 0.f, p2 = 0.f, p3 = 0.f;
  {
    float e;
    e = si + sdp[196 + lane];        e = (e >= 0.f) ? e : 0.2f * e;
    if (ar[lane] != 0) p0 = expf(e);
    e = si + sdp[196 + lane + 64];   e = (e >= 0.f) ? e : 0.2f * e;
    if (ar[lane + 64] != 0) p1 = expf(e);
    e = si + sdp[196 + lane + 128];  e = (e >= 0.f) ? e : 0.2f * e;
    if (ar[lane + 128] != 0) p2 = expf(e);
    if (lane < 4) {
      e = si + sdp[196 + lane + 192]; e = (e >= 0.f) ? e : 0.2f * e;
      if (ar[lane + 192] != 0) p3 = expf(e);
    }
  }
  const float inv = 1.0f / wave_sum(p0 + p1 + p2 + p3);

  unsigned short* row = S + ((size_t)(b * 12 + h) * 196 + i) * 224;
  row[lane] = f2bf(p0 * inv);
  row[lane + 64] = f2bf(p1 * inv);
  row[lane + 128] = f2bf(p2 * inv);
  if (lane < 4) row[lane + 192] = f2bf(p3 * inv);
  else if (lane < 32) row[lane + 192] = 0;
}

// ---------------- image GAT stage 3: hp = S @ Wh via MFMA, elu, mean ----------------
__global__ __launch_bounds__(256) void image_gat_mfma(
    const float* __restrict__ Wh, int ldw, const unsigned short* __restrict__ S,
    float* __restrict__ igf) {
  const int h = blockIdx.x, b = blockIdx.y;
  const int tid = threadIdx.x, lane = tid & 63, w = tid >> 6;
  const int quad = lane >> 4, l15 = lane & 15;

  __shared__ unsigned short VT[64][232];   // Wh^T bf16: VT[f][n]
  __shared__ float redc[4][64];

  for (int i = tid; i < P * 64; i += 256) {
    const int n = i >> 6, f = i & 63;
    VT[f][n] = f2bf(Wh[(size_t)(b * P + n) * ldw + h * 64 + f]);
  }
  if (tid < 64)
    for (int c = 196; c < 224; ++c) VT[tid][c] = 0;
  __syncthreads();

  const unsigned short* Sbh = S + (size_t)(b * 12 + h) * 196 * 224;
  float accd[4] = {};

  for (int tile = w; tile < 13; tile += 4) {
    const unsigned short* Srow = Sbh + (size_t)(tile * 16 + l15) * 224;
    floatx4 oc[4] = {};
#pragma unroll
    for (int ks = 0; ks < 7; ++ks) {
      const short8 pa = *(const short8*)(Srow + ks * 32 + quad * 8);
#pragma unroll
      for (int nt = 0; nt < 4; ++nt) {
        const short8 bv = *(const short8*)&VT[nt * 16 + l15][ks * 32 + quad * 8];
        oc[nt] = __builtin_amdgcn_mfma_f32_16x16x32_bf16(pa, bv, oc[nt], 0, 0, 0);
      }
    }
#pragma unroll
    for (int r = 0; r < 4; ++r) {
      const int io = tile * 16 + quad * 4 + r;
      if (io < P) {
#pragma unroll
        for (int nt = 0; nt < 4; ++nt) {
          const float hp = oc[nt][r];
          accd[nt] += (hp > 0.f) ? hp : (expf(hp) - 1.0f);
        }
      }
    }
  }

#pragma unroll
  for (int nt = 0; nt < 4; ++nt) {
    accd[nt] += __shfl_xor(accd[nt], 16);
    accd[nt] += __shfl_xor(accd[nt], 32);
  }
  if (quad == 0) {
#pragma unroll
    for (int nt = 0; nt < 4; ++nt) redc[w][nt * 16 + l15] = accd[nt];
  }
  __syncthreads();
  if (w == 0) {
    const float tot = redc[0][lane] + redc[1][lane] + redc[2][lane] + redc[3][lane];
    igf[b * D + h * 64 + lane] = tot * (1.0f / P);
  }
}

// ---------------- f_global = clip_t @ Wp + bp : grid (12, B) ----------------
__global__ __launch_bounds__(256) void fglob_kernel(
    const float* __restrict__ clip_t, const float* __restrict__ Wp,
    const float* __restrict__ bp, float* __restrict__ fglob) {
  const int jt = blockIdx.x, b = blockIdx.y;
  const int j = threadIdx.x & 63, kc = threadIdx.x >> 6;
  float s = 0.f;
  const float* ct = clip_t + b * 512;
#pragma unroll 4
  for (int k = kc * 128; k < kc * 128 + 128; ++k)
    s += ct[k] * Wp[(size_t)k * D + jt * 64 + j];
  __shared__ float red[4][64];
  red[kc][j] = s;
  __syncthreads();
  if (kc == 0)
    fglob[b * D + jt * 64 + j] = red[0][j] + red[1][j] + red[2][j] + red[3][j] + bp[jt * 64 + j];
}

// ---------------- Xc = [f_token; tgf; fglob] @ c1w : grid (6, 96) ----------------
__global__ __launch_bounds__(256) void xc1_kernel(
    const float* __restrict__ ftok, const float* __restrict__ tgf,
    const float* __restrict__ fglob, const float* __restrict__ c1w,
    float* __restrict__ Xc) {
  const int jt = blockIdx.x;
  const int r = blockIdx.y;
  const int b = r & 31, which = r >> 5;
  const float* src = (which == 0 ? ftok : which == 1 ? tgf : fglob) + (size_t)b * D;
  const int j = threadIdx.x & 63, kc = threadIdx.x >> 6;
  const int col = jt * 64 + j;
  float s = 0.f;
#pragma unroll 4
  for (int k = kc * 192; k < kc * 192 + 192; ++k)
    s += src[k] * c1w[(size_t)k * 384 + col];
  __shared__ float red[4][64];
  red[kc][j] = s;
  __syncthreads();
  if (kc == 0)
    Xc[(size_t)r * 384 + col] = red[0][j] + red[1][j] + red[2][j] + red[3][j];
}

// ---------------- final fusion kernel: one block per b ----------------
__device__ __forceinline__ float block_sum(float v, float* red4) {
  v = wave_sum(v);
  __syncthreads();
  if ((threadIdx.x & 63) == 0) red4[threadIdx.x >> 6] = v;
  __syncthreads();
  return red4[0] + red4[1] + red4[2] + red4[3];
}

__global__ __launch_bounds__(256) void final_kernel(
    const float* __restrict__ tgf, const float* __restrict__ igf,
    const float* __restrict__ clip_t, const float* __restrict__ clip_i,
    const float* __restrict__ logit_scale, const float* __restrict__ s_token,
    const float* __restrict__ Xc,
    const float* __restrict__ f1w, const float* __restrict__ f1b,
    const float* __restrict__ f2w, const float* __restrict__ f2b,
    const float* __restrict__ c1b,
    const float* __restrict__ c2w, const float* __restrict__ c2b,
    float* __restrict__ out) {
  const int b = blockIdx.x, tid = threadIdx.x;
  __shared__ float red[4];
  __shared__ float sres[4];
  __shared__ float hid[384];

  float d0 = 0.f, d1 = 0.f, d2 = 0.f;
  for (int i = tid; i < D; i += 256) {
    float x = tgf[b * D + i], y = igf[b * D + i];
    d0 += x * y; d1 += x * x; d2 += y * y;
  }
  float dot_ti = block_sum(d0, red);
  float n_t = sqrtf(block_sum(d1, red));
  float n_i = sqrtf(block_sum(d2, red));
  float s_phrase = dot_ti / (fmaxf(n_t, 1e-8f) * fmaxf(n_i, 1e-8f));

  float c0 = 0.f, c1 = 0.f, c2 = 0.f;
  for (int i = tid; i < 512; i += 256) {
    float x = clip_t[b * 512 + i], y = clip_i[b * 512 + i];
    c0 += x * y; c1 += x * x; c2 += y * y;
  }
  float dc = block_sum(c0, red);
  float nt2 = sqrtf(block_sum(c1, red));
  float ni2 = sqrtf(block_sum(c2, red));
  float s_global = expf(logit_scale[0]) * dc / (fmaxf(nt2, 1e-8f) * fmaxf(ni2, 1e-8f));

  if (tid == 0) {
    float s3[3] = { s_token[b], s_phrase, s_global };
    float h1[16];
    for (int j = 0; j < 16; ++j) {
      float a = f1b[j];
      for (int i2 = 0; i2 < 3; ++i2) a += s3[i2] * f1w[i2 * 16 + j];
      h1[j] = 0.5f * a * (1.0f + erff(a * 0.70710678118654752f));
    }
    for (int j = 0; j < 3; ++j) {
      float a = f2b[j];
      for (int i2 = 0; i2 < 16; ++i2) a += h1[i2] * f2w[i2 * 3 + j];
      sres[j] = 1.0f / (1.0f + expf(-a));
    }
  }
  __syncthreads();
  const float w0 = sres[0], w1 = sres[1], w2 = sres[2];

  for (int j = tid; j < 384; j += 256) {
    const float a = w0 * Xc[(size_t)b * 384 + j] +
                    w1 * Xc[(size_t)(32 + b) * 384 + j] +
                    w2 * Xc[(size_t)(64 + b) * 384 + j] + c1b[j];
    hid[j] = fmaxf(a, 0.0f);
  }
  __syncthreads();

  float p0 = 0.f, p1 = 0.f;
  for (int k2 = tid; k2 < 384; k2 += 256) {
    p0 += hid[k2] * c2w[k2 * 2 + 0];
    p1 += hid[k2] * c2w[k2 * 2 + 1];
  }
  p0 = block_sum(p0, red);
  p1 = block_sum(p1, red);
  if (tid == 0) {
    out[b * 2 + 0] = p0 + c2b[0];
    out[b * 2 + 1] = p1 + c2b[1];
  }
}

// ---------------- launch ----------------
extern "C" void kernel_launch(void* const* d_in, const int* in_sizes, int n_in,
                              void* d_out, int out_size, void* d_ws, size_t ws_size,
                              hipStream_t stream) {
  const float* text   = (const float*)d_in[0];
  const float* img    = (const float*)d_in[1];
  const float* clip_t = (const float*)d_in[2];
  const float* clip_i = (const float*)d_in[3];
  const float* lscale = (const float*)d_in[4];
  const float* wq = (const float*)d_in[5];
  const float* bq = (const float*)d_in[6];
  const float* wk = (const float*)d_in[7];
  const float* bk = (const float*)d_in[8];
  const float* wv = (const float*)d_in[9];
  const float* bv = (const float*)d_in[10];
  const float* wo = (const float*)d_in[11];
  const float* bo = (const float*)d_in[12];
  const float* Wt = (const float*)d_in[13];
  const float* at = (const float*)d_in[14];
  const float* Wi = (const float*)d_in[15];
  const float* ai = (const float*)d_in[16];
  const float* Wp = (const float*)d_in[17];
  const float* bp = (const float*)d_in[18];
  const float* f1w = (const float*)d_in[19];
  const float* f1b = (const float*)d_in[20];
  const float* f2w = (const float*)d_in[21];
  const float* f2b = (const float*)d_in[22];
  const float* c1w = (const float*)d_in[23];
  const float* c1b = (const float*)d_in[24];
  const float* c2w = (const float*)d_in[25];
  const float* c2b = (const float*)d_in[26];
  const int* text_adj  = (const int*)d_in[27];
  const int* image_adj = (const int*)d_in[28];
  float* out = (float*)d_out;

  const size_t nTD = (size_t)B * T * D;   // 1,572,864
  const size_t nPD = (size_t)B * P * D;   // 4,816,896
  const size_t nWW = (size_t)D * D;       // 589,824

  // ---- workspace layout (no aliasing; ~134 MB < 256 MiB ws) ----
  float* fbuf = (float*)d_ws;
  size_t o = 0;
  float* kvw_buf = fbuf + o; o += 3 * nPD;  // [B*P][2304]: k|v|Wh_i
  float* qa_buf  = fbuf + o; o += 2 * nTD;  // [B*T][1536]: q|Wh_t
  float* upd     = fbuf + o; o += nTD;
  float* ftok    = fbuf + o; o += (size_t)B * D;
  float* stok    = fbuf + o; o += 32;
  float* tgf     = fbuf + o; o += (size_t)B * D;
  float* igf     = fbuf + o; o += (size_t)B * D;
  float* fglob   = fbuf + o; o += (size_t)B * D;
  float* bcat_t  = fbuf + o; o += 1536;
  float* bcat_i3 = fbuf + o; o += 2304;
  float* sd      = fbuf + o; o += (size_t)384 * 392;
  float* Xc      = fbuf + o; o += (size_t)96 * 384;
  unsigned short* sbuf = (unsigned short*)(fbuf + o);
  size_t so = 0;
  unsigned short* text_bf   = sbuf + so; so += nTD;
  unsigned short* img_bf    = sbuf + so; so += nPD;
  unsigned short* att_bf    = sbuf + so; so += nTD;
  unsigned short* wcat_txt  = sbuf + so; so += 2 * nWW;  // wq^T | Wt^T
  unsigned short* wcat_img3 = sbuf + so; so += 3 * nWW;  // wk^T | wv^T | Wi^T
  unsigned short* wo_t      = sbuf + so; so += nWW;
  unsigned short* S         = sbuf + so; so += (size_t)384 * 196 * 224;

  // ---- weight casts + biases + activation casts ----
  WPack wp;
  wp.src[0] = wq; wp.dst[0] = wcat_txt;
  wp.src[1] = Wt; wp.dst[1] = wcat_txt + nWW;
  wp.src[2] = wk; wp.dst[2] = wcat_img3;
  wp.src[3] = wv; wp.dst[3] = wcat_img3 + nWW;
  wp.src[4] = Wi; wp.dst[4] = wcat_img3 + 2 * nWW;
  wp.src[5] = wo; wp.dst[5] = wo_t;
  cast_transpose6<<<dim3(D / 32, D / 32, 6), 256, 0, stream>>>(wp, D, D);
  build_bias<<<12, 256, 0, stream>>>(bq, bk, bv, bcat_t, bcat_i3, stok);
  {
    const int n40 = (int)(nTD / 4), n41 = (int)(nPD / 4);
    cast_rows2<<<(n40 + n41 + 255) / 256, 256, 0, stream>>>(text, text_bf, n40, img, img_bf, n41);
  }

  const int MT = B * T;   // 2048
  const int MP = B * P;   // 6272

  // ---- fused projections: one dual launch (img3: 882 blocks, text: 192 blocks) ----
  GemmJob jimg;  // kvw = img @ [wk|wv|Wi] + [bk,bv,0]
  jimg.A = img_bf; jimg.Bt = wcat_img3; jimg.bias = bcat_i3; jimg.C = kvw_buf;
  jimg.N = 2304; jimg.K = D; jimg.colTiles = 2304 / 128;            // 18 x 49
  GemmJob jtxt;  // qa = text @ [wq|Wt] + [bq,0]
  jtxt.A = text_bf; jtxt.Bt = wcat_txt; jtxt.bias = bcat_t; jtxt.C = qa_buf;
  jtxt.N = 1536; jtxt.K = D; jtxt.colTiles = 1536 / 128;            // 12 x 16
  const int splitBlocks = (2304 / 128) * (MP / 128);                // 882
  const int totalBlocks = splitBlocks + (1536 / 128) * (MT / 128);  // 882 + 192
  gemm_mfma_dual<<<totalBlocks, 256, 0, stream>>>(jimg, jtxt, splitBlocks);

  fglob_kernel<<<dim3(12, B), 256, 0, stream>>>(clip_t, Wp, bp, fglob);

  attn_mfma<<<dim3(H, B), 256, 0, stream>>>(qa_buf, kvw_buf, att_bf);

  GemmJob jwo;   // upd = att @ wo + bo
  jwo.A = att_bf; jwo.Bt = wo_t; jwo.bias = bo; jwo.C = upd;
  jwo.N = D; jwo.K = D; jwo.colTiles = D / 128;
  gemm_mfma<<<dim3(D / 128, MT / 128), 256, 0, stream>>>(jwo);

  token_kernel<<<dim3(12, B), 256, 0, stream>>>(upd, img, ftok, stok);
  text_gat_mfma<<<dim3(H, B), 256, 0, stream>>>(qa_buf + 768, 1536, text_adj, at, tgf);

  // ---- image GAT: 3-stage pipeline on whi = kvw cols 1536.. (stride 2304) ----
  const float* whi = kvw_buf + 1536;
  sd_kernel<<<MP * 12 / 4, 256, 0, stream>>>(whi, 2304, ai, sd);
  score_kernel<<<dim3(49, H, B), 256, 0, stream>>>(sd, image_adj, S);
  image_gat_mfma<<<dim3(H, B), 256, 0, stream>>>(whi, 2304, S, igf);

  xc1_kernel<<<dim3(6, 96), 256, 0, stream>>>(ftok, tgf, fglob, c1w, Xc);
  final_kernel<<<B, 256, 0, stream>>>(tgf, igf, clip_t, clip_i, lscale, stok, Xc,
                                      f1w, f1b, f2w, f2b, c1b, c2w, c2b, out);
}